// Round 1
// baseline (1527.557 us; speedup 1.0000x reference)
//
#include <hip/hip_runtime.h>
#include <math.h>

#define NN 100000
#define RR 4
#define EE 300000
#define PP 2
#define HH 64
#define SS 4096

// Wr[r][i][o] = sum_b C[r][b] * V[b][i][o]   (B=2, 64x64)
__global__ void compute_wr(const float* __restrict__ C, const float* __restrict__ V,
                           float* __restrict__ Wr) {
    int idx = blockIdx.x * 256 + threadIdx.x;
    if (idx >= RR * HH * HH) return;
    int r = idx >> 12;       // / 4096
    int io = idx & 4095;
    Wr[idx] = C[r * 2] * V[io] + C[r * 2 + 1] * V[4096 + io];
}

// deg[n][r] += 1 for each edge (r, src->dst)
__global__ void deg_kernel(const int* __restrict__ edges, float* __restrict__ deg) {
    int idx = blockIdx.x * 256 + threadIdx.x;
    if (idx >= RR * EE) return;
    int r = idx / EE;
    int dst = edges[2 * idx + 1];
    atomicAdd(&deg[dst * RR + r], 1.0f);
}

// agg[dst][r][h] += feat[src][h] — one wave (64 lanes) per edge
__global__ void scatter_kernel(const int* __restrict__ edges,
                               const float* __restrict__ feat,
                               float* __restrict__ agg) {
    long long gid = (long long)blockIdx.x * 256 + threadIdx.x;
    int lane = (int)(gid & 63);
    long long e = gid >> 6;
    if (e >= (long long)RR * EE) return;
    int r = (int)(e / EE);
    int src = edges[2 * e];
    int dst = edges[2 * e + 1];
    float v = feat[(long long)src * HH + lane];
    atomicAdd(&agg[((long long)dst * RR + r) * HH + lane], v);
}

__global__ void gather_kernel(const float* __restrict__ h, const int* __restrict__ seeds,
                              float* __restrict__ hs) {
    int idx = blockIdx.x * 256 + threadIdx.x;
    if (idx >= SS * HH) return;
    int s = idx >> 6;
    hs[idx] = h[(long long)seeds[s] * HH + (idx & 63)];
}

// Generic tiled fp32 GEMM: C = ACT(A@W + bias) [+ Dadd]
// ACT: 0 none, 1 relu, 2 leaky(0.01), 3 tanh
// NORM: A element (m,k) scaled by 1/max(deg[m*4 + (k>>6)],1)  (combine step)
// Tile: 64x64, BK=16, 256 threads, 4x4 per thread.
template <int ACT, bool NORM, bool ADD>
__global__ __launch_bounds__(256) void gemm_kernel(
    const float* __restrict__ A, int lda, long long sA,
    const float* __restrict__ W, long long sW,
    const float* __restrict__ bias, long long sB,
    const float* __restrict__ Dadd, int ldd,
    const float* __restrict__ deg,
    float* __restrict__ Cc, int ldc, long long sC,
    int M, int Nn, int K)
{
    __shared__ float As[64][17];
    __shared__ float Bs[16][64];
    int z = blockIdx.z;
    A += (long long)z * sA;
    W += (long long)z * sW;
    const float* bz = bias ? bias + (long long)z * sB : nullptr;
    Cc += (long long)z * sC;

    int m0 = blockIdx.y * 64;
    int n0 = blockIdx.x * 64;
    int tx = threadIdx.x, ty = threadIdx.y;
    int tid = ty * 16 + tx;

    float acc[4][4] = {};

    for (int k0 = 0; k0 < K; k0 += 16) {
        #pragma unroll
        for (int i = 0; i < 4; i++) {
            int elem = tid + i * 256;
            int m = elem >> 4;
            int k = elem & 15;
            int gm = m0 + m, gk = k0 + k;
            float v = 0.f;
            if (gm < M) {
                v = A[(long long)gm * lda + gk];
                if (NORM) {
                    float d = deg[gm * 4 + (gk >> 6)];
                    v *= 1.0f / fmaxf(d, 1.0f);
                }
            }
            As[m][k] = v;
        }
        #pragma unroll
        for (int i = 0; i < 4; i++) {
            int elem = tid + i * 256;
            int k = elem >> 6;
            int n = elem & 63;
            int gn = n0 + n;
            float v = 0.f;
            if (gn < Nn) v = W[(long long)(k0 + k) * Nn + gn];
            Bs[k][n] = v;
        }
        __syncthreads();
        #pragma unroll
        for (int kk = 0; kk < 16; kk++) {
            float a[4], b[4];
            #pragma unroll
            for (int i = 0; i < 4; i++) a[i] = As[ty * 4 + i][kk];
            #pragma unroll
            for (int j = 0; j < 4; j++) b[j] = Bs[kk][tx * 4 + j];
            #pragma unroll
            for (int i = 0; i < 4; i++)
                #pragma unroll
                for (int j = 0; j < 4; j++)
                    acc[i][j] += a[i] * b[j];
        }
        __syncthreads();
    }

    #pragma unroll
    for (int i = 0; i < 4; i++) {
        int gm = m0 + ty * 4 + i;
        if (gm >= M) continue;
        #pragma unroll
        for (int j = 0; j < 4; j++) {
            int gn = n0 + tx * 4 + j;
            if (gn >= Nn) continue;
            float v = acc[i][j];
            if (bz) v += bz[gn];
            if (ACT == 1) v = fmaxf(v, 0.f);
            else if (ACT == 2) v = (v > 0.f) ? v : 0.01f * v;
            else if (ACT == 3) v = tanhf(v);
            if (ADD) v += Dadd[(long long)gm * ldd + gn];
            Cc[(long long)gm * ldc + gn] = v;
        }
    }
}

extern "C" void kernel_launch(void* const* d_in, const int* in_sizes, int n_in,
                              void* d_out, int out_size, void* d_ws, size_t ws_size,
                              hipStream_t stream) {
    const float* x    = (const float*)d_in[0];
    const int* edges  = (const int*)d_in[1];
    const int* seeds  = (const int*)d_in[2];
    const float* noise= (const float*)d_in[3];
    const float* V1   = (const float*)d_in[4];
    const float* C1   = (const float*)d_in[5];
    const float* V2   = (const float*)d_in[6];
    const float* C2   = (const float*)d_in[7];
    const float* Wlin = (const float*)d_in[8];
    const float* blin = (const float*)d_in[9];
    const float* Wd1 = (const float*)d_in[10]; const float* bd1 = (const float*)d_in[11];
    const float* Wd2 = (const float*)d_in[12]; const float* bd2 = (const float*)d_in[13];
    const float* Wd3 = (const float*)d_in[14]; const float* bd3 = (const float*)d_in[15];
    const float* Wf1 = (const float*)d_in[16]; const float* bf1 = (const float*)d_in[17];
    const float* Wf2 = (const float*)d_in[18]; const float* bf2 = (const float*)d_in[19];
    const float* Wf3 = (const float*)d_in[20]; const float* bf3 = (const float*)d_in[21];

    float* out = (float*)d_out;

    char* ws = (char*)d_ws;
    size_t off = 0;
    auto alloc = [&](size_t nf) {
        float* p = (float*)(ws + off);
        off += ((nf * 4 + 255) / 256) * 256;
        return p;
    };
    float* Wr1 = alloc((size_t)RR * HH * HH);
    float* Wr2 = alloc((size_t)RR * HH * HH);
    float* deg = alloc((size_t)NN * RR);
    float* agg = alloc((size_t)NN * RR * HH);   // 102.4 MB; reused for MLP bufs
    float* h1  = alloc((size_t)NN * HH);        // also reused as h3
    float* h2  = alloc((size_t)NN * HH);
    float* hs  = alloc((size_t)SS * HH);

    // MLP buffers live in the (dead after combine2) agg region:
    float* d1 = agg;                                     // P*S*256
    float* d2v = d1 + (size_t)PP * SS * 256;             // P*S*32
    float* f1 = d2v + (size_t)PP * SS * 32;              // P*S*256
    float* f2 = f1 + (size_t)PP * SS * 256;              // P*S*2048 (ends < NN*RR*HH)

    hipMemsetAsync(deg, 0, (size_t)NN * RR * 4, stream);
    hipMemsetAsync(agg, 0, (size_t)NN * RR * HH * 4, stream);

    compute_wr<<<(RR * HH * HH + 255) / 256, 256, 0, stream>>>(C1, V1, Wr1);
    compute_wr<<<(RR * HH * HH + 255) / 256, 256, 0, stream>>>(C2, V2, Wr2);
    deg_kernel<<<(RR * EE + 255) / 256, 256, 0, stream>>>(edges, deg);

    long long scatter_threads = (long long)RR * EE * 64;
    int scatter_blocks = (int)((scatter_threads + 255) / 256);
    scatter_kernel<<<scatter_blocks, 256, 0, stream>>>(edges, x, agg);

    dim3 blk(16, 16);
    // combine layer 1: h1 = relu((agg/deg) @ Wr1stack), M=NN, N=64, K=256
    gemm_kernel<1, true, false><<<dim3(1, (NN + 63) / 64, 1), blk, 0, stream>>>(
        agg, 256, 0, Wr1, 0, nullptr, 0, nullptr, 0, deg, h1, 64, 0, NN, 64, 256);

    hipMemsetAsync(agg, 0, (size_t)NN * RR * HH * 4, stream);
    scatter_kernel<<<scatter_blocks, 256, 0, stream>>>(edges, h1, agg);

    // combine layer 2 -> h2
    gemm_kernel<1, true, false><<<dim3(1, (NN + 63) / 64, 1), blk, 0, stream>>>(
        agg, 256, 0, Wr2, 0, nullptr, 0, nullptr, 0, deg, h2, 64, 0, NN, 64, 256);

    // linear: h3 = leaky(h2 @ Wlin + blin) + noise   (h3 reuses h1 buffer)
    float* h3 = h1;
    gemm_kernel<2, false, true><<<dim3(1, (NN + 63) / 64, 1), blk, 0, stream>>>(
        h2, 64, 0, Wlin, 0, blin, 0, noise, 64, nullptr, h3, 64, 0, NN, 64, 64);

    gather_kernel<<<(SS * HH + 255) / 256, 256, 0, stream>>>(h3, seeds, hs);

    // d1 = leaky(hs @ Wd1[p] + bd1[p])
    gemm_kernel<2, false, false><<<dim3(4, SS / 64, PP), blk, 0, stream>>>(
        hs, 64, 0, Wd1, (long long)64 * 256, bd1, 256, nullptr, 0, nullptr,
        d1, 256, (long long)SS * 256, SS, 256, 64);
    // d2 = leaky(d1 @ Wd2[p] + bd2[p])
    gemm_kernel<2, false, false><<<dim3(1, SS / 64, PP), blk, 0, stream>>>(
        d1, 256, (long long)SS * 256, Wd2, (long long)256 * 32, bd2, 32, nullptr, 0, nullptr,
        d2v, 32, (long long)SS * 32, SS, 32, 256);
    // pred_missing = relu(d2 @ Wd3[p] + bd3[p]) -> out[0:8192]
    gemm_kernel<1, false, false><<<dim3(1, SS / 64, PP), blk, 0, stream>>>(
        d2v, 32, (long long)SS * 32, Wd3, 32, bd3, 1, nullptr, 0, nullptr,
        out, 1, (long long)SS, SS, 1, 32);
    // f1 = relu(hs @ Wf1[p] + bf1[p])
    gemm_kernel<1, false, false><<<dim3(4, SS / 64, PP), blk, 0, stream>>>(
        hs, 64, 0, Wf1, (long long)64 * 256, bf1, 256, nullptr, 0, nullptr,
        f1, 256, (long long)SS * 256, SS, 256, 64);
    // f2 = relu(f1 @ Wf2[p] + bf2[p])
    gemm_kernel<1, false, false><<<dim3(32, SS / 64, PP), blk, 0, stream>>>(
        f1, 256, (long long)SS * 256, Wf2, (long long)256 * 2048, bf2, 2048, nullptr, 0, nullptr,
        f2, 2048, (long long)SS * 2048, SS, 2048, 256);
    // pred_feat = tanh(f2 @ Wf3[p] + bf3[p]) -> out[8192:]
    gemm_kernel<3, false, false><<<dim3(5, SS / 64, PP), blk, 0, stream>>>(
        f2, 2048, (long long)SS * 2048, Wf3, (long long)2048 * 320, bf3, 320, nullptr, 0, nullptr,
        out + (size_t)PP * SS, 320, (long long)SS * 320, SS, 320, 2048);
}

// Round 2
// 1137.873 us; speedup vs baseline: 1.3425x; 1.3425x over previous
//
#include <hip/hip_runtime.h>
#include <math.h>

#define NN 100000
#define RR 4
#define EE 300000
#define PP 2
#define HH 64
#define SS 4096

typedef __attribute__((ext_vector_type(8))) short short8;
typedef __attribute__((ext_vector_type(4))) short short4v;
typedef __attribute__((ext_vector_type(4))) float f32x4;

__device__ __forceinline__ short f2bf(float v) {
    unsigned u = __float_as_uint(v);
    unsigned r = (u + 0x7FFFu + ((u >> 16) & 1u)) >> 16;
    return (short)r;
}
__device__ __forceinline__ float bf2f(short s) {
    return __uint_as_float(((unsigned)(unsigned short)s) << 16);
}

// Wr[r][i][o] = C[r,0]V1[0,i,o] + C[r,1]V1[1,i,o]; emit TRANSPOSED+split: Bt[o][r*64+i]
__global__ void compute_wr_t(const float* __restrict__ C, const float* __restrict__ V,
                             short* __restrict__ hi, short* __restrict__ lo) {
    int idx = blockIdx.x * 256 + threadIdx.x;       // 64*256 = 16384
    if (idx >= HH * RR * HH) return;
    int o = idx >> 8;
    int ri = idx & 255;
    int r = ri >> 6;
    int i = ri & 63;
    float v = C[r * 2] * V[i * 64 + o] + C[r * 2 + 1] * V[4096 + i * 64 + o];
    short h = f2bf(v);
    hi[idx] = h;
    lo[idx] = f2bf(v - bf2f(h));
}

// W[z][K][N] fp32 -> Wt_hi/lo[z][N][K] bf16
__global__ void transpose_split(const float* __restrict__ W, short* __restrict__ hi,
                                short* __restrict__ lo, int K, int N) {
    long long total = (long long)K * N;
    long long idx = (long long)blockIdx.x * 256 + threadIdx.x;
    if (idx >= total) return;
    int n = (int)(idx / K);
    int k = (int)(idx - (long long)n * K);
    float v = W[(long long)blockIdx.y * total + (long long)k * N + n];
    short h = f2bf(v);
    long long o = (long long)blockIdx.y * total + idx;
    hi[o] = h;
    lo[o] = f2bf(v - bf2f(h));
}

__global__ void deg_kernel(const int* __restrict__ edges, float* __restrict__ deg) {
    int idx = blockIdx.x * 256 + threadIdx.x;
    if (idx >= RR * EE) return;
    int r = idx / EE;
    int dst = edges[2 * idx + 1];
    atomicAdd(&deg[dst * RR + r], 1.0f);
}

// agg[dst][r][h] += feat[src][h] — one wave per edge
__global__ void scatter_kernel(const int* __restrict__ edges,
                               const float* __restrict__ feat,
                               float* __restrict__ agg) {
    long long gid = (long long)blockIdx.x * 256 + threadIdx.x;
    int lane = (int)(gid & 63);
    long long e = gid >> 6;
    if (e >= (long long)RR * EE) return;
    int r = (int)(e / EE);
    int src = edges[2 * e];
    int dst = edges[2 * e + 1];
    float v = feat[(long long)src * HH + lane];
    atomicAdd(&agg[((long long)dst * RR + r) * HH + lane], v);
}

__global__ void gather_kernel(const float* __restrict__ h, const int* __restrict__ seeds,
                              float* __restrict__ hs) {
    int idx = blockIdx.x * 256 + threadIdx.x;
    if (idx >= SS * HH) return;
    int s = idx >> 6;
    hs[idx] = h[(long long)seeds[s] * HH + (idx & 63)];
}

// pred_missing = relu(d2 @ Wd3[p] + bd3[p])
__global__ void d3_kernel(const float* __restrict__ d2v, const float* __restrict__ Wd3,
                          const float* __restrict__ bd3, float* __restrict__ out) {
    int idx = blockIdx.x * 256 + threadIdx.x;       // P*S
    if (idx >= PP * SS) return;
    int p = idx >> 12;
    const float* row = d2v + (long long)idx * 32;
    const float* w = Wd3 + p * 32;
    float s = bd3[p];
    #pragma unroll
    for (int k = 0; k < 32; k++) s += row[k] * w[k];
    out[idx] = fmaxf(s, 0.f);
}

// MFMA GEMM: C = ACT(A @ B + bias) [+Dadd], A fp32 [M][K], B pre-split bf16 [N][K].
// Split hi/lo (3 MFMAs) -> fp32-equivalent accuracy.
// Tile 128x64, 4 waves (2x2), wave = 64x32 = 4x2 of 16x16x32 MFMA, BK=32.
// ACT: 0 none, 1 relu, 2 leaky(0.01), 3 tanh. NORM: A(m,k) /= max(deg[m*4+(k>>6)],1).
template <int ACT, bool NORM, bool ADD>
__global__ __launch_bounds__(256) void mfma_gemm(
    const float* __restrict__ A, int lda, long long sA,
    const short* __restrict__ Bhi, const short* __restrict__ Blo, long long sB,
    const float* __restrict__ bias, long long sBias,
    const float* __restrict__ Dadd,
    const float* __restrict__ deg,
    float* __restrict__ Cc, int ldc, long long sC,
    int M, int Nn, int K)
{
    __shared__ short As_hi[128 * 32];
    __shared__ short As_lo[128 * 32];
    __shared__ short Bs_hi[64 * 32];
    __shared__ short Bs_lo[64 * 32];

    int z = blockIdx.z;
    A += (long long)z * sA;
    Bhi += (long long)z * sB;
    Blo += (long long)z * sB;
    const float* bz = bias ? bias + (long long)z * sBias : nullptr;
    Cc += (long long)z * sC;

    int m0 = blockIdx.y * 128;
    int n0 = blockIdx.x * 64;
    int tid = threadIdx.x;
    int lane = tid & 63;
    int w = tid >> 6;
    int wm = w >> 1, wn = w & 1;       // wave rows [wm*64,+64), cols [wn*32,+32)
    int mrow = lane & 15;
    int quad = lane >> 4;

    f32x4 acc[4][2];
    #pragma unroll
    for (int s = 0; s < 4; s++)
        #pragma unroll
        for (int t = 0; t < 2; t++)
            acc[s][t] = (f32x4){0.f, 0.f, 0.f, 0.f};

    for (int k0 = 0; k0 < K; k0 += 32) {
        // ---- stage A (128x32 fp32 -> hi/lo bf16), 1024 float4 over 256 thr x 4
        #pragma unroll
        for (int i = 0; i < 4; i++) {
            int f = tid + i * 256;
            int m = f >> 3, k4 = f & 7;
            int gm = m0 + m;
            f32x4 v = (f32x4){0.f, 0.f, 0.f, 0.f};
            if (gm < M) {
                v = *(const f32x4*)&A[(long long)gm * lda + k0 + k4 * 4];
                if (NORM) {
                    float d = deg[gm * 4 + ((k0 + k4 * 4) >> 6)];
                    v *= (1.0f / fmaxf(d, 1.0f));
                }
            }
            short4v hv, lv;
            #pragma unroll
            for (int c = 0; c < 4; c++) {
                short hh = f2bf(v[c]);
                hv[c] = hh;
                lv[c] = f2bf(v[c] - bf2f(hh));
            }
            *(short4v*)&As_hi[m * 32 + k4 * 4] = hv;
            *(short4v*)&As_lo[m * 32 + k4 * 4] = lv;
        }
        // ---- stage B (64x32 bf16 x2 planes), 16B chunks: tid -> (n = tid>>2, q = tid&3)
        {
            int n = tid >> 2, q = tid & 3;
            int gn = n0 + n;
            short8 bh = (short8)0, bl = (short8)0;
            if (gn < Nn) {
                long long off = (long long)gn * K + k0 + q * 8;
                bh = *(const short8*)&Bhi[off];
                bl = *(const short8*)&Blo[off];
            }
            *(short8*)&Bs_hi[n * 32 + q * 8] = bh;
            *(short8*)&Bs_lo[n * 32 + q * 8] = bl;
        }
        __syncthreads();

        short8 ah[4], al[4], bh[2], bl[2];
        #pragma unroll
        for (int s = 0; s < 4; s++) {
            int off = (wm * 64 + s * 16 + mrow) * 32 + quad * 8;
            ah[s] = *(const short8*)&As_hi[off];
            al[s] = *(const short8*)&As_lo[off];
        }
        #pragma unroll
        for (int t = 0; t < 2; t++) {
            int off = (wn * 32 + t * 16 + mrow) * 32 + quad * 8;
            bh[t] = *(const short8*)&Bs_hi[off];
            bl[t] = *(const short8*)&Bs_lo[off];
        }
        #pragma unroll
        for (int s = 0; s < 4; s++)
            #pragma unroll
            for (int t = 0; t < 2; t++) {
                acc[s][t] = __builtin_amdgcn_mfma_f32_16x16x32_bf16(ah[s], bh[t], acc[s][t], 0, 0, 0);
                acc[s][t] = __builtin_amdgcn_mfma_f32_16x16x32_bf16(ah[s], bl[t], acc[s][t], 0, 0, 0);
                acc[s][t] = __builtin_amdgcn_mfma_f32_16x16x32_bf16(al[s], bh[t], acc[s][t], 0, 0, 0);
            }
        __syncthreads();
    }

    // ---- epilogue: D layout col=lane&15, row=quad*4+reg
    #pragma unroll
    for (int s = 0; s < 4; s++) {
        int gmBase = m0 + wm * 64 + s * 16 + quad * 4;
        #pragma unroll
        for (int t = 0; t < 2; t++) {
            int gn = n0 + wn * 32 + t * 16 + mrow;
            if (gn >= Nn) continue;
            float bb = bz ? bz[gn] : 0.f;
            #pragma unroll
            for (int r = 0; r < 4; r++) {
                int gm = gmBase + r;
                if (gm >= M) continue;
                float v = acc[s][t][r] + bb;
                if (ACT == 1) v = fmaxf(v, 0.f);
                else if (ACT == 2) v = (v > 0.f) ? v : 0.01f * v;
                else if (ACT == 3) v = tanhf(v);
                if (ADD) v += Dadd[(long long)gm * ldc + gn];
                Cc[(long long)gm * ldc + gn] = v;
            }
        }
    }
}

extern "C" void kernel_launch(void* const* d_in, const int* in_sizes, int n_in,
                              void* d_out, int out_size, void* d_ws, size_t ws_size,
                              hipStream_t stream) {
    const float* x    = (const float*)d_in[0];
    const int* edges  = (const int*)d_in[1];
    const int* seeds  = (const int*)d_in[2];
    const float* noise= (const float*)d_in[3];
    const float* V1   = (const float*)d_in[4];
    const float* C1   = (const float*)d_in[5];
    const float* V2   = (const float*)d_in[6];
    const float* C2   = (const float*)d_in[7];
    const float* Wlin = (const float*)d_in[8];
    const float* blin = (const float*)d_in[9];
    const float* Wd1 = (const float*)d_in[10]; const float* bd1 = (const float*)d_in[11];
    const float* Wd2 = (const float*)d_in[12]; const float* bd2 = (const float*)d_in[13];
    const float* Wd3 = (const float*)d_in[14]; const float* bd3 = (const float*)d_in[15];
    const float* Wf1 = (const float*)d_in[16]; const float* bf1 = (const float*)d_in[17];
    const float* Wf2 = (const float*)d_in[18]; const float* bf2 = (const float*)d_in[19];
    const float* Wf3 = (const float*)d_in[20]; const float* bf3 = (const float*)d_in[21];

    float* out = (float*)d_out;

    char* ws = (char*)d_ws;
    size_t off = 0;
    auto allocf = [&](size_t nf) {
        float* p = (float*)(ws + off);
        off += ((nf * 4 + 255) / 256) * 256;
        return p;
    };
    auto allocs = [&](size_t ns) {
        short* p = (short*)(ws + off);
        off += ((ns * 2 + 255) / 256) * 256;
        return p;
    };

    short* Wrt1_hi = allocs(16384);          short* Wrt1_lo = allocs(16384);
    short* Wrt2_hi = allocs(16384);          short* Wrt2_lo = allocs(16384);
    short* Wlint_hi = allocs(4096);          short* Wlint_lo = allocs(4096);
    short* Wd1t_hi = allocs(2 * 64 * 256);   short* Wd1t_lo = allocs(2 * 64 * 256);
    short* Wd2t_hi = allocs(2 * 256 * 32);   short* Wd2t_lo = allocs(2 * 256 * 32);
    short* Wf1t_hi = allocs(2 * 64 * 256);   short* Wf1t_lo = allocs(2 * 64 * 256);
    short* Wf2t_hi = allocs((size_t)2 * 256 * 2048);  short* Wf2t_lo = allocs((size_t)2 * 256 * 2048);
    short* Wf3t_hi = allocs((size_t)2 * 2048 * 320);  short* Wf3t_lo = allocs((size_t)2 * 2048 * 320);

    float* deg = allocf((size_t)NN * RR);
    float* agg = allocf((size_t)NN * RR * HH);   // 102.4 MB; reused for MLP bufs
    float* h1  = allocf((size_t)NN * HH);        // also h3
    float* h2  = allocf((size_t)NN * HH);
    float* hs  = allocf((size_t)SS * HH);

    // MLP intermediates live in agg (dead after combine2):
    float* d1  = agg;                                  // P*S*256
    float* d2v = d1 + (size_t)PP * SS * 256;           // P*S*32
    float* f1  = d2v + (size_t)PP * SS * 32;           // P*S*256
    float* f2  = f1 + (size_t)PP * SS * 256;           // P*S*2048

    hipMemsetAsync(deg, 0, (size_t)NN * RR * 4, stream);
    hipMemsetAsync(agg, 0, (size_t)NN * RR * HH * 4, stream);

    compute_wr_t<<<64, 256, 0, stream>>>(C1, V1, Wrt1_hi, Wrt1_lo);
    compute_wr_t<<<64, 256, 0, stream>>>(C2, V2, Wrt2_hi, Wrt2_lo);

    auto tsp = [&](const float* W, short* hi, short* lo, int Z, int K, int N) {
        long long total = (long long)K * N;
        transpose_split<<<dim3((unsigned)((total + 255) / 256), Z), 256, 0, stream>>>(W, hi, lo, K, N);
    };
    tsp(Wlin, Wlint_hi, Wlint_lo, 1, 64, 64);
    tsp(Wd1, Wd1t_hi, Wd1t_lo, 2, 64, 256);
    tsp(Wd2, Wd2t_hi, Wd2t_lo, 2, 256, 32);
    tsp(Wf1, Wf1t_hi, Wf1t_lo, 2, 64, 256);
    tsp(Wf2, Wf2t_hi, Wf2t_lo, 2, 256, 2048);
    tsp(Wf3, Wf3t_hi, Wf3t_lo, 2, 2048, 320);

    deg_kernel<<<(RR * EE + 255) / 256, 256, 0, stream>>>(edges, deg);

    long long scatter_threads = (long long)RR * EE * 64;
    int scatter_blocks = (int)((scatter_threads + 255) / 256);
    scatter_kernel<<<scatter_blocks, 256, 0, stream>>>(edges, x, agg);

    int MY = (NN + 127) / 128;   // 782
    // combine1: h1 = relu((agg/deg) @ Wr1)
    mfma_gemm<1, true, false><<<dim3(1, MY, 1), 256, 0, stream>>>(
        agg, 256, 0, Wrt1_hi, Wrt1_lo, 0, nullptr, 0, nullptr, deg,
        h1, 64, 0, NN, 64, 256);

    hipMemsetAsync(agg, 0, (size_t)NN * RR * HH * 4, stream);
    scatter_kernel<<<scatter_blocks, 256, 0, stream>>>(edges, h1, agg);

    // combine2 -> h2
    mfma_gemm<1, true, false><<<dim3(1, MY, 1), 256, 0, stream>>>(
        agg, 256, 0, Wrt2_hi, Wrt2_lo, 0, nullptr, 0, nullptr, deg,
        h2, 64, 0, NN, 64, 256);

    // linear: h3 = leaky(h2 @ Wlin + blin) + noise  (h3 reuses h1)
    float* h3 = h1;
    mfma_gemm<2, false, true><<<dim3(1, MY, 1), 256, 0, stream>>>(
        h2, 64, 0, Wlint_hi, Wlint_lo, 0, blin, 0, noise, nullptr,
        h3, 64, 0, NN, 64, 64);

    gather_kernel<<<(SS * HH + 255) / 256, 256, 0, stream>>>(h3, seeds, hs);

    // d1 = leaky(hs @ Wd1[p] + bd1[p])
    mfma_gemm<2, false, false><<<dim3(4, 32, PP), 256, 0, stream>>>(
        hs, 64, 0, Wd1t_hi, Wd1t_lo, (long long)256 * 64, bd1, 256, nullptr, nullptr,
        d1, 256, (long long)SS * 256, SS, 256, 64);
    // d2 = leaky(d1 @ Wd2[p] + bd2[p])
    mfma_gemm<2, false, false><<<dim3(1, 32, PP), 256, 0, stream>>>(
        d1, 256, (long long)SS * 256, Wd2t_hi, Wd2t_lo, (long long)32 * 256, bd2, 32, nullptr, nullptr,
        d2v, 32, (long long)SS * 32, SS, 32, 256);
    // pred_missing -> out[0 : P*S]
    d3_kernel<<<(PP * SS + 255) / 256, 256, 0, stream>>>(d2v, Wd3, bd3, out);

    // f1 = relu(hs @ Wf1[p] + bf1[p])
    mfma_gemm<1, false, false><<<dim3(4, 32, PP), 256, 0, stream>>>(
        hs, 64, 0, Wf1t_hi, Wf1t_lo, (long long)256 * 64, bf1, 256, nullptr, nullptr,
        f1, 256, (long long)SS * 256, SS, 256, 64);
    // f2 = relu(f1 @ Wf2[p] + bf2[p])
    mfma_gemm<1, false, false><<<dim3(32, 32, PP), 256, 0, stream>>>(
        f1, 256, (long long)SS * 256, Wf2t_hi, Wf2t_lo, (long long)2048 * 256, bf2, 2048, nullptr, nullptr,
        f2, 2048, (long long)SS * 2048, SS, 2048, 256);
    // pred_feat = tanh(f2 @ Wf3[p] + bf3[p]) -> out[P*S : ]
    mfma_gemm<3, false, false><<<dim3(5, 32, PP), 256, 0, stream>>>(
        f2, 2048, (long long)SS * 2048, Wf3t_hi, Wf3t_lo, (long long)320 * 2048, bf3, 320, nullptr, nullptr,
        out + (size_t)PP * SS, 320, (long long)SS * 320, SS, 320, 2048);
}

// Round 3
// 971.185 us; speedup vs baseline: 1.5729x; 1.1716x over previous
//
#include <hip/hip_runtime.h>
#include <math.h>

#define NN 100000
#define RR 4
#define EE 300000
#define PP 2
#define HH 64
#define SS 4096
#define NSEG (NN * RR)          // 400000 segments

typedef __attribute__((ext_vector_type(8))) short short8;
typedef __attribute__((ext_vector_type(4))) short short4v;
typedef __attribute__((ext_vector_type(4))) float f32x4;

__device__ __forceinline__ short f2bf(float v) {
    unsigned u = __float_as_uint(v);
    unsigned r = (u + 0x7FFFu + ((u >> 16) & 1u)) >> 16;
    return (short)r;
}
__device__ __forceinline__ float bf2f(short s) {
    return __uint_as_float(((unsigned)(unsigned short)s) << 16);
}

// Wr[r][i][o]; emit TRANSPOSED+split: Bt[o][r*64+i]
__global__ void compute_wr_t(const float* __restrict__ C, const float* __restrict__ V,
                             short* __restrict__ hi, short* __restrict__ lo) {
    int idx = blockIdx.x * 256 + threadIdx.x;       // 64*256 = 16384
    if (idx >= HH * RR * HH) return;
    int o = idx >> 8;
    int ri = idx & 255;
    int r = ri >> 6;
    int i = ri & 63;
    float v = C[r * 2] * V[i * 64 + o] + C[r * 2 + 1] * V[4096 + i * 64 + o];
    short h = f2bf(v);
    hi[idx] = h;
    lo[idx] = f2bf(v - bf2f(h));
}

// W[z][K][N] fp32 -> Wt_hi/lo[z][N][K] bf16
__global__ void transpose_split(const float* __restrict__ W, short* __restrict__ hi,
                                short* __restrict__ lo, int K, int N) {
    long long total = (long long)K * N;
    long long idx = (long long)blockIdx.x * 256 + threadIdx.x;
    if (idx >= total) return;
    int n = (int)(idx / K);
    int k = (int)(idx - (long long)n * K);
    float v = W[(long long)blockIdx.y * total + (long long)k * N + n];
    short h = f2bf(v);
    long long o = (long long)blockIdx.y * total + idx;
    hi[o] = h;
    lo[o] = f2bf(v - bf2f(h));
}

// ---------------- CSR build (once per call; shared by both conv layers) -------------

__global__ void count_kernel(const int* __restrict__ edges, int* __restrict__ counts) {
    int idx = blockIdx.x * 256 + threadIdx.x;
    if (idx >= RR * EE) return;
    int r = idx / EE;
    int dst = edges[2 * idx + 1];
    atomicAdd(&counts[dst * RR + r], 1);
}

// per-block (256-elem) exclusive scan; block totals to bsums
__global__ void scan1(const int* __restrict__ counts, int* __restrict__ excl,
                      int* __restrict__ bsums, int n) {
    __shared__ int tmp[256];
    int tid = threadIdx.x;
    int gid = blockIdx.x * 256 + tid;
    int v = (gid < n) ? counts[gid] : 0;
    tmp[tid] = v;
    __syncthreads();
    #pragma unroll
    for (int off = 1; off < 256; off <<= 1) {
        int y = (tid >= off) ? tmp[tid - off] : 0;
        __syncthreads();
        tmp[tid] += y;
        __syncthreads();
    }
    if (gid < n) excl[gid] = tmp[tid] - v;
    if (tid == 255) bsums[blockIdx.x] = tmp[255];
}

// single-block exclusive scan of bsums (nb up to a few thousand)
__global__ void scan2(int* __restrict__ bsums, int nb) {
    __shared__ int tmp[256];
    __shared__ int carry;
    int tid = threadIdx.x;
    if (tid == 0) carry = 0;
    __syncthreads();
    for (int base = 0; base < nb; base += 256) {
        int i = base + tid;
        int v = (i < nb) ? bsums[i] : 0;
        tmp[tid] = v;
        __syncthreads();
        #pragma unroll
        for (int off = 1; off < 256; off <<= 1) {
            int y = (tid >= off) ? tmp[tid - off] : 0;
            __syncthreads();
            tmp[tid] += y;
            __syncthreads();
        }
        if (i < nb) bsums[i] = tmp[tid] - v + carry;
        __syncthreads();
        if (tid == 0) carry += tmp[255];
        __syncthreads();
    }
}

__global__ void scan3(const int* __restrict__ excl, const int* __restrict__ bsums,
                      int* __restrict__ row_ptr, int* __restrict__ cursor, int n, int total) {
    int gid = blockIdx.x * 256 + threadIdx.x;
    if (gid < n) {
        int v = excl[gid] + bsums[gid >> 8];
        row_ptr[gid] = v;
        cursor[gid] = v;
    }
    if (gid == 0) row_ptr[n] = total;
}

__global__ void fill_csr(const int* __restrict__ edges, int* __restrict__ cursor,
                         int* __restrict__ csr_src) {
    int idx = blockIdx.x * 256 + threadIdx.x;
    if (idx >= RR * EE) return;
    int r = idx / EE;
    int src = edges[2 * idx];
    int dst = edges[2 * idx + 1];
    int pos = atomicAdd(&cursor[dst * RR + r], 1);
    csr_src[pos] = src;
}

// ---------------- gather aggregation: one wave per (dst,r) segment ------------------
// agg[w][lane] = mean over in-edges of feat[src][lane]  (normalized mean, no atomics)
__global__ __launch_bounds__(256) void gather_agg(const int* __restrict__ row_ptr,
                                                  const int* __restrict__ csr_src,
                                                  const float* __restrict__ feat,
                                                  float* __restrict__ agg) {
    long long gid = (long long)blockIdx.x * 256 + threadIdx.x;
    int lane = threadIdx.x & 63;
    long long w = gid >> 6;
    if (w >= (long long)NSEG) return;
    int beg = row_ptr[w];
    int end = row_ptr[w + 1];
    float s = 0.f;
    for (int i = beg; i < end; i++) {
        int src = csr_src[i];
        s += feat[(long long)src * HH + lane];
    }
    int d = end - beg;
    float inv = 1.0f / (float)(d > 1 ? d : 1);
    agg[w * HH + lane] = s * inv;
}

__global__ void gather_kernel(const float* __restrict__ h, const int* __restrict__ seeds,
                              float* __restrict__ hs) {
    int idx = blockIdx.x * 256 + threadIdx.x;
    if (idx >= SS * HH) return;
    int s = idx >> 6;
    hs[idx] = h[(long long)seeds[s] * HH + (idx & 63)];
}

// pred_missing = relu(d2 @ Wd3[p] + bd3[p])
__global__ void d3_kernel(const float* __restrict__ d2v, const float* __restrict__ Wd3,
                          const float* __restrict__ bd3, float* __restrict__ out) {
    int idx = blockIdx.x * 256 + threadIdx.x;       // P*S
    if (idx >= PP * SS) return;
    int p = idx >> 12;
    const float* row = d2v + (long long)idx * 32;
    const float* w = Wd3 + p * 32;
    float s = bd3[p];
    #pragma unroll
    for (int k = 0; k < 32; k++) s += row[k] * w[k];
    out[idx] = fmaxf(s, 0.f);
}

// MFMA GEMM: C = ACT(A @ B + bias) [+Dadd], A fp32 [M][K], B pre-split bf16 [N][K].
// Split hi/lo (3 MFMAs) -> fp32-equivalent accuracy.
// Tile 128x64, 4 waves (2x2), wave = 64x32 = 4x2 of 16x16x32 MFMA, BK=32.
// ACT: 0 none, 1 relu, 2 leaky(0.01), 3 tanh.
template <int ACT, bool ADD>
__global__ __launch_bounds__(256) void mfma_gemm(
    const float* __restrict__ A, int lda, long long sA,
    const short* __restrict__ Bhi, const short* __restrict__ Blo, long long sB,
    const float* __restrict__ bias, long long sBias,
    const float* __restrict__ Dadd,
    float* __restrict__ Cc, int ldc, long long sC,
    int M, int Nn, int K)
{
    __shared__ short As_hi[128 * 32];
    __shared__ short As_lo[128 * 32];
    __shared__ short Bs_hi[64 * 32];
    __shared__ short Bs_lo[64 * 32];

    int z = blockIdx.z;
    A += (long long)z * sA;
    Bhi += (long long)z * sB;
    Blo += (long long)z * sB;
    const float* bz = bias ? bias + (long long)z * sBias : nullptr;
    Cc += (long long)z * sC;

    int m0 = blockIdx.y * 128;
    int n0 = blockIdx.x * 64;
    int tid = threadIdx.x;
    int lane = tid & 63;
    int w = tid >> 6;
    int wm = w >> 1, wn = w & 1;       // wave rows [wm*64,+64), cols [wn*32,+32)
    int mrow = lane & 15;
    int quad = lane >> 4;

    f32x4 acc[4][2];
    #pragma unroll
    for (int s = 0; s < 4; s++)
        #pragma unroll
        for (int t = 0; t < 2; t++)
            acc[s][t] = (f32x4){0.f, 0.f, 0.f, 0.f};

    for (int k0 = 0; k0 < K; k0 += 32) {
        // ---- stage A (128x32 fp32 -> hi/lo bf16)
        #pragma unroll
        for (int i = 0; i < 4; i++) {
            int f = tid + i * 256;
            int m = f >> 3, k4 = f & 7;
            int gm = m0 + m;
            f32x4 v = (f32x4){0.f, 0.f, 0.f, 0.f};
            if (gm < M) {
                v = *(const f32x4*)&A[(long long)gm * lda + k0 + k4 * 4];
            }
            short4v hv, lv;
            #pragma unroll
            for (int c = 0; c < 4; c++) {
                short hh = f2bf(v[c]);
                hv[c] = hh;
                lv[c] = f2bf(v[c] - bf2f(hh));
            }
            *(short4v*)&As_hi[m * 32 + k4 * 4] = hv;
            *(short4v*)&As_lo[m * 32 + k4 * 4] = lv;
        }
        // ---- stage B (64x32 bf16 x2 planes)
        {
            int n = tid >> 2, q = tid & 3;
            int gn = n0 + n;
            short8 bh = (short8)0, bl = (short8)0;
            if (gn < Nn) {
                long long boff = (long long)gn * K + k0 + q * 8;
                bh = *(const short8*)&Bhi[boff];
                bl = *(const short8*)&Blo[boff];
            }
            *(short8*)&Bs_hi[n * 32 + q * 8] = bh;
            *(short8*)&Bs_lo[n * 32 + q * 8] = bl;
        }
        __syncthreads();

        short8 ah[4], al[4], bh[2], bl[2];
        #pragma unroll
        for (int s = 0; s < 4; s++) {
            int soff = (wm * 64 + s * 16 + mrow) * 32 + quad * 8;
            ah[s] = *(const short8*)&As_hi[soff];
            al[s] = *(const short8*)&As_lo[soff];
        }
        #pragma unroll
        for (int t = 0; t < 2; t++) {
            int soff = (wn * 32 + t * 16 + mrow) * 32 + quad * 8;
            bh[t] = *(const short8*)&Bs_hi[soff];
            bl[t] = *(const short8*)&Bs_lo[soff];
        }
        #pragma unroll
        for (int s = 0; s < 4; s++)
            #pragma unroll
            for (int t = 0; t < 2; t++) {
                acc[s][t] = __builtin_amdgcn_mfma_f32_16x16x32_bf16(ah[s], bh[t], acc[s][t], 0, 0, 0);
                acc[s][t] = __builtin_amdgcn_mfma_f32_16x16x32_bf16(ah[s], bl[t], acc[s][t], 0, 0, 0);
                acc[s][t] = __builtin_amdgcn_mfma_f32_16x16x32_bf16(al[s], bh[t], acc[s][t], 0, 0, 0);
            }
        __syncthreads();
    }

    // ---- epilogue: D layout col=lane&15, row=quad*4+reg
    #pragma unroll
    for (int s = 0; s < 4; s++) {
        int gmBase = m0 + wm * 64 + s * 16 + quad * 4;
        #pragma unroll
        for (int t = 0; t < 2; t++) {
            int gn = n0 + wn * 32 + t * 16 + mrow;
            if (gn >= Nn) continue;
            float bb = bz ? bz[gn] : 0.f;
            #pragma unroll
            for (int r = 0; r < 4; r++) {
                int gm = gmBase + r;
                if (gm >= M) continue;
                float v = acc[s][t][r] + bb;
                if (ACT == 1) v = fmaxf(v, 0.f);
                else if (ACT == 2) v = (v > 0.f) ? v : 0.01f * v;
                else if (ACT == 3) v = tanhf(v);
                if (ADD) v += Dadd[(long long)gm * ldc + gn];
                Cc[(long long)gm * ldc + gn] = v;
            }
        }
    }
}

extern "C" void kernel_launch(void* const* d_in, const int* in_sizes, int n_in,
                              void* d_out, int out_size, void* d_ws, size_t ws_size,
                              hipStream_t stream) {
    const float* x    = (const float*)d_in[0];
    const int* edges  = (const int*)d_in[1];
    const int* seeds  = (const int*)d_in[2];
    const float* noise= (const float*)d_in[3];
    const float* V1   = (const float*)d_in[4];
    const float* C1   = (const float*)d_in[5];
    const float* V2   = (const float*)d_in[6];
    const float* C2   = (const float*)d_in[7];
    const float* Wlin = (const float*)d_in[8];
    const float* blin = (const float*)d_in[9];
    const float* Wd1 = (const float*)d_in[10]; const float* bd1 = (const float*)d_in[11];
    const float* Wd2 = (const float*)d_in[12]; const float* bd2 = (const float*)d_in[13];
    const float* Wd3 = (const float*)d_in[14]; const float* bd3 = (const float*)d_in[15];
    const float* Wf1 = (const float*)d_in[16]; const float* bf1 = (const float*)d_in[17];
    const float* Wf2 = (const float*)d_in[18]; const float* bf2 = (const float*)d_in[19];
    const float* Wf3 = (const float*)d_in[20]; const float* bf3 = (const float*)d_in[21];

    float* out = (float*)d_out;

    char* ws = (char*)d_ws;
    size_t off = 0;
    auto allocf = [&](size_t nf) {
        float* p = (float*)(ws + off);
        off += ((nf * 4 + 255) / 256) * 256;
        return p;
    };
    auto allocs = [&](size_t ns) {
        short* p = (short*)(ws + off);
        off += ((ns * 2 + 255) / 256) * 256;
        return p;
    };
    auto alloci = [&](size_t ni) {
        int* p = (int*)(ws + off);
        off += ((ni * 4 + 255) / 256) * 256;
        return p;
    };

    short* Wrt1_hi = allocs(16384);          short* Wrt1_lo = allocs(16384);
    short* Wrt2_hi = allocs(16384);          short* Wrt2_lo = allocs(16384);
    short* Wlint_hi = allocs(4096);          short* Wlint_lo = allocs(4096);
    short* Wd1t_hi = allocs(2 * 64 * 256);   short* Wd1t_lo = allocs(2 * 64 * 256);
    short* Wd2t_hi = allocs(2 * 256 * 32);   short* Wd2t_lo = allocs(2 * 256 * 32);
    short* Wf1t_hi = allocs(2 * 64 * 256);   short* Wf1t_lo = allocs(2 * 64 * 256);
    short* Wf2t_hi = allocs((size_t)2 * 256 * 2048);  short* Wf2t_lo = allocs((size_t)2 * 256 * 2048);
    short* Wf3t_hi = allocs((size_t)2 * 2048 * 320);  short* Wf3t_lo = allocs((size_t)2 * 2048 * 320);

    // CSR
    int* counts  = alloci(NSEG);
    int* excl    = alloci(NSEG);
    int* bsums   = alloci(2048);
    int* row_ptr = alloci(NSEG + 1);
    int* cursor  = alloci(NSEG);
    int* csr_src = alloci((size_t)RR * EE);

    float* agg = allocf((size_t)NN * RR * HH);   // 102.4 MB; reused for MLP bufs
    float* h1  = allocf((size_t)NN * HH);        // also h3
    float* h2  = allocf((size_t)NN * HH);
    float* hs  = allocf((size_t)SS * HH);

    // MLP intermediates live in agg (dead after combine2):
    float* d1  = agg;                                  // P*S*256
    float* d2v = d1 + (size_t)PP * SS * 256;           // P*S*32
    float* f1  = d2v + (size_t)PP * SS * 32;           // P*S*256
    float* f2  = f1 + (size_t)PP * SS * 256;           // P*S*2048

    // ---- weight prep
    compute_wr_t<<<64, 256, 0, stream>>>(C1, V1, Wrt1_hi, Wrt1_lo);
    compute_wr_t<<<64, 256, 0, stream>>>(C2, V2, Wrt2_hi, Wrt2_lo);
    auto tsp = [&](const float* W, short* hi, short* lo, int Z, int K, int N) {
        long long total = (long long)K * N;
        transpose_split<<<dim3((unsigned)((total + 255) / 256), Z), 256, 0, stream>>>(W, hi, lo, K, N);
    };
    tsp(Wlin, Wlint_hi, Wlint_lo, 1, 64, 64);
    tsp(Wd1, Wd1t_hi, Wd1t_lo, 2, 64, 256);
    tsp(Wd2, Wd2t_hi, Wd2t_lo, 2, 256, 32);
    tsp(Wf1, Wf1t_hi, Wf1t_lo, 2, 64, 256);
    tsp(Wf2, Wf2t_hi, Wf2t_lo, 2, 256, 2048);
    tsp(Wf3, Wf3t_hi, Wf3t_lo, 2, 2048, 320);

    // ---- CSR build (once)
    hipMemsetAsync(counts, 0, (size_t)NSEG * 4, stream);
    int eb = (RR * EE + 255) / 256;
    count_kernel<<<eb, 256, 0, stream>>>(edges, counts);
    int nb = (NSEG + 255) / 256;                      // 1563
    scan1<<<nb, 256, 0, stream>>>(counts, excl, bsums, NSEG);
    scan2<<<1, 256, 0, stream>>>(bsums, nb);
    scan3<<<nb, 256, 0, stream>>>(excl, bsums, row_ptr, cursor, NSEG, RR * EE);
    fill_csr<<<eb, 256, 0, stream>>>(edges, cursor, csr_src);

    int gb = (int)(((long long)NSEG * 64 + 255) / 256);   // 100000 blocks

    // ---- layer 1: gather + combine
    gather_agg<<<gb, 256, 0, stream>>>(row_ptr, csr_src, x, agg);
    int MY = (NN + 127) / 128;   // 782
    mfma_gemm<1, false><<<dim3(1, MY, 1), 256, 0, stream>>>(
        agg, 256, 0, Wrt1_hi, Wrt1_lo, 0, nullptr, 0, nullptr,
        h1, 64, 0, NN, 64, 256);

    // ---- layer 2
    gather_agg<<<gb, 256, 0, stream>>>(row_ptr, csr_src, h1, agg);
    mfma_gemm<1, false><<<dim3(1, MY, 1), 256, 0, stream>>>(
        agg, 256, 0, Wrt2_hi, Wrt2_lo, 0, nullptr, 0, nullptr,
        h2, 64, 0, NN, 64, 256);

    // linear: h3 = leaky(h2 @ Wlin + blin) + noise  (h3 reuses h1)
    float* h3 = h1;
    mfma_gemm<2, true><<<dim3(1, MY, 1), 256, 0, stream>>>(
        h2, 64, 0, Wlint_hi, Wlint_lo, 0, blin, 0, noise,
        h3, 64, 0, NN, 64, 64);

    gather_kernel<<<(SS * HH + 255) / 256, 256, 0, stream>>>(h3, seeds, hs);

    // d1 = leaky(hs @ Wd1[p] + bd1[p])
    mfma_gemm<2, false><<<dim3(4, 32, PP), 256, 0, stream>>>(
        hs, 64, 0, Wd1t_hi, Wd1t_lo, (long long)256 * 64, bd1, 256, nullptr,
        d1, 256, (long long)SS * 256, SS, 256, 64);
    // d2 = leaky(d1 @ Wd2[p] + bd2[p])
    mfma_gemm<2, false><<<dim3(1, 32, PP), 256, 0, stream>>>(
        d1, 256, (long long)SS * 256, Wd2t_hi, Wd2t_lo, (long long)32 * 256, bd2, 32, nullptr,
        d2v, 32, (long long)SS * 32, SS, 32, 256);
    // pred_missing -> out[0 : P*S]
    d3_kernel<<<(PP * SS + 255) / 256, 256, 0, stream>>>(d2v, Wd3, bd3, out);

    // f1 = relu(hs @ Wf1[p] + bf1[p])
    mfma_gemm<1, false><<<dim3(4, 32, PP), 256, 0, stream>>>(
        hs, 64, 0, Wf1t_hi, Wf1t_lo, (long long)256 * 64, bf1, 256, nullptr,
        f1, 256, (long long)SS * 256, SS, 256, 64);
    // f2 = relu(f1 @ Wf2[p] + bf2[p])
    mfma_gemm<1, false><<<dim3(32, 32, PP), 256, 0, stream>>>(
        f1, 256, (long long)SS * 256, Wf2t_hi, Wf2t_lo, (long long)2048 * 256, bf2, 2048, nullptr,
        f2, 2048, (long long)SS * 2048, SS, 2048, 256);
    // pred_feat = tanh(f2 @ Wf3[p] + bf3[p]) -> out[P*S : ]
    mfma_gemm<3, false><<<dim3(5, 32, PP), 256, 0, stream>>>(
        f2, 2048, (long long)SS * 2048, Wf3t_hi, Wf3t_lo, (long long)320 * 2048, bf3, 320, nullptr,
        out + (size_t)PP * SS, 320, (long long)SS * 320, SS, 320, 2048);
}

// Round 4
// 822.045 us; speedup vs baseline: 1.8582x; 1.1814x over previous
//
#include <hip/hip_runtime.h>
#include <math.h>

#define NN 100000
#define RR 4
#define EE 300000
#define PP 2
#define HH 64
#define SS 4096
#define NSEG (NN * RR)          // 400000 segments

typedef __attribute__((ext_vector_type(8))) short short8;
typedef __attribute__((ext_vector_type(4))) short short4v;
typedef __attribute__((ext_vector_type(4))) float f32x4;

__device__ __forceinline__ short f2bf(float v) {
    unsigned u = __float_as_uint(v);
    unsigned r = (u + 0x7FFFu + ((u >> 16) & 1u)) >> 16;
    return (short)r;
}
__device__ __forceinline__ float bf2f(short s) {
    return __uint_as_float(((unsigned)(unsigned short)s) << 16);
}
__device__ __forceinline__ float ldval(const float* p) { return *p; }
__device__ __forceinline__ float ldval(const short* p) { return bf2f(*p); }

// Wr[r][i][o]; emit TRANSPOSED+split: Bt[o][r*64+i]
__global__ void compute_wr_t(const float* __restrict__ C, const float* __restrict__ V,
                             short* __restrict__ hi, short* __restrict__ lo) {
    int idx = blockIdx.x * 256 + threadIdx.x;       // 64*256 = 16384
    if (idx >= HH * RR * HH) return;
    int o = idx >> 8;
    int ri = idx & 255;
    int r = ri >> 6;
    int i = ri & 63;
    float v = C[r * 2] * V[i * 64 + o] + C[r * 2 + 1] * V[4096 + i * 64 + o];
    short h = f2bf(v);
    hi[idx] = h;
    lo[idx] = f2bf(v - bf2f(h));
}

// W[z][K][N] fp32 -> Wt_hi/lo[z][N][K] bf16
__global__ void transpose_split(const float* __restrict__ W, short* __restrict__ hi,
                                short* __restrict__ lo, int K, int N) {
    long long total = (long long)K * N;
    long long idx = (long long)blockIdx.x * 256 + threadIdx.x;
    if (idx >= total) return;
    int n = (int)(idx / K);
    int k = (int)(idx - (long long)n * K);
    float v = W[(long long)blockIdx.y * total + (long long)k * N + n];
    short h = f2bf(v);
    long long o = (long long)blockIdx.y * total + idx;
    hi[o] = h;
    lo[o] = f2bf(v - bf2f(h));
}

// ---------------- CSR build ----------------
__global__ void count_kernel(const int* __restrict__ edges, int* __restrict__ counts) {
    int idx = blockIdx.x * 256 + threadIdx.x;
    if (idx >= RR * EE) return;
    int r = idx / EE;
    int dst = edges[2 * idx + 1];
    atomicAdd(&counts[dst * RR + r], 1);
}

__global__ void scan1(const int* __restrict__ counts, int* __restrict__ excl,
                      int* __restrict__ bsums, int n) {
    __shared__ int tmp[256];
    int tid = threadIdx.x;
    int gid = blockIdx.x * 256 + tid;
    int v = (gid < n) ? counts[gid] : 0;
    tmp[tid] = v;
    __syncthreads();
    #pragma unroll
    for (int off = 1; off < 256; off <<= 1) {
        int y = (tid >= off) ? tmp[tid - off] : 0;
        __syncthreads();
        tmp[tid] += y;
        __syncthreads();
    }
    if (gid < n) excl[gid] = tmp[tid] - v;
    if (tid == 255) bsums[blockIdx.x] = tmp[255];
}

__global__ void scan2(int* __restrict__ bsums, int nb) {
    __shared__ int tmp[256];
    __shared__ int carry;
    int tid = threadIdx.x;
    if (tid == 0) carry = 0;
    __syncthreads();
    for (int base = 0; base < nb; base += 256) {
        int i = base + tid;
        int v = (i < nb) ? bsums[i] : 0;
        tmp[tid] = v;
        __syncthreads();
        #pragma unroll
        for (int off = 1; off < 256; off <<= 1) {
            int y = (tid >= off) ? tmp[tid - off] : 0;
            __syncthreads();
            tmp[tid] += y;
            __syncthreads();
        }
        if (i < nb) bsums[i] = tmp[tid] - v + carry;
        __syncthreads();
        if (tid == 0) carry += tmp[255];
        __syncthreads();
    }
}

__global__ void scan3(const int* __restrict__ excl, const int* __restrict__ bsums,
                      int* __restrict__ row_ptr, int* __restrict__ cursor, int n, int total) {
    int gid = blockIdx.x * 256 + threadIdx.x;
    if (gid < n) {
        int v = excl[gid] + bsums[gid >> 8];
        row_ptr[gid] = v;
        cursor[gid] = v;
    }
    if (gid == 0) row_ptr[n] = total;
}

__global__ void fill_csr(const int* __restrict__ edges, int* __restrict__ cursor,
                         int* __restrict__ csr_src) {
    int idx = blockIdx.x * 256 + threadIdx.x;
    if (idx >= RR * EE) return;
    int r = idx / EE;
    int src = edges[2 * idx];
    int dst = edges[2 * idx + 1];
    int pos = atomicAdd(&cursor[dst * RR + r], 1);
    csr_src[pos] = src;
}

// ---------------- gather aggregation -> bf16 agg ----------------
template <typename T>
__global__ __launch_bounds__(256) void gather_agg(const int* __restrict__ row_ptr,
                                                  const int* __restrict__ csr_src,
                                                  const T* __restrict__ feat,
                                                  short* __restrict__ agg) {
    long long gid = (long long)blockIdx.x * 256 + threadIdx.x;
    int lane = threadIdx.x & 63;
    long long w = gid >> 6;
    if (w >= (long long)NSEG) return;
    int beg = row_ptr[w];
    int end = row_ptr[w + 1];
    float s = 0.f;
    for (int i = beg; i < end; i++) {
        int src = csr_src[i];
        s += ldval(&feat[(long long)src * HH + lane]);
    }
    int d = end - beg;
    float inv = 1.0f / (float)(d > 1 ? d : 1);
    agg[w * HH + lane] = f2bf(s * inv);
}

__global__ void gather_kernel(const float* __restrict__ h, const int* __restrict__ seeds,
                              float* __restrict__ hs) {
    int idx = blockIdx.x * 256 + threadIdx.x;
    if (idx >= SS * HH) return;
    int s = idx >> 6;
    hs[idx] = h[(long long)seeds[s] * HH + (idx & 63)];
}

// pred_missing = relu(d2 @ Wd3[p] + bd3[p])
__global__ void d3_kernel(const float* __restrict__ d2v, const float* __restrict__ Wd3,
                          const float* __restrict__ bd3, float* __restrict__ out) {
    int idx = blockIdx.x * 256 + threadIdx.x;       // P*S
    if (idx >= PP * SS) return;
    int p = idx >> 12;
    const float* row = d2v + (long long)idx * 32;
    const float* w = Wd3 + p * 32;
    float s = bd3[p];
    #pragma unroll
    for (int k = 0; k < 32; k++) s += row[k] * w[k];
    out[idx] = fmaxf(s, 0.f);
}

// split-K reduction + bias + tanh for f3
__global__ void reduce_tanh(const float* __restrict__ part, const float* __restrict__ bf3,
                            float* __restrict__ out) {
    int idx = blockIdx.x * 256 + threadIdx.x;
    if (idx >= PP * SS * 320) return;
    int p = idx / (SS * 320);
    int rem = idx - p * (SS * 320);
    int n = rem % 320;
    float s = bf3[p * 320 + n];
    #pragma unroll
    for (int ks = 0; ks < 4; ks++)
        s += part[((long long)(p * 4 + ks)) * SS * 320 + rem];
    out[idx] = tanhf(s);
}

// ================= MFMA GEMM, A = fp32 (in-kernel hi/lo split, 3 MFMAs) =================
// ACT: 0 none, 1 relu, 2 leaky, 3 tanh. OUTBF: write bf16.
template <int ACT, bool ADD, bool OUTBF>
__global__ __launch_bounds__(256) void mfma_gemm(
    const float* __restrict__ A, int lda, long long sA,
    const short* __restrict__ Bhi, const short* __restrict__ Blo, long long sB,
    const float* __restrict__ bias, long long sBias,
    const float* __restrict__ Dadd,
    void* __restrict__ Cc, int ldc, long long sC,
    int M, int Nn, int K)
{
    __shared__ short As_hi[128 * 32];
    __shared__ short As_lo[128 * 32];
    __shared__ short Bs_hi[64 * 32];
    __shared__ short Bs_lo[64 * 32];

    int z = blockIdx.z;
    A += (long long)z * sA;
    Bhi += (long long)z * sB;
    Blo += (long long)z * sB;
    const float* bz = bias ? bias + (long long)z * sBias : nullptr;
    long long cbase = (long long)z * sC;

    int m0 = blockIdx.y * 128;
    int n0 = blockIdx.x * 64;
    int tid = threadIdx.x;
    int lane = tid & 63;
    int w = tid >> 6;
    int wm = w >> 1, wn = w & 1;
    int mrow = lane & 15;
    int quad = lane >> 4;

    f32x4 acc[4][2];
    #pragma unroll
    for (int s = 0; s < 4; s++)
        #pragma unroll
        for (int t = 0; t < 2; t++)
            acc[s][t] = (f32x4){0.f, 0.f, 0.f, 0.f};

    for (int k0 = 0; k0 < K; k0 += 32) {
        #pragma unroll
        for (int i = 0; i < 4; i++) {
            int f = tid + i * 256;
            int m = f >> 3, k4 = f & 7;
            int gm = m0 + m;
            f32x4 v = (f32x4){0.f, 0.f, 0.f, 0.f};
            if (gm < M) v = *(const f32x4*)&A[(long long)gm * lda + k0 + k4 * 4];
            short4v hv, lv;
            #pragma unroll
            for (int c = 0; c < 4; c++) {
                short hh = f2bf(v[c]);
                hv[c] = hh;
                lv[c] = f2bf(v[c] - bf2f(hh));
            }
            *(short4v*)&As_hi[m * 32 + k4 * 4] = hv;
            *(short4v*)&As_lo[m * 32 + k4 * 4] = lv;
        }
        {
            int n = tid >> 2, q = tid & 3;
            int gn = n0 + n;
            short8 bh = (short8)0, bl = (short8)0;
            if (gn < Nn) {
                long long boff = (long long)gn * K + k0 + q * 8;
                bh = *(const short8*)&Bhi[boff];
                bl = *(const short8*)&Blo[boff];
            }
            *(short8*)&Bs_hi[n * 32 + q * 8] = bh;
            *(short8*)&Bs_lo[n * 32 + q * 8] = bl;
        }
        __syncthreads();

        short8 ah[4], al[4], bh[2], bl[2];
        #pragma unroll
        for (int s = 0; s < 4; s++) {
            int soff = (wm * 64 + s * 16 + mrow) * 32 + quad * 8;
            ah[s] = *(const short8*)&As_hi[soff];
            al[s] = *(const short8*)&As_lo[soff];
        }
        #pragma unroll
        for (int t = 0; t < 2; t++) {
            int soff = (wn * 32 + t * 16 + mrow) * 32 + quad * 8;
            bh[t] = *(const short8*)&Bs_hi[soff];
            bl[t] = *(const short8*)&Bs_lo[soff];
        }
        #pragma unroll
        for (int s = 0; s < 4; s++)
            #pragma unroll
            for (int t = 0; t < 2; t++) {
                acc[s][t] = __builtin_amdgcn_mfma_f32_16x16x32_bf16(ah[s], bh[t], acc[s][t], 0, 0, 0);
                acc[s][t] = __builtin_amdgcn_mfma_f32_16x16x32_bf16(ah[s], bl[t], acc[s][t], 0, 0, 0);
                acc[s][t] = __builtin_amdgcn_mfma_f32_16x16x32_bf16(al[s], bh[t], acc[s][t], 0, 0, 0);
            }
        __syncthreads();
    }

    #pragma unroll
    for (int s = 0; s < 4; s++) {
        int gmBase = m0 + wm * 64 + s * 16 + quad * 4;
        #pragma unroll
        for (int t = 0; t < 2; t++) {
            int gn = n0 + wn * 32 + t * 16 + mrow;
            if (gn >= Nn) continue;
            float bb = bz ? bz[gn] : 0.f;
            #pragma unroll
            for (int r = 0; r < 4; r++) {
                int gm = gmBase + r;
                if (gm >= M) continue;
                float v = acc[s][t][r] + bb;
                if (ACT == 1) v = fmaxf(v, 0.f);
                else if (ACT == 2) v = (v > 0.f) ? v : 0.01f * v;
                else if (ACT == 3) v = tanhf(v);
                if (ADD) v += Dadd[(long long)gm * ldc + gn];
                long long co = cbase + (long long)gm * ldc + gn;
                if (OUTBF) ((short*)Cc)[co] = f2bf(v);
                else ((float*)Cc)[co] = v;
            }
        }
    }
}

// ================= MFMA GEMM, A = bf16 single plane (2 MFMAs), optional split-K =========
template <int ACT, bool ADD, bool OUTBF, int KSPLIT>
__global__ __launch_bounds__(256) void mfma_gemm_bfA(
    const short* __restrict__ A, int lda, long long sA,
    const short* __restrict__ Bhi, const short* __restrict__ Blo, long long sB,
    const float* __restrict__ bias, long long sBias,
    const float* __restrict__ Dadd,
    void* __restrict__ Cc, int ldc, long long sC,
    int M, int Nn, int K)
{
    __shared__ short As[128 * 32];
    __shared__ short Bs_hi[64 * 32];
    __shared__ short Bs_lo[64 * 32];

    int z = blockIdx.z;
    int p = z / KSPLIT, ks = z % KSPLIT;
    A += (long long)p * sA;
    Bhi += (long long)p * sB;
    Blo += (long long)p * sB;
    const float* bz = bias ? bias + (long long)p * sBias : nullptr;
    long long cbase = (long long)((KSPLIT > 1) ? z : p) * sC;

    int Kc = K / KSPLIT;
    int kbeg = ks * Kc;

    int m0 = blockIdx.y * 128;
    int n0 = blockIdx.x * 64;
    int tid = threadIdx.x;
    int lane = tid & 63;
    int w = tid >> 6;
    int wm = w >> 1, wn = w & 1;
    int mrow = lane & 15;
    int quad = lane >> 4;

    f32x4 acc[4][2];
    #pragma unroll
    for (int s = 0; s < 4; s++)
        #pragma unroll
        for (int t = 0; t < 2; t++)
            acc[s][t] = (f32x4){0.f, 0.f, 0.f, 0.f};

    for (int k0 = kbeg; k0 < kbeg + Kc; k0 += 32) {
        // A stage: 128x32 bf16, 512 chunks of short8 over 256 thr x 2
        #pragma unroll
        for (int i = 0; i < 2; i++) {
            int f = tid + i * 256;
            int m = f >> 2, q = f & 3;
            int gm = m0 + m;
            short8 av = (short8)0;
            if (gm < M) av = *(const short8*)&A[(long long)gm * lda + k0 + q * 8];
            *(short8*)&As[m * 32 + q * 8] = av;
        }
        {
            int n = tid >> 2, q = tid & 3;
            int gn = n0 + n;
            short8 bh = (short8)0, bl = (short8)0;
            if (gn < Nn) {
                long long boff = (long long)gn * K + k0 + q * 8;
                bh = *(const short8*)&Bhi[boff];
                bl = *(const short8*)&Blo[boff];
            }
            *(short8*)&Bs_hi[n * 32 + q * 8] = bh;
            *(short8*)&Bs_lo[n * 32 + q * 8] = bl;
        }
        __syncthreads();

        short8 ah[4], bh[2], bl[2];
        #pragma unroll
        for (int s = 0; s < 4; s++)
            ah[s] = *(const short8*)&As[(wm * 64 + s * 16 + mrow) * 32 + quad * 8];
        #pragma unroll
        for (int t = 0; t < 2; t++) {
            int soff = (wn * 32 + t * 16 + mrow) * 32 + quad * 8;
            bh[t] = *(const short8*)&Bs_hi[soff];
            bl[t] = *(const short8*)&Bs_lo[soff];
        }
        #pragma unroll
        for (int s = 0; s < 4; s++)
            #pragma unroll
            for (int t = 0; t < 2; t++) {
                acc[s][t] = __builtin_amdgcn_mfma_f32_16x16x32_bf16(ah[s], bh[t], acc[s][t], 0, 0, 0);
                acc[s][t] = __builtin_amdgcn_mfma_f32_16x16x32_bf16(ah[s], bl[t], acc[s][t], 0, 0, 0);
            }
        __syncthreads();
    }

    #pragma unroll
    for (int s = 0; s < 4; s++) {
        int gmBase = m0 + wm * 64 + s * 16 + quad * 4;
        #pragma unroll
        for (int t = 0; t < 2; t++) {
            int gn = n0 + wn * 32 + t * 16 + mrow;
            if (gn >= Nn) continue;
            float bb = bz ? bz[gn] : 0.f;
            #pragma unroll
            for (int r = 0; r < 4; r++) {
                int gm = gmBase + r;
                if (gm >= M) continue;
                float v = acc[s][t][r] + bb;
                if (ACT == 1) v = fmaxf(v, 0.f);
                else if (ACT == 2) v = (v > 0.f) ? v : 0.01f * v;
                else if (ACT == 3) v = tanhf(v);
                if (ADD) v += Dadd[(long long)gm * ldc + gn];
                long long co = cbase + (long long)gm * ldc + gn;
                if (OUTBF) ((short*)Cc)[co] = f2bf(v);
                else ((float*)Cc)[co] = v;
            }
        }
    }
}

extern "C" void kernel_launch(void* const* d_in, const int* in_sizes, int n_in,
                              void* d_out, int out_size, void* d_ws, size_t ws_size,
                              hipStream_t stream) {
    const float* x    = (const float*)d_in[0];
    const int* edges  = (const int*)d_in[1];
    const int* seeds  = (const int*)d_in[2];
    const float* noise= (const float*)d_in[3];
    const float* V1   = (const float*)d_in[4];
    const float* C1   = (const float*)d_in[5];
    const float* V2   = (const float*)d_in[6];
    const float* C2   = (const float*)d_in[7];
    const float* Wlin = (const float*)d_in[8];
    const float* blin = (const float*)d_in[9];
    const float* Wd1 = (const float*)d_in[10]; const float* bd1 = (const float*)d_in[11];
    const float* Wd2 = (const float*)d_in[12]; const float* bd2 = (const float*)d_in[13];
    const float* Wd3 = (const float*)d_in[14]; const float* bd3 = (const float*)d_in[15];
    const float* Wf1 = (const float*)d_in[16]; const float* bf1 = (const float*)d_in[17];
    const float* Wf2 = (const float*)d_in[18]; const float* bf2 = (const float*)d_in[19];
    const float* Wf3 = (const float*)d_in[20]; const float* bf3 = (const float*)d_in[21];

    float* out = (float*)d_out;

    char* ws = (char*)d_ws;
    size_t off = 0;
    auto allocf = [&](size_t nf) {
        float* p = (float*)(ws + off);
        off += ((nf * 4 + 255) / 256) * 256;
        return p;
    };
    auto allocs = [&](size_t ns) {
        short* p = (short*)(ws + off);
        off += ((ns * 2 + 255) / 256) * 256;
        return p;
    };
    auto alloci = [&](size_t ni) {
        int* p = (int*)(ws + off);
        off += ((ni * 4 + 255) / 256) * 256;
        return p;
    };

    short* Wrt1_hi = allocs(16384);          short* Wrt1_lo = allocs(16384);
    short* Wrt2_hi = allocs(16384);          short* Wrt2_lo = allocs(16384);
    short* Wlint_hi = allocs(4096);          short* Wlint_lo = allocs(4096);
    short* Wd1t_hi = allocs(2 * 64 * 256);   short* Wd1t_lo = allocs(2 * 64 * 256);
    short* Wd2t_hi = allocs(2 * 256 * 32);   short* Wd2t_lo = allocs(2 * 256 * 32);
    short* Wf1t_hi = allocs(2 * 64 * 256);   short* Wf1t_lo = allocs(2 * 64 * 256);
    short* Wf2t_hi = allocs((size_t)2 * 256 * 2048);  short* Wf2t_lo = allocs((size_t)2 * 256 * 2048);
    short* Wf3t_hi = allocs((size_t)2 * 2048 * 320);  short* Wf3t_lo = allocs((size_t)2 * 2048 * 320);

    // CSR
    int* counts  = alloci(NSEG);
    int* excl    = alloci(NSEG);
    int* bsums   = alloci(2048);
    int* row_ptr = alloci(NSEG + 1);
    int* cursor  = alloci(NSEG);
    int* csr_src = alloci((size_t)RR * EE);

    short* agg = allocs((size_t)NSEG * HH);      // 51.2 MB; reused as fpart later
    short* h1  = allocs((size_t)NN * HH);        // bf16
    short* h2  = allocs((size_t)NN * HH);        // bf16
    float* h3  = allocf((size_t)NN * HH);        // fp32 (noise precision)
    float* hs  = allocf((size_t)SS * HH);
    float* d1  = allocf((size_t)PP * SS * 256);
    float* d2v = allocf((size_t)PP * SS * 32);
    short* f1  = allocs((size_t)PP * SS * 256);  // bf16
    short* f2b = allocs((size_t)PP * SS * 2048); // bf16

    float* fpart = (float*)agg;                  // 4*2*4096*320*4 = 41.9 MB <= 51.2 MB

    // ---- weight prep
    compute_wr_t<<<64, 256, 0, stream>>>(C1, V1, Wrt1_hi, Wrt1_lo);
    compute_wr_t<<<64, 256, 0, stream>>>(C2, V2, Wrt2_hi, Wrt2_lo);
    auto tsp = [&](const float* W, short* hi, short* lo, int Z, int K, int N) {
        long long total = (long long)K * N;
        transpose_split<<<dim3((unsigned)((total + 255) / 256), Z), 256, 0, stream>>>(W, hi, lo, K, N);
    };
    tsp(Wlin, Wlint_hi, Wlint_lo, 1, 64, 64);
    tsp(Wd1, Wd1t_hi, Wd1t_lo, 2, 64, 256);
    tsp(Wd2, Wd2t_hi, Wd2t_lo, 2, 256, 32);
    tsp(Wf1, Wf1t_hi, Wf1t_lo, 2, 64, 256);
    tsp(Wf2, Wf2t_hi, Wf2t_lo, 2, 256, 2048);
    tsp(Wf3, Wf3t_hi, Wf3t_lo, 2, 2048, 320);

    // ---- CSR build (once)
    hipMemsetAsync(counts, 0, (size_t)NSEG * 4, stream);
    int eb = (RR * EE + 255) / 256;
    count_kernel<<<eb, 256, 0, stream>>>(edges, counts);
    int nb = (NSEG + 255) / 256;                      // 1563
    scan1<<<nb, 256, 0, stream>>>(counts, excl, bsums, NSEG);
    scan2<<<1, 256, 0, stream>>>(bsums, nb);
    scan3<<<nb, 256, 0, stream>>>(excl, bsums, row_ptr, cursor, NSEG, RR * EE);
    fill_csr<<<eb, 256, 0, stream>>>(edges, cursor, csr_src);

    int gb = (int)(((long long)NSEG * 64 + 255) / 256);   // 100000 blocks
    int MY = (NN + 127) / 128;                            // 782

    // ---- layer 1
    gather_agg<float><<<gb, 256, 0, stream>>>(row_ptr, csr_src, x, agg);
    mfma_gemm_bfA<1, false, true, 1><<<dim3(1, MY, 1), 256, 0, stream>>>(
        agg, 256, 0, Wrt1_hi, Wrt1_lo, 0, nullptr, 0, nullptr,
        h1, 64, 0, NN, 64, 256);

    // ---- layer 2
    gather_agg<short><<<gb, 256, 0, stream>>>(row_ptr, csr_src, h1, agg);
    mfma_gemm_bfA<1, false, true, 1><<<dim3(1, MY, 1), 256, 0, stream>>>(
        agg, 256, 0, Wrt2_hi, Wrt2_lo, 0, nullptr, 0, nullptr,
        h2, 64, 0, NN, 64, 256);

    // linear: h3 = leaky(h2 @ Wlin + blin) + noise  (fp32 out)
    mfma_gemm_bfA<2, true, false, 1><<<dim3(1, MY, 1), 256, 0, stream>>>(
        h2, 64, 0, Wlint_hi, Wlint_lo, 0, blin, 0, noise,
        h3, 64, 0, NN, 64, 64);

    gather_kernel<<<(SS * HH + 255) / 256, 256, 0, stream>>>(h3, seeds, hs);

    // d-head (fp32 path, small)
    mfma_gemm<2, false, false><<<dim3(4, 32, PP), 256, 0, stream>>>(
        hs, 64, 0, Wd1t_hi, Wd1t_lo, (long long)256 * 64, bd1, 256, nullptr,
        d1, 256, (long long)SS * 256, SS, 256, 64);
    mfma_gemm<2, false, false><<<dim3(1, 32, PP), 256, 0, stream>>>(
        d1, 256, (long long)SS * 256, Wd2t_hi, Wd2t_lo, (long long)32 * 256, bd2, 32, nullptr,
        d2v, 32, (long long)SS * 32, SS, 32, 256);
    d3_kernel<<<(PP * SS + 255) / 256, 256, 0, stream>>>(d2v, Wd3, bd3, out);

    // f-head
    // f1 = relu(hs @ Wf1 + bf1) -> bf16
    mfma_gemm<1, false, true><<<dim3(4, 32, PP), 256, 0, stream>>>(
        hs, 64, 0, Wf1t_hi, Wf1t_lo, (long long)256 * 64, bf1, 256, nullptr,
        f1, 256, (long long)SS * 256, SS, 256, 64);
    // f2 = relu(f1 @ Wf2 + bf2) -> bf16
    mfma_gemm_bfA<1, false, true, 1><<<dim3(32, 32, PP), 256, 0, stream>>>(
        f1, 256, (long long)SS * 256, Wf2t_hi, Wf2t_lo, (long long)2048 * 256, bf2, 2048, nullptr,
        f2b, 2048, (long long)SS * 2048, SS, 2048, 256);
    // f3 partials: split-K=4, grid (5, 32, PP*4)
    mfma_gemm_bfA<0, false, false, 4><<<dim3(5, 32, PP * 4), 256, 0, stream>>>(
        f2b, 2048, (long long)SS * 2048, Wf3t_hi, Wf3t_lo, (long long)320 * 2048, nullptr, 0, nullptr,
        fpart, 320, (long long)SS * 320, SS, 320, 2048);
    // reduce + bias + tanh -> out[P*S : ]
    reduce_tanh<<<(PP * SS * 320 + 255) / 256, 256, 0, stream>>>(fpart, bf3, out + (size_t)PP * SS);
}

// Round 5
// 702.231 us; speedup vs baseline: 2.1753x; 1.1706x over previous
//
#include <hip/hip_runtime.h>
#include <math.h>

#define NN 100000
#define RR 4
#define EE 300000
#define PP 2
#define HH 64
#define SS 4096
#define NSEG (NN * RR)          // 400000 segments

typedef __attribute__((ext_vector_type(8))) short short8;
typedef __attribute__((ext_vector_type(4))) short short4v;
typedef __attribute__((ext_vector_type(4))) float f32x4;

__device__ __forceinline__ short f2bf(float v) {
    unsigned u = __float_as_uint(v);
    unsigned r = (u + 0x7FFFu + ((u >> 16) & 1u)) >> 16;
    return (short)r;
}
__device__ __forceinline__ float bf2f(short s) {
    return __uint_as_float(((unsigned)(unsigned short)s) << 16);
}

// Wr[r][i][o]; emit TRANSPOSED+split: Bt[o][r*64+i]
__global__ void compute_wr_t(const float* __restrict__ C, const float* __restrict__ V,
                             short* __restrict__ hi, short* __restrict__ lo) {
    int idx = blockIdx.x * 256 + threadIdx.x;       // 64*256 = 16384
    if (idx >= HH * RR * HH) return;
    int o = idx >> 8;
    int ri = idx & 255;
    int r = ri >> 6;
    int i = ri & 63;
    float v = C[r * 2] * V[i * 64 + o] + C[r * 2 + 1] * V[4096 + i * 64 + o];
    short h = f2bf(v);
    hi[idx] = h;
    lo[idx] = f2bf(v - bf2f(h));
}

// W[z][K][N] fp32 -> Wt_hi/lo[z][N][K] bf16
__global__ void transpose_split(const float* __restrict__ W, short* __restrict__ hi,
                                short* __restrict__ lo, int K, int N) {
    long long total = (long long)K * N;
    long long idx = (long long)blockIdx.x * 256 + threadIdx.x;
    if (idx >= total) return;
    int n = (int)(idx / K);
    int k = (int)(idx - (long long)n * K);
    float v = W[(long long)blockIdx.y * total + (long long)k * N + n];
    short h = f2bf(v);
    long long o = (long long)blockIdx.y * total + idx;
    hi[o] = h;
    lo[o] = f2bf(v - bf2f(h));
}

// fp32 -> bf16 (vectorized x4)
__global__ void to_bf16(const float* __restrict__ x, short* __restrict__ xb, int n4) {
    int idx = blockIdx.x * 256 + threadIdx.x;
    if (idx >= n4) return;
    f32x4 v = *(const f32x4*)&x[(long long)idx * 4];
    short4v o;
    #pragma unroll
    for (int c = 0; c < 4; c++) o[c] = f2bf(v[c]);
    *(short4v*)&xb[(long long)idx * 4] = o;
}

// ---------------- CSR build ----------------
__global__ void count_kernel(const int* __restrict__ edges, int* __restrict__ counts) {
    int idx = blockIdx.x * 256 + threadIdx.x;
    if (idx >= RR * EE) return;
    int r = idx / EE;
    int dst = edges[2 * idx + 1];
    atomicAdd(&counts[dst * RR + r], 1);
}

__global__ void scan1(const int* __restrict__ counts, int* __restrict__ excl,
                      int* __restrict__ bsums, int n) {
    __shared__ int tmp[256];
    int tid = threadIdx.x;
    int gid = blockIdx.x * 256 + tid;
    int v = (gid < n) ? counts[gid] : 0;
    tmp[tid] = v;
    __syncthreads();
    #pragma unroll
    for (int off = 1; off < 256; off <<= 1) {
        int y = (tid >= off) ? tmp[tid - off] : 0;
        __syncthreads();
        tmp[tid] += y;
        __syncthreads();
    }
    if (gid < n) excl[gid] = tmp[tid] - v;
    if (tid == 255) bsums[blockIdx.x] = tmp[255];
}

__global__ void scan2(int* __restrict__ bsums, int nb) {
    __shared__ int tmp[256];
    __shared__ int carry;
    int tid = threadIdx.x;
    if (tid == 0) carry = 0;
    __syncthreads();
    for (int base = 0; base < nb; base += 256) {
        int i = base + tid;
        int v = (i < nb) ? bsums[i] : 0;
        tmp[tid] = v;
        __syncthreads();
        #pragma unroll
        for (int off = 1; off < 256; off <<= 1) {
            int y = (tid >= off) ? tmp[tid - off] : 0;
            __syncthreads();
            tmp[tid] += y;
            __syncthreads();
        }
        if (i < nb) bsums[i] = tmp[tid] - v + carry;
        __syncthreads();
        if (tid == 0) carry += tmp[255];
        __syncthreads();
    }
}

__global__ void scan3(const int* __restrict__ excl, const int* __restrict__ bsums,
                      int* __restrict__ row_ptr, int* __restrict__ cursor, int n, int total) {
    int gid = blockIdx.x * 256 + threadIdx.x;
    if (gid < n) {
        int v = excl[gid] + bsums[gid >> 8];
        row_ptr[gid] = v;
        cursor[gid] = v;
    }
    if (gid == 0) row_ptr[n] = total;
}

__global__ void fill_csr(const int* __restrict__ edges, int* __restrict__ cursor,
                         int* __restrict__ csr_src) {
    int idx = blockIdx.x * 256 + threadIdx.x;
    if (idx >= RR * EE) return;
    int r = idx / EE;
    int src = edges[2 * idx];
    int dst = edges[2 * idx + 1];
    int pos = atomicAdd(&cursor[dst * RR + r], 1);
    csr_src[pos] = src;
}

// ---------------- gather aggregation (bf16 feat), MLP-batched ----------------
// One wave per (dst,r) segment. Indices pre-batched so feat loads issue independently.
__global__ __launch_bounds__(256) void gather_agg(const int* __restrict__ row_ptr,
                                                  const int* __restrict__ csr_src,
                                                  const short* __restrict__ feat,
                                                  short* __restrict__ agg) {
    long long gid = (long long)blockIdx.x * 256 + threadIdx.x;
    int lane = threadIdx.x & 63;
    long long w = gid >> 6;
    if (w >= (long long)NSEG) return;
    int beg = row_ptr[w];
    int end = row_ptr[w + 1];
    float s = 0.f;
    int i = beg;
    for (; i + 4 <= end; i += 4) {
        int a = csr_src[i];
        int b = csr_src[i + 1];
        int c = csr_src[i + 2];
        int d = csr_src[i + 3];
        float va = bf2f(feat[(long long)a * HH + lane]);
        float vb = bf2f(feat[(long long)b * HH + lane]);
        float vc = bf2f(feat[(long long)c * HH + lane]);
        float vd = bf2f(feat[(long long)d * HH + lane]);
        s += (va + vb) + (vc + vd);
    }
    int rem = end - i;
    if (rem > 0) {
        int a = csr_src[i];
        int b = csr_src[rem > 1 ? i + 1 : i];
        int c = csr_src[rem > 2 ? i + 2 : i];
        float va = bf2f(feat[(long long)a * HH + lane]);
        float vb = bf2f(feat[(long long)b * HH + lane]);
        float vc = bf2f(feat[(long long)c * HH + lane]);
        s += va;
        s += (rem > 1) ? vb : 0.f;
        s += (rem > 2) ? vc : 0.f;
    }
    int d = end - beg;
    float inv = 1.0f / (float)(d > 1 ? d : 1);
    agg[w * HH + lane] = f2bf(s * inv);
}

__global__ void gather_kernel(const float* __restrict__ h, const int* __restrict__ seeds,
                              float* __restrict__ hs) {
    int idx = blockIdx.x * 256 + threadIdx.x;
    if (idx >= SS * HH) return;
    int s = idx >> 6;
    hs[idx] = h[(long long)seeds[s] * HH + (idx & 63)];
}

// pred_missing = relu(d2 @ Wd3[p] + bd3[p])
__global__ void d3_kernel(const float* __restrict__ d2v, const float* __restrict__ Wd3,
                          const float* __restrict__ bd3, float* __restrict__ out) {
    int idx = blockIdx.x * 256 + threadIdx.x;       // P*S
    if (idx >= PP * SS) return;
    int p = idx >> 12;
    const float* row = d2v + (long long)idx * 32;
    const float* w = Wd3 + p * 32;
    float s = bd3[p];
    #pragma unroll
    for (int k = 0; k < 32; k++) s += row[k] * w[k];
    out[idx] = fmaxf(s, 0.f);
}

// split-K reduction + bias + tanh for f3
__global__ void reduce_tanh(const float* __restrict__ part, const float* __restrict__ bf3,
                            float* __restrict__ out) {
    int idx = blockIdx.x * 256 + threadIdx.x;
    if (idx >= PP * SS * 320) return;
    int p = idx / (SS * 320);
    int rem = idx - p * (SS * 320);
    int n = rem % 320;
    float s = bf3[p * 320 + n];
    #pragma unroll
    for (int ks = 0; ks < 4; ks++)
        s += part[((long long)(p * 4 + ks)) * SS * 320 + rem];
    out[idx] = tanhf(s);
}

// ================= MFMA GEMM, A = fp32 (in-kernel hi/lo split, 3 MFMAs) =================
template <int ACT, bool ADD, bool OUTBF>
__global__ __launch_bounds__(256) void mfma_gemm(
    const float* __restrict__ A, int lda, long long sA,
    const short* __restrict__ Bhi, const short* __restrict__ Blo, long long sB,
    const float* __restrict__ bias, long long sBias,
    const float* __restrict__ Dadd,
    void* __restrict__ Cc, int ldc, long long sC,
    int M, int Nn, int K)
{
    __shared__ short As_hi[128 * 32];
    __shared__ short As_lo[128 * 32];
    __shared__ short Bs_hi[64 * 32];
    __shared__ short Bs_lo[64 * 32];

    int z = blockIdx.z;
    A += (long long)z * sA;
    Bhi += (long long)z * sB;
    Blo += (long long)z * sB;
    const float* bz = bias ? bias + (long long)z * sBias : nullptr;
    long long cbase = (long long)z * sC;

    int m0 = blockIdx.y * 128;
    int n0 = blockIdx.x * 64;
    int tid = threadIdx.x;
    int lane = tid & 63;
    int w = tid >> 6;
    int wm = w >> 1, wn = w & 1;
    int mrow = lane & 15;
    int quad = lane >> 4;

    f32x4 acc[4][2];
    #pragma unroll
    for (int s = 0; s < 4; s++)
        #pragma unroll
        for (int t = 0; t < 2; t++)
            acc[s][t] = (f32x4){0.f, 0.f, 0.f, 0.f};

    for (int k0 = 0; k0 < K; k0 += 32) {
        #pragma unroll
        for (int i = 0; i < 4; i++) {
            int f = tid + i * 256;
            int m = f >> 3, k4 = f & 7;
            int gm = m0 + m;
            f32x4 v = (f32x4){0.f, 0.f, 0.f, 0.f};
            if (gm < M) v = *(const f32x4*)&A[(long long)gm * lda + k0 + k4 * 4];
            short4v hv, lv;
            #pragma unroll
            for (int c = 0; c < 4; c++) {
                short hh = f2bf(v[c]);
                hv[c] = hh;
                lv[c] = f2bf(v[c] - bf2f(hh));
            }
            *(short4v*)&As_hi[m * 32 + k4 * 4] = hv;
            *(short4v*)&As_lo[m * 32 + k4 * 4] = lv;
        }
        {
            int n = tid >> 2, q = tid & 3;
            int gn = n0 + n;
            short8 bh = (short8)0, bl = (short8)0;
            if (gn < Nn) {
                long long boff = (long long)gn * K + k0 + q * 8;
                bh = *(const short8*)&Bhi[boff];
                bl = *(const short8*)&Blo[boff];
            }
            *(short8*)&Bs_hi[n * 32 + q * 8] = bh;
            *(short8*)&Bs_lo[n * 32 + q * 8] = bl;
        }
        __syncthreads();

        short8 ah[4], al[4], bh[2], bl[2];
        #pragma unroll
        for (int s = 0; s < 4; s++) {
            int soff = (wm * 64 + s * 16 + mrow) * 32 + quad * 8;
            ah[s] = *(const short8*)&As_hi[soff];
            al[s] = *(const short8*)&As_lo[soff];
        }
        #pragma unroll
        for (int t = 0; t < 2; t++) {
            int soff = (wn * 32 + t * 16 + mrow) * 32 + quad * 8;
            bh[t] = *(const short8*)&Bs_hi[soff];
            bl[t] = *(const short8*)&Bs_lo[soff];
        }
        #pragma unroll
        for (int s = 0; s < 4; s++)
            #pragma unroll
            for (int t = 0; t < 2; t++) {
                acc[s][t] = __builtin_amdgcn_mfma_f32_16x16x32_bf16(ah[s], bh[t], acc[s][t], 0, 0, 0);
                acc[s][t] = __builtin_amdgcn_mfma_f32_16x16x32_bf16(ah[s], bl[t], acc[s][t], 0, 0, 0);
                acc[s][t] = __builtin_amdgcn_mfma_f32_16x16x32_bf16(al[s], bh[t], acc[s][t], 0, 0, 0);
            }
        __syncthreads();
    }

    #pragma unroll
    for (int s = 0; s < 4; s++) {
        int gmBase = m0 + wm * 64 + s * 16 + quad * 4;
        #pragma unroll
        for (int t = 0; t < 2; t++) {
            int gn = n0 + wn * 32 + t * 16 + mrow;
            if (gn >= Nn) continue;
            float bb = bz ? bz[gn] : 0.f;
            #pragma unroll
            for (int r = 0; r < 4; r++) {
                int gm = gmBase + r;
                if (gm >= M) continue;
                float v = acc[s][t][r] + bb;
                if (ACT == 1) v = fmaxf(v, 0.f);
                else if (ACT == 2) v = (v > 0.f) ? v : 0.01f * v;
                else if (ACT == 3) v = tanhf(v);
                if (ADD) v += Dadd[(long long)gm * ldc + gn];
                long long co = cbase + (long long)gm * ldc + gn;
                if (OUTBF) ((short*)Cc)[co] = f2bf(v);
                else ((float*)Cc)[co] = v;
            }
        }
    }
}

// ================= MFMA GEMM, A = bf16 single plane (2 MFMAs), optional split-K =========
template <int ACT, bool ADD, bool OUTBF, int KSPLIT>
__global__ __launch_bounds__(256) void mfma_gemm_bfA(
    const short* __restrict__ A, int lda, long long sA,
    const short* __restrict__ Bhi, const short* __restrict__ Blo, long long sB,
    const float* __restrict__ bias, long long sBias,
    const float* __restrict__ Dadd,
    void* __restrict__ Cc, int ldc, long long sC,
    int M, int Nn, int K)
{
    __shared__ short As[128 * 32];
    __shared__ short Bs_hi[64 * 32];
    __shared__ short Bs_lo[64 * 32];

    int z = blockIdx.z;
    int p = z / KSPLIT, ks = z % KSPLIT;
    A += (long long)p * sA;
    Bhi += (long long)p * sB;
    Blo += (long long)p * sB;
    const float* bz = bias ? bias + (long long)p * sBias : nullptr;
    long long cbase = (long long)((KSPLIT > 1) ? z : p) * sC;

    int Kc = K / KSPLIT;
    int kbeg = ks * Kc;

    int m0 = blockIdx.y * 128;
    int n0 = blockIdx.x * 64;
    int tid = threadIdx.x;
    int lane = tid & 63;
    int w = tid >> 6;
    int wm = w >> 1, wn = w & 1;
    int mrow = lane & 15;
    int quad = lane >> 4;

    f32x4 acc[4][2];
    #pragma unroll
    for (int s = 0; s < 4; s++)
        #pragma unroll
        for (int t = 0; t < 2; t++)
            acc[s][t] = (f32x4){0.f, 0.f, 0.f, 0.f};

    for (int k0 = kbeg; k0 < kbeg + Kc; k0 += 32) {
        #pragma unroll
        for (int i = 0; i < 2; i++) {
            int f = tid + i * 256;
            int m = f >> 2, q = f & 3;
            int gm = m0 + m;
            short8 av = (short8)0;
            if (gm < M) av = *(const short8*)&A[(long long)gm * lda + k0 + q * 8];
            *(short8*)&As[m * 32 + q * 8] = av;
        }
        {
            int n = tid >> 2, q = tid & 3;
            int gn = n0 + n;
            short8 bh = (short8)0, bl = (short8)0;
            if (gn < Nn) {
                long long boff = (long long)gn * K + k0 + q * 8;
                bh = *(const short8*)&Bhi[boff];
                bl = *(const short8*)&Blo[boff];
            }
            *(short8*)&Bs_hi[n * 32 + q * 8] = bh;
            *(short8*)&Bs_lo[n * 32 + q * 8] = bl;
        }
        __syncthreads();

        short8 ah[4], bh[2], bl[2];
        #pragma unroll
        for (int s = 0; s < 4; s++)
            ah[s] = *(const short8*)&As[(wm * 64 + s * 16 + mrow) * 32 + quad * 8];
        #pragma unroll
        for (int t = 0; t < 2; t++) {
            int soff = (wn * 32 + t * 16 + mrow) * 32 + quad * 8;
            bh[t] = *(const short8*)&Bs_hi[soff];
            bl[t] = *(const short8*)&Bs_lo[soff];
        }
        #pragma unroll
        for (int s = 0; s < 4; s++)
            #pragma unroll
            for (int t = 0; t < 2; t++) {
                acc[s][t] = __builtin_amdgcn_mfma_f32_16x16x32_bf16(ah[s], bh[t], acc[s][t], 0, 0, 0);
                acc[s][t] = __builtin_amdgcn_mfma_f32_16x16x32_bf16(ah[s], bl[t], acc[s][t], 0, 0, 0);
            }
        __syncthreads();
    }

    #pragma unroll
    for (int s = 0; s < 4; s++) {
        int gmBase = m0 + wm * 64 + s * 16 + quad * 4;
        #pragma unroll
        for (int t = 0; t < 2; t++) {
            int gn = n0 + wn * 32 + t * 16 + mrow;
            if (gn >= Nn) continue;
            float bb = bz ? bz[gn] : 0.f;
            #pragma unroll
            for (int r = 0; r < 4; r++) {
                int gm = gmBase + r;
                if (gm >= M) continue;
                float v = acc[s][t][r] + bb;
                if (ACT == 1) v = fmaxf(v, 0.f);
                else if (ACT == 2) v = (v > 0.f) ? v : 0.01f * v;
                else if (ACT == 3) v = tanhf(v);
                if (ADD) v += Dadd[(long long)gm * ldc + gn];
                long long co = cbase + (long long)gm * ldc + gn;
                if (OUTBF) ((short*)Cc)[co] = f2bf(v);
                else ((float*)Cc)[co] = v;
            }
        }
    }
}

extern "C" void kernel_launch(void* const* d_in, const int* in_sizes, int n_in,
                              void* d_out, int out_size, void* d_ws, size_t ws_size,
                              hipStream_t stream) {
    const float* x    = (const float*)d_in[0];
    const int* edges  = (const int*)d_in[1];
    const int* seeds  = (const int*)d_in[2];
    const float* noise= (const float*)d_in[3];
    const float* V1   = (const float*)d_in[4];
    const float* C1   = (const float*)d_in[5];
    const float* V2   = (const float*)d_in[6];
    const float* C2   = (const float*)d_in[7];
    const float* Wlin = (const float*)d_in[8];
    const float* blin = (const float*)d_in[9];
    const float* Wd1 = (const float*)d_in[10]; const float* bd1 = (const float*)d_in[11];
    const float* Wd2 = (const float*)d_in[12]; const float* bd2 = (const float*)d_in[13];
    const float* Wd3 = (const float*)d_in[14]; const float* bd3 = (const float*)d_in[15];
    const float* Wf1 = (const float*)d_in[16]; const float* bf1 = (const float*)d_in[17];
    const float* Wf2 = (const float*)d_in[18]; const float* bf2 = (const float*)d_in[19];
    const float* Wf3 = (const float*)d_in[20]; const float* bf3 = (const float*)d_in[21];

    float* out = (float*)d_out;

    char* ws = (char*)d_ws;
    size_t off = 0;
    auto allocf = [&](size_t nf) {
        float* p = (float*)(ws + off);
        off += ((nf * 4 + 255) / 256) * 256;
        return p;
    };
    auto allocs = [&](size_t ns) {
        short* p = (short*)(ws + off);
        off += ((ns * 2 + 255) / 256) * 256;
        return p;
    };
    auto alloci = [&](size_t ni) {
        int* p = (int*)(ws + off);
        off += ((ni * 4 + 255) / 256) * 256;
        return p;
    };

    short* Wrt1_hi = allocs(16384);          short* Wrt1_lo = allocs(16384);
    short* Wrt2_hi = allocs(16384);          short* Wrt2_lo = allocs(16384);
    short* Wlint_hi = allocs(4096);          short* Wlint_lo = allocs(4096);
    short* Wd1t_hi = allocs(2 * 64 * 256);   short* Wd1t_lo = allocs(2 * 64 * 256);
    short* Wd2t_hi = allocs(2 * 256 * 32);   short* Wd2t_lo = allocs(2 * 256 * 32);
    short* Wf1t_hi = allocs(2 * 64 * 256);   short* Wf1t_lo = allocs(2 * 64 * 256);
    short* Wf2t_hi = allocs((size_t)2 * 256 * 2048);  short* Wf2t_lo = allocs((size_t)2 * 256 * 2048);
    short* Wf3t_hi = allocs((size_t)2 * 2048 * 320);  short* Wf3t_lo = allocs((size_t)2 * 2048 * 320);

    // CSR
    int* counts  = alloci(NSEG);
    int* excl    = alloci(NSEG);
    int* bsums   = alloci(2048);
    int* row_ptr = alloci(NSEG + 1);
    int* cursor  = alloci(NSEG);
    int* csr_src = alloci((size_t)RR * EE);

    short* xb  = allocs((size_t)NN * HH);        // bf16 copy of x
    short* agg = allocs((size_t)NSEG * HH);      // 51.2 MB; reused as fpart later
    short* h1  = allocs((size_t)NN * HH);        // bf16
    short* h2  = allocs((size_t)NN * HH);        // bf16
    float* h3  = allocf((size_t)NN * HH);        // fp32 (noise precision)
    float* hs  = allocf((size_t)SS * HH);
    float* d1  = allocf((size_t)PP * SS * 256);
    float* d2v = allocf((size_t)PP * SS * 32);
    short* f1  = allocs((size_t)PP * SS * 256);  // bf16
    short* f2b = allocs((size_t)PP * SS * 2048); // bf16

    float* fpart = (float*)agg;                  // 4*2*4096*320*4 = 41.9 MB <= 51.2 MB

    // ---- weight prep
    compute_wr_t<<<64, 256, 0, stream>>>(C1, V1, Wrt1_hi, Wrt1_lo);
    compute_wr_t<<<64, 256, 0, stream>>>(C2, V2, Wrt2_hi, Wrt2_lo);
    auto tsp = [&](const float* W, short* hi, short* lo, int Z, int K, int N) {
        long long total = (long long)K * N;
        transpose_split<<<dim3((unsigned)((total + 255) / 256), Z), 256, 0, stream>>>(W, hi, lo, K, N);
    };
    tsp(Wlin, Wlint_hi, Wlint_lo, 1, 64, 64);
    tsp(Wd1, Wd1t_hi, Wd1t_lo, 2, 64, 256);
    tsp(Wd2, Wd2t_hi, Wd2t_lo, 2, 256, 32);
    tsp(Wf1, Wf1t_hi, Wf1t_lo, 2, 64, 256);
    tsp(Wf2, Wf2t_hi, Wf2t_lo, 2, 256, 2048);
    tsp(Wf3, Wf3t_hi, Wf3t_lo, 2, 2048, 320);

    to_bf16<<<(NN * HH / 4 + 255) / 256, 256, 0, stream>>>(x, xb, NN * HH / 4);

    // ---- CSR build (once)
    hipMemsetAsync(counts, 0, (size_t)NSEG * 4, stream);
    int eb = (RR * EE + 255) / 256;
    count_kernel<<<eb, 256, 0, stream>>>(edges, counts);
    int nb = (NSEG + 255) / 256;                      // 1563
    scan1<<<nb, 256, 0, stream>>>(counts, excl, bsums, NSEG);
    scan2<<<1, 256, 0, stream>>>(bsums, nb);
    scan3<<<nb, 256, 0, stream>>>(excl, bsums, row_ptr, cursor, NSEG, RR * EE);
    fill_csr<<<eb, 256, 0, stream>>>(edges, cursor, csr_src);

    int gb = (int)(((long long)NSEG * 64 + 255) / 256);   // 100000 blocks
    int MY = (NN + 127) / 128;                            // 782

    // ---- layer 1
    gather_agg<<<gb, 256, 0, stream>>>(row_ptr, csr_src, xb, agg);
    mfma_gemm_bfA<1, false, true, 1><<<dim3(1, MY, 1), 256, 0, stream>>>(
        agg, 256, 0, Wrt1_hi, Wrt1_lo, 0, nullptr, 0, nullptr,
        h1, 64, 0, NN, 64, 256);

    // ---- layer 2
    gather_agg<<<gb, 256, 0, stream>>>(row_ptr, csr_src, h1, agg);
    mfma_gemm_bfA<1, false, true, 1><<<dim3(1, MY, 1), 256, 0, stream>>>(
        agg, 256, 0, Wrt2_hi, Wrt2_lo, 0, nullptr, 0, nullptr,
        h2, 64, 0, NN, 64, 256);

    // linear: h3 = leaky(h2 @ Wlin + blin) + noise  (fp32 out)
    mfma_gemm_bfA<2, true, false, 1><<<dim3(1, MY, 1), 256, 0, stream>>>(
        h2, 64, 0, Wlint_hi, Wlint_lo, 0, blin, 0, noise,
        h3, 64, 0, NN, 64, 64);

    gather_kernel<<<(SS * HH + 255) / 256, 256, 0, stream>>>(h3, seeds, hs);

    // d-head (fp32 path, small)
    mfma_gemm<2, false, false><<<dim3(4, 32, PP), 256, 0, stream>>>(
        hs, 64, 0, Wd1t_hi, Wd1t_lo, (long long)256 * 64, bd1, 256, nullptr,
        d1, 256, (long long)SS * 256, SS, 256, 64);
    mfma_gemm<2, false, false><<<dim3(1, 32, PP), 256, 0, stream>>>(
        d1, 256, (long long)SS * 256, Wd2t_hi, Wd2t_lo, (long long)32 * 256, bd2, 32, nullptr,
        d2v, 32, (long long)SS * 32, SS, 32, 256);
    d3_kernel<<<(PP * SS + 255) / 256, 256, 0, stream>>>(d2v, Wd3, bd3, out);

    // f-head
    mfma_gemm<1, false, true><<<dim3(4, 32, PP), 256, 0, stream>>>(
        hs, 64, 0, Wf1t_hi, Wf1t_lo, (long long)256 * 64, bf1, 256, nullptr,
        f1, 256, (long long)SS * 256, SS, 256, 64);
    mfma_gemm_bfA<1, false, true, 1><<<dim3(32, 32, PP), 256, 0, stream>>>(
        f1, 256, (long long)SS * 256, Wf2t_hi, Wf2t_lo, (long long)2048 * 256, bf2, 2048, nullptr,
        f2b, 2048, (long long)SS * 2048, SS, 2048, 256);
    mfma_gemm_bfA<0, false, false, 4><<<dim3(5, 32, PP * 4), 256, 0, stream>>>(
        f2b, 2048, (long long)SS * 2048, Wf3t_hi, Wf3t_lo, (long long)320 * 2048, nullptr, 0, nullptr,
        fpart, 320, (long long)SS * 320, SS, 320, 2048);
    reduce_tanh<<<(PP * SS * 320 + 255) / 256, 256, 0, stream>>>(fpart, bf3, out + (size_t)PP * SS);
}

// Round 6
// 690.946 us; speedup vs baseline: 2.2108x; 1.0163x over previous
//
#include <hip/hip_runtime.h>
#include <math.h>

#define NN 100000
#define RR 4
#define EE 300000
#define PP 2
#define HH 64
#define SS 4096
#define NSEG (NN * RR)          // 400000 segments
#define FPART 8
#define PWIDTH ((NN + FPART - 1) / FPART)   // 12500

typedef __attribute__((ext_vector_type(8))) short short8;
typedef __attribute__((ext_vector_type(4))) short short4v;
typedef __attribute__((ext_vector_type(4))) float f32x4;

__device__ __forceinline__ short f2bf(float v) {
    unsigned u = __float_as_uint(v);
    unsigned r = (u + 0x7FFFu + ((u >> 16) & 1u)) >> 16;
    return (short)r;
}
__device__ __forceinline__ float bf2f(short s) {
    return __uint_as_float(((unsigned)(unsigned short)s) << 16);
}

// Wr[r][i][o] for both layers; emit TRANSPOSED+split: Bt[o][r*64+i]
__global__ void compute_wr_t2(const float* __restrict__ C1, const float* __restrict__ V1,
                              short* __restrict__ hi1, short* __restrict__ lo1,
                              const float* __restrict__ C2, const float* __restrict__ V2,
                              short* __restrict__ hi2, short* __restrict__ lo2) {
    int b = blockIdx.x;
    const float* C = (b < 64) ? C1 : C2;
    const float* V = (b < 64) ? V1 : V2;
    short* hi = (b < 64) ? hi1 : hi2;
    short* lo = (b < 64) ? lo1 : lo2;
    int idx = (b & 63) * 256 + threadIdx.x;       // 64*256 = 16384
    int o = idx >> 8;
    int ri = idx & 255;
    int r = ri >> 6;
    int i = ri & 63;
    float v = C[r * 2] * V[i * 64 + o] + C[r * 2 + 1] * V[4096 + i * 64 + o];
    short h = f2bf(v);
    hi[idx] = h;
    lo[idx] = f2bf(v - bf2f(h));
}

// ---- consolidated transpose+split for all dense weights ----
struct PrepPtrs {
    const float *Wlin, *Wd1, *Wd2, *Wf1, *Wf2, *Wf3;
    short *Wlin_hi, *Wlin_lo, *Wd1_hi, *Wd1_lo, *Wd2_hi, *Wd2_lo,
          *Wf1_hi, *Wf1_lo, *Wf2_hi, *Wf2_lo, *Wf3_hi, *Wf3_lo;
};

__device__ __forceinline__ void tsp_one(const float* __restrict__ W, short* __restrict__ hi,
                                        short* __restrict__ lo, int K, int N, int idx) {
    int total = K * N;
    int z = idx / total;
    int rem = idx - z * total;
    int n = rem / K;
    int k = rem - n * K;
    float v = W[(long long)z * total + (long long)k * N + n];
    short h = f2bf(v);
    hi[idx] = h;
    lo[idx] = f2bf(v - bf2f(h));
}

#define T0 4096
#define T1 32768
#define T2 16384
#define T3 32768
#define T4 1048576
#define T5 1310720
#define TSP_TOTAL (T0 + T1 + T2 + T3 + T4 + T5)

__global__ void prep_weights(PrepPtrs pp) {
    int idx = blockIdx.x * 256 + threadIdx.x;
    if (idx >= TSP_TOTAL) return;
    if (idx < T0) { tsp_one(pp.Wlin, pp.Wlin_hi, pp.Wlin_lo, 64, 64, idx); return; }
    idx -= T0;
    if (idx < T1) { tsp_one(pp.Wd1, pp.Wd1_hi, pp.Wd1_lo, 64, 256, idx); return; }
    idx -= T1;
    if (idx < T2) { tsp_one(pp.Wd2, pp.Wd2_hi, pp.Wd2_lo, 256, 32, idx); return; }
    idx -= T2;
    if (idx < T3) { tsp_one(pp.Wf1, pp.Wf1_hi, pp.Wf1_lo, 64, 256, idx); return; }
    idx -= T3;
    if (idx < T4) { tsp_one(pp.Wf2, pp.Wf2_hi, pp.Wf2_lo, 256, 2048, idx); return; }
    idx -= T4;
    tsp_one(pp.Wf3, pp.Wf3_hi, pp.Wf3_lo, 2048, 320, idx);
}

// fp32 -> bf16 (vectorized x4)
__global__ void to_bf16(const float* __restrict__ x, short* __restrict__ xb, int n4) {
    int idx = blockIdx.x * 256 + threadIdx.x;
    if (idx >= n4) return;
    f32x4 v = *(const f32x4*)&x[(long long)idx * 4];
    short4v o;
    #pragma unroll
    for (int c = 0; c < 4; c++) o[c] = f2bf(v[c]);
    *(short4v*)&xb[(long long)idx * 4] = o;
}

// ---------------- CSR build (dst-partitioned for XCD/L2 write locality) ----------------
__global__ void count_kernel(const int* __restrict__ edges, int* __restrict__ counts) {
    int part = blockIdx.x & (FPART - 1);
    int idx = (blockIdx.x >> 3) * 256 + threadIdx.x;
    if (idx >= RR * EE) return;
    int dst = edges[2 * idx + 1];
    int lo = part * PWIDTH;
    if (dst < lo || dst >= lo + PWIDTH) return;
    int r = idx / EE;
    atomicAdd(&counts[dst * RR + r], 1);
}

__global__ void scan1(const int* __restrict__ counts, int* __restrict__ excl,
                      int* __restrict__ bsums, int n) {
    __shared__ int tmp[256];
    int tid = threadIdx.x;
    int gid = blockIdx.x * 256 + tid;
    int v = (gid < n) ? counts[gid] : 0;
    tmp[tid] = v;
    __syncthreads();
    #pragma unroll
    for (int off = 1; off < 256; off <<= 1) {
        int y = (tid >= off) ? tmp[tid - off] : 0;
        __syncthreads();
        tmp[tid] += y;
        __syncthreads();
    }
    if (gid < n) excl[gid] = tmp[tid] - v;
    if (tid == 255) bsums[blockIdx.x] = tmp[255];
}

__global__ void scan2(int* __restrict__ bsums, int nb) {
    __shared__ int tmp[256];
    __shared__ int carry;
    int tid = threadIdx.x;
    if (tid == 0) carry = 0;
    __syncthreads();
    for (int base = 0; base < nb; base += 256) {
        int i = base + tid;
        int v = (i < nb) ? bsums[i] : 0;
        tmp[tid] = v;
        __syncthreads();
        #pragma unroll
        for (int off = 1; off < 256; off <<= 1) {
            int y = (tid >= off) ? tmp[tid - off] : 0;
            __syncthreads();
            tmp[tid] += y;
            __syncthreads();
        }
        if (i < nb) bsums[i] = tmp[tid] - v + carry;
        __syncthreads();
        if (tid == 0) carry += tmp[255];
        __syncthreads();
    }
}

__global__ void scan3(const int* __restrict__ excl, const int* __restrict__ bsums,
                      int* __restrict__ row_ptr, int* __restrict__ cursor, int n, int total) {
    int gid = blockIdx.x * 256 + threadIdx.x;
    if (gid < n) {
        int v = excl[gid] + bsums[gid >> 8];
        row_ptr[gid] = v;
        cursor[gid] = v;
    }
    if (gid == 0) row_ptr[n] = total;
}

__global__ void fill_csr(const int* __restrict__ edges, int* __restrict__ cursor,
                         int* __restrict__ csr_src) {
    int part = blockIdx.x & (FPART - 1);
    int idx = (blockIdx.x >> 3) * 256 + threadIdx.x;
    if (idx >= RR * EE) return;
    int dst = edges[2 * idx + 1];
    int lo = part * PWIDTH;
    if (dst < lo || dst >= lo + PWIDTH) return;
    int r = idx / EE;
    int src = edges[2 * idx];
    int pos = atomicAdd(&cursor[dst * RR + r], 1);
    csr_src[pos] = src;
}

// ---------------- gather aggregation: half-wave pairs, short2 per lane ----------------
// One wave per (dst,r) segment. lane = (half, cl): channel pair 2cl,2cl+1; halves take
// alternate edges; final shfl_xor(32) merges. One 32-lane 4B load covers one edge row,
// both halves issue in one wave inst (256B / inst).
__global__ __launch_bounds__(256) void gather_agg(const int* __restrict__ row_ptr,
                                                  const int* __restrict__ csr_src,
                                                  const short* __restrict__ feat,
                                                  short* __restrict__ agg) {
    long long gid = (long long)blockIdx.x * 256 + threadIdx.x;
    int lane = threadIdx.x & 63;
    long long w = gid >> 6;
    if (w >= (long long)NSEG) return;
    int beg = row_ptr[w];
    int end = row_ptr[w + 1];
    int half = lane >> 5;
    int cl = lane & 31;
    float s0 = 0.f, s1 = 0.f;
    for (int i = beg + half; i < end; i += 2) {
        int src = csr_src[i];
        unsigned v = *(const unsigned*)&feat[(long long)src * HH + cl * 2];
        s0 += __uint_as_float(v << 16);
        s1 += __uint_as_float(v & 0xFFFF0000u);
    }
    s0 += __shfl_xor(s0, 32, 64);
    s1 += __shfl_xor(s1, 32, 64);
    if (half == 0) {
        int d = end - beg;
        float inv = 1.0f / (float)(d > 1 ? d : 1);
        unsigned lo = (unsigned)(unsigned short)f2bf(s0 * inv);
        unsigned hi = (unsigned)(unsigned short)f2bf(s1 * inv);
        *(unsigned*)&agg[w * HH + cl * 2] = lo | (hi << 16);
    }
}

__global__ void gather_kernel(const float* __restrict__ h, const int* __restrict__ seeds,
                              float* __restrict__ hs) {
    int idx = blockIdx.x * 256 + threadIdx.x;
    if (idx >= SS * HH) return;
    int s = idx >> 6;
    hs[idx] = h[(long long)seeds[s] * HH + (idx & 63)];
}

// pred_missing = relu(d2 @ Wd3[p] + bd3[p])
__global__ void d3_kernel(const float* __restrict__ d2v, const float* __restrict__ Wd3,
                          const float* __restrict__ bd3, float* __restrict__ out) {
    int idx = blockIdx.x * 256 + threadIdx.x;       // P*S
    if (idx >= PP * SS) return;
    int p = idx >> 12;
    const float* row = d2v + (long long)idx * 32;
    const float* w = Wd3 + p * 32;
    float s = bd3[p];
    #pragma unroll
    for (int k = 0; k < 32; k++) s += row[k] * w[k];
    out[idx] = fmaxf(s, 0.f);
}

// split-K reduction + bias + tanh for f3
__global__ void reduce_tanh(const float* __restrict__ part, const float* __restrict__ bf3,
                            float* __restrict__ out) {
    int idx = blockIdx.x * 256 + threadIdx.x;
    if (idx >= PP * SS * 320) return;
    int p = idx / (SS * 320);
    int rem = idx - p * (SS * 320);
    int n = rem % 320;
    float s = bf3[p * 320 + n];
    #pragma unroll
    for (int ks = 0; ks < 4; ks++)
        s += part[((long long)(p * 4 + ks)) * SS * 320 + rem];
    out[idx] = tanhf(s);
}

// ================= MFMA GEMM, A = fp32 (in-kernel hi/lo split, 3 MFMAs) =================
template <int ACT, bool ADD, bool OUTBF>
__global__ __launch_bounds__(256) void mfma_gemm(
    const float* __restrict__ A, int lda, long long sA,
    const short* __restrict__ Bhi, const short* __restrict__ Blo, long long sB,
    const float* __restrict__ bias, long long sBias,
    const float* __restrict__ Dadd,
    void* __restrict__ Cc, int ldc, long long sC,
    int M, int Nn, int K)
{
    __shared__ short As_hi[128 * 32];
    __shared__ short As_lo[128 * 32];
    __shared__ short Bs_hi[64 * 32];
    __shared__ short Bs_lo[64 * 32];

    int z = blockIdx.z;
    A += (long long)z * sA;
    Bhi += (long long)z * sB;
    Blo += (long long)z * sB;
    const float* bz = bias ? bias + (long long)z * sBias : nullptr;
    long long cbase = (long long)z * sC;

    int m0 = blockIdx.y * 128;
    int n0 = blockIdx.x * 64;
    int tid = threadIdx.x;
    int lane = tid & 63;
    int w = tid >> 6;
    int wm = w >> 1, wn = w & 1;
    int mrow = lane & 15;
    int quad = lane >> 4;

    f32x4 acc[4][2];
    #pragma unroll
    for (int s = 0; s < 4; s++)
        #pragma unroll
        for (int t = 0; t < 2; t++)
            acc[s][t] = (f32x4){0.f, 0.f, 0.f, 0.f};

    for (int k0 = 0; k0 < K; k0 += 32) {
        #pragma unroll
        for (int i = 0; i < 4; i++) {
            int f = tid + i * 256;
            int m = f >> 3, k4 = f & 7;
            int gm = m0 + m;
            f32x4 v = (f32x4){0.f, 0.f, 0.f, 0.f};
            if (gm < M) v = *(const f32x4*)&A[(long long)gm * lda + k0 + k4 * 4];
            short4v hv, lv;
            #pragma unroll
            for (int c = 0; c < 4; c++) {
                short hh = f2bf(v[c]);
                hv[c] = hh;
                lv[c] = f2bf(v[c] - bf2f(hh));
            }
            *(short4v*)&As_hi[m * 32 + k4 * 4] = hv;
            *(short4v*)&As_lo[m * 32 + k4 * 4] = lv;
        }
        {
            int n = tid >> 2, q = tid & 3;
            int gn = n0 + n;
            short8 bh = (short8)0, bl = (short8)0;
            if (gn < Nn) {
                long long boff = (long long)gn * K + k0 + q * 8;
                bh = *(const short8*)&Bhi[boff];
                bl = *(const short8*)&Blo[boff];
            }
            *(short8*)&Bs_hi[n * 32 + q * 8] = bh;
            *(short8*)&Bs_lo[n * 32 + q * 8] = bl;
        }
        __syncthreads();

        short8 ah[4], al[4], bh[2], bl[2];
        #pragma unroll
        for (int s = 0; s < 4; s++) {
            int soff = (wm * 64 + s * 16 + mrow) * 32 + quad * 8;
            ah[s] = *(const short8*)&As_hi[soff];
            al[s] = *(const short8*)&As_lo[soff];
        }
        #pragma unroll
        for (int t = 0; t < 2; t++) {
            int soff = (wn * 32 + t * 16 + mrow) * 32 + quad * 8;
            bh[t] = *(const short8*)&Bs_hi[soff];
            bl[t] = *(const short8*)&Bs_lo[soff];
        }
        #pragma unroll
        for (int s = 0; s < 4; s++)
            #pragma unroll
            for (int t = 0; t < 2; t++) {
                acc[s][t] = __builtin_amdgcn_mfma_f32_16x16x32_bf16(ah[s], bh[t], acc[s][t], 0, 0, 0);
                acc[s][t] = __builtin_amdgcn_mfma_f32_16x16x32_bf16(ah[s], bl[t], acc[s][t], 0, 0, 0);
                acc[s][t] = __builtin_amdgcn_mfma_f32_16x16x32_bf16(al[s], bh[t], acc[s][t], 0, 0, 0);
            }
        __syncthreads();
    }

    #pragma unroll
    for (int s = 0; s < 4; s++) {
        int gmBase = m0 + wm * 64 + s * 16 + quad * 4;
        #pragma unroll
        for (int t = 0; t < 2; t++) {
            int gn = n0 + wn * 32 + t * 16 + mrow;
            if (gn >= Nn) continue;
            float bb = bz ? bz[gn] : 0.f;
            #pragma unroll
            for (int r = 0; r < 4; r++) {
                int gm = gmBase + r;
                if (gm >= M) continue;
                float v = acc[s][t][r] + bb;
                if (ACT == 1) v = fmaxf(v, 0.f);
                else if (ACT == 2) v = (v > 0.f) ? v : 0.01f * v;
                else if (ACT == 3) v = tanhf(v);
                if (ADD) v += Dadd[(long long)gm * ldc + gn];
                long long co = cbase + (long long)gm * ldc + gn;
                if (OUTBF) ((short*)Cc)[co] = f2bf(v);
                else ((float*)Cc)[co] = v;
            }
        }
    }
}

// ================= MFMA GEMM, A = bf16 single plane (2 MFMAs), optional split-K =========
template <int ACT, bool ADD, bool OUTBF, int KSPLIT>
__global__ __launch_bounds__(256) void mfma_gemm_bfA(
    const short* __restrict__ A, int lda, long long sA,
    const short* __restrict__ Bhi, const short* __restrict__ Blo, long long sB,
    const float* __restrict__ bias, long long sBias,
    const float* __restrict__ Dadd,
    void* __restrict__ Cc, int ldc, long long sC,
    int M, int Nn, int K)
{
    __shared__ short As[128 * 32];
    __shared__ short Bs_hi[64 * 32];
    __shared__ short Bs_lo[64 * 32];

    int z = blockIdx.z;
    int p = z / KSPLIT, ks = z % KSPLIT;
    A += (long long)p * sA;
    Bhi += (long long)p * sB;
    Blo += (long long)p * sB;
    const float* bz = bias ? bias + (long long)p * sBias : nullptr;
    long long cbase = (long long)((KSPLIT > 1) ? z : p) * sC;

    int Kc = K / KSPLIT;
    int kbeg = ks * Kc;

    int m0 = blockIdx.y * 128;
    int n0 = blockIdx.x * 64;
    int tid = threadIdx.x;
    int lane = tid & 63;
    int w = tid >> 6;
    int wm = w >> 1, wn = w & 1;
    int mrow = lane & 15;
    int quad = lane >> 4;

    f32x4 acc[4][2];
    #pragma unroll
    for (int s = 0; s < 4; s++)
        #pragma unroll
        for (int t = 0; t < 2; t++)
            acc[s][t] = (f32x4){0.f, 0.f, 0.f, 0.f};

    for (int k0 = kbeg; k0 < kbeg + Kc; k0 += 32) {
        #pragma unroll
        for (int i = 0; i < 2; i++) {
            int f = tid + i * 256;
            int m = f >> 2, q = f & 3;
            int gm = m0 + m;
            short8 av = (short8)0;
            if (gm < M) av = *(const short8*)&A[(long long)gm * lda + k0 + q * 8];
            *(short8*)&As[m * 32 + q * 8] = av;
        }
        {
            int n = tid >> 2, q = tid & 3;
            int gn = n0 + n;
            short8 bh = (short8)0, bl = (short8)0;
            if (gn < Nn) {
                long long boff = (long long)gn * K + k0 + q * 8;
                bh = *(const short8*)&Bhi[boff];
                bl = *(const short8*)&Blo[boff];
            }
            *(short8*)&Bs_hi[n * 32 + q * 8] = bh;
            *(short8*)&Bs_lo[n * 32 + q * 8] = bl;
        }
        __syncthreads();

        short8 ah[4], bh[2], bl[2];
        #pragma unroll
        for (int s = 0; s < 4; s++)
            ah[s] = *(const short8*)&As[(wm * 64 + s * 16 + mrow) * 32 + quad * 8];
        #pragma unroll
        for (int t = 0; t < 2; t++) {
            int soff = (wn * 32 + t * 16 + mrow) * 32 + quad * 8;
            bh[t] = *(const short8*)&Bs_hi[soff];
            bl[t] = *(const short8*)&Bs_lo[soff];
        }
        #pragma unroll
        for (int s = 0; s < 4; s++)
            #pragma unroll
            for (int t = 0; t < 2; t++) {
                acc[s][t] = __builtin_amdgcn_mfma_f32_16x16x32_bf16(ah[s], bh[t], acc[s][t], 0, 0, 0);
                acc[s][t] = __builtin_amdgcn_mfma_f32_16x16x32_bf16(ah[s], bl[t], acc[s][t], 0, 0, 0);
            }
        __syncthreads();
    }

    #pragma unroll
    for (int s = 0; s < 4; s++) {
        int gmBase = m0 + wm * 64 + s * 16 + quad * 4;
        #pragma unroll
        for (int t = 0; t < 2; t++) {
            int gn = n0 + wn * 32 + t * 16 + mrow;
            if (gn >= Nn) continue;
            float bb = bz ? bz[gn] : 0.f;
            #pragma unroll
            for (int r = 0; r < 4; r++) {
                int gm = gmBase + r;
                if (gm >= M) continue;
                float v = acc[s][t][r] + bb;
                if (ACT == 1) v = fmaxf(v, 0.f);
                else if (ACT == 2) v = (v > 0.f) ? v : 0.01f * v;
                else if (ACT == 3) v = tanhf(v);
                if (ADD) v += Dadd[(long long)gm * ldc + gn];
                long long co = cbase + (long long)gm * ldc + gn;
                if (OUTBF) ((short*)Cc)[co] = f2bf(v);
                else ((float*)Cc)[co] = v;
            }
        }
    }
}

extern "C" void kernel_launch(void* const* d_in, const int* in_sizes, int n_in,
                              void* d_out, int out_size, void* d_ws, size_t ws_size,
                              hipStream_t stream) {
    const float* x    = (const float*)d_in[0];
    const int* edges  = (const int*)d_in[1];
    const int* seeds  = (const int*)d_in[2];
    const float* noise= (const float*)d_in[3];
    const float* V1   = (const float*)d_in[4];
    const float* C1   = (const float*)d_in[5];
    const float* V2   = (const float*)d_in[6];
    const float* C2   = (const float*)d_in[7];
    const float* Wlin = (const float*)d_in[8];
    const float* blin = (const float*)d_in[9];
    const float* Wd1 = (const float*)d_in[10]; const float* bd1 = (const float*)d_in[11];
    const float* Wd2 = (const float*)d_in[12]; const float* bd2 = (const float*)d_in[13];
    const float* Wd3 = (const float*)d_in[14]; const float* bd3 = (const float*)d_in[15];
    const float* Wf1 = (const float*)d_in[16]; const float* bf1 = (const float*)d_in[17];
    const float* Wf2 = (const float*)d_in[18]; const float* bf2 = (const float*)d_in[19];
    const float* Wf3 = (const float*)d_in[20]; const float* bf3 = (const float*)d_in[21];

    float* out = (float*)d_out;

    char* ws = (char*)d_ws;
    size_t off = 0;
    auto allocf = [&](size_t nf) {
        float* p = (float*)(ws + off);
        off += ((nf * 4 + 255) / 256) * 256;
        return p;
    };
    auto allocs = [&](size_t ns) {
        short* p = (short*)(ws + off);
        off += ((ns * 2 + 255) / 256) * 256;
        return p;
    };
    auto alloci = [&](size_t ni) {
        int* p = (int*)(ws + off);
        off += ((ni * 4 + 255) / 256) * 256;
        return p;
    };

    short* Wrt1_hi = allocs(16384);          short* Wrt1_lo = allocs(16384);
    short* Wrt2_hi = allocs(16384);          short* Wrt2_lo = allocs(16384);
    short* Wlint_hi = allocs(4096);          short* Wlint_lo = allocs(4096);
    short* Wd1t_hi = allocs(2 * 64 * 256);   short* Wd1t_lo = allocs(2 * 64 * 256);
    short* Wd2t_hi = allocs(2 * 256 * 32);   short* Wd2t_lo = allocs(2 * 256 * 32);
    short* Wf1t_hi = allocs(2 * 64 * 256);   short* Wf1t_lo = allocs(2 * 64 * 256);
    short* Wf2t_hi = allocs((size_t)2 * 256 * 2048);  short* Wf2t_lo = allocs((size_t)2 * 256 * 2048);
    short* Wf3t_hi = allocs((size_t)2 * 2048 * 320);  short* Wf3t_lo = allocs((size_t)2 * 2048 * 320);

    // CSR
    int* counts  = alloci(NSEG);
    int* excl    = alloci(NSEG);
    int* bsums   = alloci(2048);
    int* row_ptr = alloci(NSEG + 1);
    int* cursor  = alloci(NSEG);
    int* csr_src = alloci((size_t)RR * EE);

    short* xb  = allocs((size_t)NN * HH);        // bf16 copy of x
    short* agg = allocs((size_t)NSEG * HH);      // 51.2 MB; reused as fpart later
    short* h1  = allocs((size_t)NN * HH);        // bf16
    short* h2  = allocs((size_t)NN * HH);        // bf16
    float* h3  = allocf((size_t)NN * HH);        // fp32 (noise precision)
    float* hs  = allocf((size_t)SS * HH);
    float* d1  = allocf((size_t)PP * SS * 256);
    float* d2v = allocf((size_t)PP * SS * 32);
    short* f1  = allocs((size_t)PP * SS * 256);  // bf16
    short* f2b = allocs((size_t)PP * SS * 2048); // bf16

    float* fpart = (float*)agg;                  // 4*2*4096*320*4 = 41.9 MB <= 51.2 MB

    // ---- weight prep (2 launches)
    compute_wr_t2<<<128, 256, 0, stream>>>(C1, V1, Wrt1_hi, Wrt1_lo, C2, V2, Wrt2_hi, Wrt2_lo);
    PrepPtrs pp;
    pp.Wlin = Wlin; pp.Wd1 = Wd1; pp.Wd2 = Wd2; pp.Wf1 = Wf1; pp.Wf2 = Wf2; pp.Wf3 = Wf3;
    pp.Wlin_hi = Wlint_hi; pp.Wlin_lo = Wlint_lo;
    pp.Wd1_hi = Wd1t_hi;   pp.Wd1_lo = Wd1t_lo;
    pp.Wd2_hi = Wd2t_hi;   pp.Wd2_lo = Wd2t_lo;
    pp.Wf1_hi = Wf1t_hi;   pp.Wf1_lo = Wf1t_lo;
    pp.Wf2_hi = Wf2t_hi;   pp.Wf2_lo = Wf2t_lo;
    pp.Wf3_hi = Wf3t_hi;   pp.Wf3_lo = Wf3t_lo;
    prep_weights<<<(TSP_TOTAL + 255) / 256, 256, 0, stream>>>(pp);

    to_bf16<<<(NN * HH / 4 + 255) / 256, 256, 0, stream>>>(x, xb, NN * HH / 4);

    // ---- CSR build (dst-partitioned)
    hipMemsetAsync(counts, 0, (size_t)NSEG * 4, stream);
    int echunks = (RR * EE + 255) / 256;                  // 4688
    int eb = echunks * FPART;                             // 37504 blocks
    count_kernel<<<eb, 256, 0, stream>>>(edges, counts);
    int nb = (NSEG + 255) / 256;                          // 1563
    scan1<<<nb, 256, 0, stream>>>(counts, excl, bsums, NSEG);
    scan2<<<1, 256, 0, stream>>>(bsums, nb);
    scan3<<<nb, 256, 0, stream>>>(excl, bsums, row_ptr, cursor, NSEG, RR * EE);
    fill_csr<<<eb, 256, 0, stream>>>(edges, cursor, csr_src);

    int gb = (int)(((long long)NSEG * 64 + 255) / 256);   // 100000 blocks
    int MY = (NN + 127) / 128;                            // 782

    // ---- layer 1
    gather_agg<<<gb, 256, 0, stream>>>(row_ptr, csr_src, xb, agg);
    mfma_gemm_bfA<1, false, true, 1><<<dim3(1, MY, 1), 256, 0, stream>>>(
        agg, 256, 0, Wrt1_hi, Wrt1_lo, 0, nullptr, 0, nullptr,
        h1, 64, 0, NN, 64, 256);

    // ---- layer 2
    gather_agg<<<gb, 256, 0, stream>>>(row_ptr, csr_src, h1, agg);
    mfma_gemm_bfA<1, false, true, 1><<<dim3(1, MY, 1), 256, 0, stream>>>(
        agg, 256, 0, Wrt2_hi, Wrt2_lo, 0, nullptr, 0, nullptr,
        h2, 64, 0, NN, 64, 256);

    // linear: h3 = leaky(h2 @ Wlin + blin) + noise  (fp32 out)
    mfma_gemm_bfA<2, true, false, 1><<<dim3(1, MY, 1), 256, 0, stream>>>(
        h2, 64, 0, Wlint_hi, Wlint_lo, 0, blin, 0, noise,
        h3, 64, 0, NN, 64, 64);

    gather_kernel<<<(SS * HH + 255) / 256, 256, 0, stream>>>(h3, seeds, hs);

    // d-head (fp32 path, small)
    mfma_gemm<2, false, false><<<dim3(4, 32, PP), 256, 0, stream>>>(
        hs, 64, 0, Wd1t_hi, Wd1t_lo, (long long)256 * 64, bd1, 256, nullptr,
        d1, 256, (long long)SS * 256, SS, 256, 64);
    mfma_gemm<2, false, false><<<dim3(1, 32, PP), 256, 0, stream>>>(
        d1, 256, (long long)SS * 256, Wd2t_hi, Wd2t_lo, (long long)32 * 256, bd2, 32, nullptr,
        d2v, 32, (long long)SS * 32, SS, 32, 256);
    d3_kernel<<<(PP * SS + 255) / 256, 256, 0, stream>>>(d2v, Wd3, bd3, out);

    // f-head
    mfma_gemm<1, false, true><<<dim3(4, 32, PP), 256, 0, stream>>>(
        hs, 64, 0, Wf1t_hi, Wf1t_lo, (long long)256 * 64, bf1, 256, nullptr,
        f1, 256, (long long)SS * 256, SS, 256, 64);
    mfma_gemm_bfA<1, false, true, 1><<<dim3(32, 32, PP), 256, 0, stream>>>(
        f1, 256, (long long)SS * 256, Wf2t_hi, Wf2t_lo, (long long)2048 * 256, bf2, 2048, nullptr,
        f2b, 2048, (long long)SS * 2048, SS, 2048, 256);
    mfma_gemm_bfA<0, false, false, 4><<<dim3(5, 32, PP * 4), 256, 0, stream>>>(
        f2b, 2048, (long long)SS * 2048, Wf3t_hi, Wf3t_lo, (long long)320 * 2048, nullptr, 0, nullptr,
        fpart, 320, (long long)SS * 320, SS, 320, 2048);
    reduce_tanh<<<(PP * SS * 320 + 255) / 256, 256, 0, stream>>>(fpart, bf3, out + (size_t)PP * SS);
}

// Round 7
// 572.267 us; speedup vs baseline: 2.6693x; 1.2074x over previous
//
#include <hip/hip_runtime.h>
#include <math.h>

#define NN 100000
#define RR 4
#define EE 300000
#define PP 2
#define HH 64
#define SS 4096
#define NSEG (NN * RR)          // 400000 segments
#define FPART 8
#define PWIDTH ((NN + FPART - 1) / FPART)   // 12500

typedef __attribute__((ext_vector_type(8))) short short8;
typedef __attribute__((ext_vector_type(4))) short short4v;
typedef __attribute__((ext_vector_type(4))) float f32x4;

__device__ __forceinline__ short f2bf(float v) {
    unsigned u = __float_as_uint(v);
    unsigned r = (u + 0x7FFFu + ((u >> 16) & 1u)) >> 16;
    return (short)r;
}
__device__ __forceinline__ float bf2f(short s) {
    return __uint_as_float(((unsigned)(unsigned short)s) << 16);
}
__device__ __forceinline__ float bflo(unsigned v) { return __uint_as_float(v << 16); }
__device__ __forceinline__ float bfhi(unsigned v) { return __uint_as_float(v & 0xFFFF0000u); }

// Wr[r][i][o] for both layers; emit TRANSPOSED+split: Bt[o][r*64+i]
__global__ void compute_wr_t2(const float* __restrict__ C1, const float* __restrict__ V1,
                              short* __restrict__ hi1, short* __restrict__ lo1,
                              const float* __restrict__ C2, const float* __restrict__ V2,
                              short* __restrict__ hi2, short* __restrict__ lo2) {
    int b = blockIdx.x;
    const float* C = (b < 64) ? C1 : C2;
    const float* V = (b < 64) ? V1 : V2;
    short* hi = (b < 64) ? hi1 : hi2;
    short* lo = (b < 64) ? lo1 : lo2;
    int idx = (b & 63) * 256 + threadIdx.x;       // 64*256 = 16384
    int o = idx >> 8;
    int ri = idx & 255;
    int r = ri >> 6;
    int i = ri & 63;
    float v = C[r * 2] * V[i * 64 + o] + C[r * 2 + 1] * V[4096 + i * 64 + o];
    short h = f2bf(v);
    hi[idx] = h;
    lo[idx] = f2bf(v - bf2f(h));
}

// ---- consolidated transpose+split for all dense weights ----
struct PrepPtrs {
    const float *Wlin, *Wd1, *Wd2, *Wf1, *Wf2, *Wf3;
    short *Wlin_hi, *Wlin_lo, *Wd1_hi, *Wd1_lo, *Wd2_hi, *Wd2_lo,
          *Wf1_hi, *Wf1_lo, *Wf2_hi, *Wf2_lo, *Wf3_hi, *Wf3_lo;
};

__device__ __forceinline__ void tsp_one(const float* __restrict__ W, short* __restrict__ hi,
                                        short* __restrict__ lo, int K, int N, int idx) {
    int total = K * N;
    int z = idx / total;
    int rem = idx - z * total;
    int n = rem / K;
    int k = rem - n * K;
    float v = W[(long long)z * total + (long long)k * N + n];
    short h = f2bf(v);
    hi[idx] = h;
    lo[idx] = f2bf(v - bf2f(h));
}

#define T0 4096
#define T1 32768
#define T2 16384
#define T3 32768
#define T4 1048576
#define T5 1310720
#define TSP_TOTAL (T0 + T1 + T2 + T3 + T4 + T5)

__global__ void prep_weights(PrepPtrs pp) {
    int idx = blockIdx.x * 256 + threadIdx.x;
    if (idx >= TSP_TOTAL) return;
    if (idx < T0) { tsp_one(pp.Wlin, pp.Wlin_hi, pp.Wlin_lo, 64, 64, idx); return; }
    idx -= T0;
    if (idx < T1) { tsp_one(pp.Wd1, pp.Wd1_hi, pp.Wd1_lo, 64, 256, idx); return; }
    idx -= T1;
    if (idx < T2) { tsp_one(pp.Wd2, pp.Wd2_hi, pp.Wd2_lo, 256, 32, idx); return; }
    idx -= T2;
    if (idx < T3) { tsp_one(pp.Wf1, pp.Wf1_hi, pp.Wf1_lo, 64, 256, idx); return; }
    idx -= T3;
    if (idx < T4) { tsp_one(pp.Wf2, pp.Wf2_hi, pp.Wf2_lo, 256, 2048, idx); return; }
    idx -= T4;
    tsp_one(pp.Wf3, pp.Wf3_hi, pp.Wf3_lo, 2048, 320, idx);
}

// fp32 -> bf16 (vectorized x4)
__global__ void to_bf16(const float* __restrict__ x, short* __restrict__ xb, int n4) {
    int idx = blockIdx.x * 256 + threadIdx.x;
    if (idx >= n4) return;
    f32x4 v = *(const f32x4*)&x[(long long)idx * 4];
    short4v o;
    #pragma unroll
    for (int c = 0; c < 4; c++) o[c] = f2bf(v[c]);
    *(short4v*)&xb[(long long)idx * 4] = o;
}

// ---------------- CSR build ----------------
// count: single pass (atomic increments stay in L2; no partial-line store storm)
__global__ void count_kernel(const int* __restrict__ edges, int* __restrict__ counts) {
    int idx = blockIdx.x * 256 + threadIdx.x;
    if (idx >= RR * EE) return;
    int r = idx / EE;
    int dst = edges[2 * idx + 1];
    atomicAdd(&counts[dst * RR + r], 1);
}

__global__ void scan1(const int* __restrict__ counts, int* __restrict__ excl,
                      int* __restrict__ bsums, int n) {
    __shared__ int tmp[256];
    int tid = threadIdx.x;
    int gid = blockIdx.x * 256 + tid;
    int v = (gid < n) ? counts[gid] : 0;
    tmp[tid] = v;
    __syncthreads();
    #pragma unroll
    for (int off = 1; off < 256; off <<= 1) {
        int y = (tid >= off) ? tmp[tid - off] : 0;
        __syncthreads();
        tmp[tid] += y;
        __syncthreads();
    }
    if (gid < n) excl[gid] = tmp[tid] - v;
    if (tid == 255) bsums[blockIdx.x] = tmp[255];
}

__global__ void scan2(int* __restrict__ bsums, int nb) {
    __shared__ int tmp[256];
    __shared__ int carry;
    int tid = threadIdx.x;
    if (tid == 0) carry = 0;
    __syncthreads();
    for (int base = 0; base < nb; base += 256) {
        int i = base + tid;
        int v = (i < nb) ? bsums[i] : 0;
        tmp[tid] = v;
        __syncthreads();
        #pragma unroll
        for (int off = 1; off < 256; off <<= 1) {
            int y = (tid >= off) ? tmp[tid - off] : 0;
            __syncthreads();
            tmp[tid] += y;
            __syncthreads();
        }
        if (i < nb) bsums[i] = tmp[tid] - v + carry;
        __syncthreads();
        if (tid == 0) carry += tmp[255];
        __syncthreads();
    }
}

__global__ void scan3(const int* __restrict__ excl, const int* __restrict__ bsums,
                      int* __restrict__ row_ptr, int* __restrict__ cursor, int n, int total) {
    int gid = blockIdx.x * 256 + threadIdx.x;
    if (gid < n) {
        int v = excl[gid] + bsums[gid >> 8];
        row_ptr[gid] = v;
        cursor[gid] = v;
    }
    if (gid == 0) row_ptr[n] = total;
}

// fill: dst-partitioned so csr_src stores are localized (fixes 17x writeback amplification)
__global__ void fill_csr(const int* __restrict__ edges, int* __restrict__ cursor,
                         int* __restrict__ csr_src) {
    int part = blockIdx.x & (FPART - 1);
    int idx = (blockIdx.x >> 3) * 256 + threadIdx.x;
    if (idx >= RR * EE) return;
    int dst = edges[2 * idx + 1];
    int lo = part * PWIDTH;
    if (dst < lo || dst >= lo + PWIDTH) return;
    int r = idx / EE;
    int src = edges[2 * idx];
    int pos = atomicAdd(&cursor[dst * RR + r], 1);
    csr_src[pos] = src;
}

// ---------------- gather aggregation ----------------
// One segment per 32-lane HALF-WAVE (lane = channel pair, short2), with 4-wide
// independent batched loads for memory-level parallelism. No cross-lane reduce.
__global__ __launch_bounds__(256) void gather_agg(const int* __restrict__ row_ptr,
                                                  const int* __restrict__ csr_src,
                                                  const short* __restrict__ feat,
                                                  short* __restrict__ agg) {
    long long tg = (long long)blockIdx.x * 256 + threadIdx.x;
    long long seg = tg >> 5;
    int cl = threadIdx.x & 31;
    if (seg >= (long long)NSEG) return;
    int beg = row_ptr[seg];
    int end = row_ptr[seg + 1];
    float s0 = 0.f, s1 = 0.f;
    int i = beg;
    for (; i + 4 <= end; i += 4) {
        int a = csr_src[i];
        int b = csr_src[i + 1];
        int c = csr_src[i + 2];
        int d = csr_src[i + 3];
        unsigned va = *(const unsigned*)&feat[a * HH + cl * 2];
        unsigned vb = *(const unsigned*)&feat[b * HH + cl * 2];
        unsigned vc = *(const unsigned*)&feat[c * HH + cl * 2];
        unsigned vd = *(const unsigned*)&feat[d * HH + cl * 2];
        s0 += (bflo(va) + bflo(vb)) + (bflo(vc) + bflo(vd));
        s1 += (bfhi(va) + bfhi(vb)) + (bfhi(vc) + bfhi(vd));
    }
    int rem = end - i;
    if (rem > 0) {
        int a = csr_src[i];
        int b = csr_src[rem > 1 ? i + 1 : i];
        int c = csr_src[rem > 2 ? i + 2 : i];
        unsigned va = *(const unsigned*)&feat[a * HH + cl * 2];
        unsigned vb = *(const unsigned*)&feat[b * HH + cl * 2];
        unsigned vc = *(const unsigned*)&feat[c * HH + cl * 2];
        s0 += bflo(va);
        s1 += bfhi(va);
        s0 += (rem > 1) ? bflo(vb) : 0.f;
        s1 += (rem > 1) ? bfhi(vb) : 0.f;
        s0 += (rem > 2) ? bflo(vc) : 0.f;
        s1 += (rem > 2) ? bfhi(vc) : 0.f;
    }
    int d = end - beg;
    float inv = 1.0f / (float)(d > 1 ? d : 1);
    unsigned plo = (unsigned)(unsigned short)f2bf(s0 * inv);
    unsigned phi = (unsigned)(unsigned short)f2bf(s1 * inv);
    *(unsigned*)&agg[seg * HH + cl * 2] = plo | (phi << 16);
}

__global__ void gather_kernel(const float* __restrict__ h, const int* __restrict__ seeds,
                              float* __restrict__ hs) {
    int idx = blockIdx.x * 256 + threadIdx.x;
    if (idx >= SS * HH) return;
    int s = idx >> 6;
    hs[idx] = h[(long long)seeds[s] * HH + (idx & 63)];
}

// pred_missing = relu(d2 @ Wd3[p] + bd3[p])
__global__ void d3_kernel(const float* __restrict__ d2v, const float* __restrict__ Wd3,
                          const float* __restrict__ bd3, float* __restrict__ out) {
    int idx = blockIdx.x * 256 + threadIdx.x;       // P*S
    if (idx >= PP * SS) return;
    int p = idx >> 12;
    const float* row = d2v + (long long)idx * 32;
    const float* w = Wd3 + p * 32;
    float s = bd3[p];
    #pragma unroll
    for (int k = 0; k < 32; k++) s += row[k] * w[k];
    out[idx] = fmaxf(s, 0.f);
}

// split-K reduction + bias + tanh for f3
__global__ void reduce_tanh(const float* __restrict__ part, const float* __restrict__ bf3,
                            float* __restrict__ out) {
    int idx = blockIdx.x * 256 + threadIdx.x;
    if (idx >= PP * SS * 320) return;
    int p = idx / (SS * 320);
    int rem = idx - p * (SS * 320);
    int n = rem % 320;
    float s = bf3[p * 320 + n];
    #pragma unroll
    for (int ks = 0; ks < 4; ks++)
        s += part[((long long)(p * 4 + ks)) * SS * 320 + rem];
    out[idx] = tanhf(s);
}

// ======== head layer-1 GEMM: d1 and f1 fused (same shape 4096x256, K=64, A=hs fp32) ====
// z = blockIdx.z: head = z>>1 (0=d leaky, 1=f relu), p = z&1. hi/lo A split (3 MFMAs).
__global__ __launch_bounds__(256) void head1_gemm(
    const float* __restrict__ hs,
    const short* __restrict__ Bd_hi, const short* __restrict__ Bd_lo, const float* __restrict__ bd,
    const short* __restrict__ Bf_hi, const short* __restrict__ Bf_lo, const float* __restrict__ bfb,
    short* __restrict__ outd, short* __restrict__ outf)
{
    __shared__ short As_hi[128 * 32];
    __shared__ short As_lo[128 * 32];
    __shared__ short Bs_hi[64 * 32];
    __shared__ short Bs_lo[64 * 32];

    int z = blockIdx.z;
    int head = z >> 1, p = z & 1;
    const short* Bhi = (head ? Bf_hi : Bd_hi) + (long long)p * 256 * 64;
    const short* Blo = (head ? Bf_lo : Bd_lo) + (long long)p * 256 * 64;
    const float* bz = (head ? bfb : bd) + p * 256;
    short* Cc = (head ? outf : outd) + (long long)p * SS * 256;

    int m0 = blockIdx.y * 128;
    int n0 = blockIdx.x * 64;
    int tid = threadIdx.x;
    int lane = tid & 63;
    int w = tid >> 6;
    int wm = w >> 1, wn = w & 1;
    int mrow = lane & 15;
    int quad = lane >> 4;

    f32x4 acc[4][2];
    #pragma unroll
    for (int s = 0; s < 4; s++)
        #pragma unroll
        for (int t = 0; t < 2; t++)
            acc[s][t] = (f32x4){0.f, 0.f, 0.f, 0.f};

    #pragma unroll
    for (int k0 = 0; k0 < 64; k0 += 32) {
        #pragma unroll
        for (int i = 0; i < 4; i++) {
            int f = tid + i * 256;
            int m = f >> 3, k4 = f & 7;
            f32x4 v = *(const f32x4*)&hs[(m0 + m) * 64 + k0 + k4 * 4];
            short4v hv, lv;
            #pragma unroll
            for (int c = 0; c < 4; c++) {
                short hh = f2bf(v[c]);
                hv[c] = hh;
                lv[c] = f2bf(v[c] - bf2f(hh));
            }
            *(short4v*)&As_hi[m * 32 + k4 * 4] = hv;
            *(short4v*)&As_lo[m * 32 + k4 * 4] = lv;
        }
        {
            int n = tid >> 2, q = tid & 3;
            long long boff = (long long)(n0 + n) * 64 + k0 + q * 8;
            *(short8*)&Bs_hi[n * 32 + q * 8] = *(const short8*)&Bhi[boff];
            *(short8*)&Bs_lo[n * 32 + q * 8] = *(const short8*)&Blo[boff];
        }
        __syncthreads();

        short8 ah[4], al[4], bh[2], bl[2];
        #pragma unroll
        for (int s = 0; s < 4; s++) {
            int soff = (wm * 64 + s * 16 + mrow) * 32 + quad * 8;
            ah[s] = *(const short8*)&As_hi[soff];
            al[s] = *(const short8*)&As_lo[soff];
        }
        #pragma unroll
        for (int t = 0; t < 2; t++) {
            int soff = (wn * 32 + t * 16 + mrow) * 32 + quad * 8;
            bh[t] = *(const short8*)&Bs_hi[soff];
            bl[t] = *(const short8*)&Bs_lo[soff];
        }
        #pragma unroll
        for (int s = 0; s < 4; s++)
            #pragma unroll
            for (int t = 0; t < 2; t++) {
                acc[s][t] = __builtin_amdgcn_mfma_f32_16x16x32_bf16(ah[s], bh[t], acc[s][t], 0, 0, 0);
                acc[s][t] = __builtin_amdgcn_mfma_f32_16x16x32_bf16(ah[s], bl[t], acc[s][t], 0, 0, 0);
                acc[s][t] = __builtin_amdgcn_mfma_f32_16x16x32_bf16(al[s], bh[t], acc[s][t], 0, 0, 0);
            }
        __syncthreads();
    }

    #pragma unroll
    for (int s = 0; s < 4; s++) {
        int gmBase = m0 + wm * 64 + s * 16 + quad * 4;
        #pragma unroll
        for (int t = 0; t < 2; t++) {
            int gn = n0 + wn * 32 + t * 16 + mrow;
            float bb = bz[gn];
            #pragma unroll
            for (int r = 0; r < 4; r++) {
                int gm = gmBase + r;
                float v = acc[s][t][r] + bb;
                v = (head == 1) ? fmaxf(v, 0.f) : ((v > 0.f) ? v : 0.01f * v);
                Cc[(long long)gm * 256 + gn] = f2bf(v);
            }
        }
    }
}

// ================= MFMA GEMM, A = bf16 single plane (2 MFMAs), optional split-K =========
template <int ACT, bool ADD, bool OUTBF, int KSPLIT>
__global__ __launch_bounds__(256) void mfma_gemm_bfA(
    const short* __restrict__ A, int lda, long long sA,
    const short* __restrict__ Bhi, const short* __restrict__ Blo, long long sB,
    const float* __restrict__ bias, long long sBias,
    const float* __restrict__ Dadd,
    void* __restrict__ Cc, int ldc, long long sC,
    int M, int Nn, int K)
{
    __shared__ short As[128 * 32];
    __shared__ short Bs_hi[64 * 32];
    __shared__ short Bs_lo[64 * 32];

    int z = blockIdx.z;
    int p = z / KSPLIT, ks = z % KSPLIT;
    A += (long long)p * sA;
    Bhi += (long long)p * sB;
    Blo += (long long)p * sB;
    const float* bz = bias ? bias + (long long)p * sBias : nullptr;
    long long cbase = (long long)((KSPLIT > 1) ? z : p) * sC;

    int Kc = K / KSPLIT;
    int kbeg = ks * Kc;

    int m0 = blockIdx.y * 128;
    int n0 = blockIdx.x * 64;
    int tid = threadIdx.x;
    int lane = tid & 63;
    int w = tid >> 6;
    int wm = w >> 1, wn = w & 1;
    int mrow = lane & 15;
    int quad = lane >> 4;

    f32x4 acc[4][2];
    #pragma unroll
    for (int s = 0; s < 4; s++)
        #pragma unroll
        for (int t = 0; t < 2; t++)
            acc[s][t] = (f32x4){0.f, 0.f, 0.f, 0.f};

    for (int k0 = kbeg; k0 < kbeg + Kc; k0 += 32) {
        #pragma unroll
        for (int i = 0; i < 2; i++) {
            int f = tid + i * 256;
            int m = f >> 2, q = f & 3;
            int gm = m0 + m;
            short8 av = (short8)0;
            if (gm < M) av = *(const short8*)&A[(long long)gm * lda + k0 + q * 8];
            *(short8*)&As[m * 32 + q * 8] = av;
        }
        {
            int n = tid >> 2, q = tid & 3;
            int gn = n0 + n;
            short8 bh = (short8)0, bl = (short8)0;
            if (gn < Nn) {
                long long boff = (long long)gn * K + k0 + q * 8;
                bh = *(const short8*)&Bhi[boff];
                bl = *(const short8*)&Blo[boff];
            }
            *(short8*)&Bs_hi[n * 32 + q * 8] = bh;
            *(short8*)&Bs_lo[n * 32 + q * 8] = bl;
        }
        __syncthreads();

        short8 ah[4], bh[2], bl[2];
        #pragma unroll
        for (int s = 0; s < 4; s++)
            ah[s] = *(const short8*)&As[(wm * 64 + s * 16 + mrow) * 32 + quad * 8];
        #pragma unroll
        for (int t = 0; t < 2; t++) {
            int soff = (wn * 32 + t * 16 + mrow) * 32 + quad * 8;
            bh[t] = *(const short8*)&Bs_hi[soff];
            bl[t] = *(const short8*)&Bs_lo[soff];
        }
        #pragma unroll
        for (int s = 0; s < 4; s++)
            #pragma unroll
            for (int t = 0; t < 2; t++) {
                acc[s][t] = __builtin_amdgcn_mfma_f32_16x16x32_bf16(ah[s], bh[t], acc[s][t], 0, 0, 0);
                acc[s][t] = __builtin_amdgcn_mfma_f32_16x16x32_bf16(ah[s], bl[t], acc[s][t], 0, 0, 0);
            }
        __syncthreads();
    }

    #pragma unroll
    for (int s = 0; s < 4; s++) {
        int gmBase = m0 + wm * 64 + s * 16 + quad * 4;
        #pragma unroll
        for (int t = 0; t < 2; t++) {
            int gn = n0 + wn * 32 + t * 16 + mrow;
            if (gn >= Nn) continue;
            float bb = bz ? bz[gn] : 0.f;
            #pragma unroll
            for (int r = 0; r < 4; r++) {
                int gm = gmBase + r;
                if (gm >= M) continue;
                float v = acc[s][t][r] + bb;
                if (ACT == 1) v = fmaxf(v, 0.f);
                else if (ACT == 2) v = (v > 0.f) ? v : 0.01f * v;
                else if (ACT == 3) v = tanhf(v);
                if (ADD) v += Dadd[(long long)gm * ldc + gn];
                long long co = cbase + (long long)gm * ldc + gn;
                if (OUTBF) ((short*)Cc)[co] = f2bf(v);
                else ((float*)Cc)[co] = v;
            }
        }
    }
}

extern "C" void kernel_launch(void* const* d_in, const int* in_sizes, int n_in,
                              void* d_out, int out_size, void* d_ws, size_t ws_size,
                              hipStream_t stream) {
    const float* x    = (const float*)d_in[0];
    const int* edges  = (const int*)d_in[1];
    const int* seeds  = (const int*)d_in[2];
    const float* noise= (const float*)d_in[3];
    const float* V1   = (const float*)d_in[4];
    const float* C1   = (const float*)d_in[5];
    const float* V2   = (const float*)d_in[6];
    const float* C2   = (const float*)d_in[7];
    const float* Wlin = (const float*)d_in[8];
    const float* blin = (const float*)d_in[9];
    const float* Wd1 = (const float*)d_in[10]; const float* bd1 = (const float*)d_in[11];
    const float* Wd2 = (const float*)d_in[12]; const float* bd2 = (const float*)d_in[13];
    const float* Wd3 = (const float*)d_in[14]; const float* bd3 = (const float*)d_in[15];
    const float* Wf1 = (const float*)d_in[16]; const float* bf1 = (const float*)d_in[17];
    const float* Wf2 = (const float*)d_in[18]; const float* bf2 = (const float*)d_in[19];
    const float* Wf3 = (const float*)d_in[20]; const float* bf3 = (const float*)d_in[21];

    float* out = (float*)d_out;

    char* ws = (char*)d_ws;
    size_t off = 0;
    auto allocf = [&](size_t nf) {
        float* p = (float*)(ws + off);
        off += ((nf * 4 + 255) / 256) * 256;
        return p;
    };
    auto allocs = [&](size_t ns) {
        short* p = (short*)(ws + off);
        off += ((ns * 2 + 255) / 256) * 256;
        return p;
    };
    auto alloci = [&](size_t ni) {
        int* p = (int*)(ws + off);
        off += ((ni * 4 + 255) / 256) * 256;
        return p;
    };

    short* Wrt1_hi = allocs(16384);          short* Wrt1_lo = allocs(16384);
    short* Wrt2_hi = allocs(16384);          short* Wrt2_lo = allocs(16384);
    short* Wlint_hi = allocs(4096);          short* Wlint_lo = allocs(4096);
    short* Wd1t_hi = allocs(2 * 64 * 256);   short* Wd1t_lo = allocs(2 * 64 * 256);
    short* Wd2t_hi = allocs(2 * 256 * 32);   short* Wd2t_lo = allocs(2 * 256 * 32);
    short* Wf1t_hi = allocs(2 * 64 * 256);   short* Wf1t_lo = allocs(2 * 64 * 256);
    short* Wf2t_hi = allocs((size_t)2 * 256 * 2048);  short* Wf2t_lo = allocs((size_t)2 * 256 * 2048);
    short* Wf3t_hi = allocs((size_t)2 * 2048 * 320);  short* Wf3t_lo = allocs((size_t)2 * 2048 * 320);

    // CSR
    int* counts  = alloci(NSEG);
    int* excl    = alloci(NSEG);
    int* bsums   = alloci(2048);
    int* row_ptr = alloci(NSEG + 1);
    int* cursor  = alloci(NSEG);
    int* csr_src = alloci((size_t)RR * EE);

    short* xb  = allocs((size_t)NN * HH);        // bf16 copy of x
    short* agg = allocs((size_t)NSEG * HH);      // 51.2 MB; reused as fpart later
    short* h1  = allocs((size_t)NN * HH);        // bf16
    short* h2  = allocs((size_t)NN * HH);        // bf16
    float* h3  = allocf((size_t)NN * HH);        // fp32 (noise precision)
    float* hs  = allocf((size_t)SS * HH);
    short* d1b = allocs((size_t)PP * SS * 256);  // bf16
    float* d2v = allocf((size_t)PP * SS * 32);
    short* f1  = allocs((size_t)PP * SS * 256);  // bf16
    short* f2b = allocs((size_t)PP * SS * 2048); // bf16

    float* fpart = (float*)agg;                  // 4*2*4096*320*4 = 41.9 MB <= 51.2 MB

    // ---- weight prep (2 launches)
    compute_wr_t2<<<128, 256, 0, stream>>>(C1, V1, Wrt1_hi, Wrt1_lo, C2, V2, Wrt2_hi, Wrt2_lo);
    PrepPtrs pp;
    pp.Wlin = Wlin; pp.Wd1 = Wd1; pp.Wd2 = Wd2; pp.Wf1 = Wf1; pp.Wf2 = Wf2; pp.Wf3 = Wf3;
    pp.Wlin_hi = Wlint_hi; pp.Wlin_lo = Wlint_lo;
    pp.Wd1_hi = Wd1t_hi;   pp.Wd1_lo = Wd1t_lo;
    pp.Wd2_hi = Wd2t_hi;   pp.Wd2_lo = Wd2t_lo;
    pp.Wf1_hi = Wf1t_hi;   pp.Wf1_lo = Wf1t_lo;
    pp.Wf2_hi = Wf2t_hi;   pp.Wf2_lo = Wf2t_lo;
    pp.Wf3_hi = Wf3t_hi;   pp.Wf3_lo = Wf3t_lo;
    prep_weights<<<(TSP_TOTAL + 255) / 256, 256, 0, stream>>>(pp);

    to_bf16<<<(NN * HH / 4 + 255) / 256, 256, 0, stream>>>(x, xb, NN * HH / 4);

    // ---- CSR build
    hipMemsetAsync(counts, 0, (size_t)NSEG * 4, stream);
    int eb0 = (RR * EE + 255) / 256;                      // 4688
    count_kernel<<<eb0, 256, 0, stream>>>(edges, counts);
    int nb = (NSEG + 255) / 256;                          // 1563
    scan1<<<nb, 256, 0, stream>>>(counts, excl, bsums, NSEG);
    scan2<<<1, 256, 0, stream>>>(bsums, nb);
    scan3<<<nb, 256, 0, stream>>>(excl, bsums, row_ptr, cursor, NSEG, RR * EE);
    fill_csr<<<eb0 * FPART, 256, 0, stream>>>(edges, cursor, csr_src);

    int gb = (int)(((long long)NSEG * 32 + 255) / 256);   // 50000 blocks
    int MY = (NN + 127) / 128;                            // 782

    // ---- layer 1
    gather_agg<<<gb, 256, 0, stream>>>(row_ptr, csr_src, xb, agg);
    mfma_gemm_bfA<1, false, true, 1><<<dim3(1, MY, 1), 256, 0, stream>>>(
        agg, 256, 0, Wrt1_hi, Wrt1_lo, 0, nullptr, 0, nullptr,
        h1, 64, 0, NN, 64, 256);

    // ---- layer 2
    gather_agg<<<gb, 256, 0, stream>>>(row_ptr, csr_src, h1, agg);
    mfma_gemm_bfA<1, false, true, 1><<<dim3(1, MY, 1), 256, 0, stream>>>(
        agg, 256, 0, Wrt2_hi, Wrt2_lo, 0, nullptr, 0, nullptr,
        h2, 64, 0, NN, 64, 256);

    // linear: h3 = leaky(h2 @ Wlin + blin) + noise  (fp32 out)
    mfma_gemm_bfA<2, true, false, 1><<<dim3(1, MY, 1), 256, 0, stream>>>(
        h2, 64, 0, Wlint_hi, Wlint_lo, 0, blin, 0, noise,
        h3, 64, 0, NN, 64, 64);

    gather_kernel<<<(SS * HH + 255) / 256, 256, 0, stream>>>(h3, seeds, hs);

    // head layer 1: d1 (leaky) + f1 (relu) fused, both bf16 out
    head1_gemm<<<dim3(4, 32, 4), 256, 0, stream>>>(
        hs, Wd1t_hi, Wd1t_lo, bd1, Wf1t_hi, Wf1t_lo, bf1, d1b, f1);

    // d2 = leaky(d1 @ Wd2[p] + bd2[p]) -> fp32
    mfma_gemm_bfA<2, false, false, 1><<<dim3(1, 32, PP), 256, 0, stream>>>(
        d1b, 256, (long long)SS * 256, Wd2t_hi, Wd2t_lo, (long long)32 * 256, bd2, 32, nullptr,
        d2v, 32, (long long)SS * 32, SS, 32, 256);
    d3_kernel<<<(PP * SS + 255) / 256, 256, 0, stream>>>(d2v, Wd3, bd3, out);

    // f2 = relu(f1 @ Wf2 + bf2) -> bf16
    mfma_gemm_bfA<1, false, true, 1><<<dim3(32, 32, PP), 256, 0, stream>>>(
        f1, 256, (long long)SS * 256, Wf2t_hi, Wf2t_lo, (long long)2048 * 256, bf2, 2048, nullptr,
        f2b, 2048, (long long)SS * 2048, SS, 2048, 256);
    // f3 partials: split-K=4
    mfma_gemm_bfA<0, false, false, 4><<<dim3(5, 32, PP * 4), 256, 0, stream>>>(
        f2b, 2048, (long long)SS * 2048, Wf3t_hi, Wf3t_lo, (long long)320 * 2048, nullptr, 0, nullptr,
        fpart, 320, (long long)SS * 320, SS, 320, 2048);
    reduce_tanh<<<(PP * SS * 320 + 255) / 256, 256, 0, stream>>>(fpart, bf3, out + (size_t)PP * SS);
}

// Round 8
// 529.079 us; speedup vs baseline: 2.8872x; 1.0816x over previous
//
#include <hip/hip_runtime.h>
#include <math.h>

#define NN 100000
#define RR 4
#define EE 300000
#define PP 2
#define HH 64
#define SS 4096
#define NSEG (NN * RR)          // 400000 segments
#define FPART 8
#define PWIDTH ((NN + FPART - 1) / FPART)   // 12500

typedef __attribute__((ext_vector_type(8))) short short8;
typedef __attribute__((ext_vector_type(4))) short short4v;
typedef __attribute__((ext_vector_type(4))) float f32x4;
typedef __attribute__((ext_vector_type(2))) unsigned int u32x2;

__device__ __forceinline__ short f2bf(float v) {
    unsigned u = __float_as_uint(v);
    unsigned r = (u + 0x7FFFu + ((u >> 16) & 1u)) >> 16;
    return (short)r;
}
__device__ __forceinline__ float bf2f(short s) {
    return __uint_as_float(((unsigned)(unsigned short)s) << 16);
}
__device__ __forceinline__ float bflo(unsigned v) { return __uint_as_float(v << 16); }
__device__ __forceinline__ float bfhi(unsigned v) { return __uint_as_float(v & 0xFFFF0000u); }
__device__ __forceinline__ unsigned pack2(float a, float b) {
    return (unsigned)(unsigned short)f2bf(a) | ((unsigned)(unsigned short)f2bf(b) << 16);
}

// ---- consolidated prep: Wr for both layers + all dense weight transp/split + x->bf16 ----
struct PrepPtrs {
    const float *Wlin, *Wd1, *Wd2, *Wf1, *Wf2, *Wf3;
    short *Wlin_hi, *Wlin_lo, *Wd1_hi, *Wd1_lo, *Wd2_hi, *Wd2_lo,
          *Wf1_hi, *Wf1_lo, *Wf2_hi, *Wf2_lo, *Wf3_hi, *Wf3_lo;
    const float *C1, *V1, *C2, *V2;
    short *wr1_hi, *wr1_lo, *wr2_hi, *wr2_lo;
    const float *x;
    short *xb;
};

__device__ __forceinline__ void tsp_one(const float* __restrict__ W, short* __restrict__ hi,
                                        short* __restrict__ lo, int K, int N, int idx) {
    int total = K * N;
    int z = idx / total;
    int rem = idx - z * total;
    int n = rem / K;
    int k = rem - n * K;
    float v = W[(long long)z * total + (long long)k * N + n];
    short h = f2bf(v);
    hi[idx] = h;
    lo[idx] = f2bf(v - bf2f(h));
}

#define T0 4096
#define T1 32768
#define T2 16384
#define T3 32768
#define T4 1048576
#define T5 1310720
#define TSP_TOTAL (T0 + T1 + T2 + T3 + T4 + T5)   // 2445312 = 9552*256
#define WR_BLK 128
#define TSP_BLK 9552
#define XB_BLK 6250

__global__ void prep_all(PrepPtrs pp) {
    int b = blockIdx.x;
    if (b < WR_BLK) {
        const float* C = (b < 64) ? pp.C1 : pp.C2;
        const float* V = (b < 64) ? pp.V1 : pp.V2;
        short* hi = (b < 64) ? pp.wr1_hi : pp.wr2_hi;
        short* lo = (b < 64) ? pp.wr1_lo : pp.wr2_lo;
        int idx = (b & 63) * 256 + threadIdx.x;
        int o = idx >> 8;
        int ri = idx & 255;
        int r = ri >> 6;
        int i = ri & 63;
        float v = C[r * 2] * V[i * 64 + o] + C[r * 2 + 1] * V[4096 + i * 64 + o];
        short h = f2bf(v);
        hi[idx] = h;
        lo[idx] = f2bf(v - bf2f(h));
        return;
    }
    b -= WR_BLK;
    if (b < TSP_BLK) {
        int idx = b * 256 + threadIdx.x;
        if (idx < T0) { tsp_one(pp.Wlin, pp.Wlin_hi, pp.Wlin_lo, 64, 64, idx); return; }
        idx -= T0;
        if (idx < T1) { tsp_one(pp.Wd1, pp.Wd1_hi, pp.Wd1_lo, 64, 256, idx); return; }
        idx -= T1;
        if (idx < T2) { tsp_one(pp.Wd2, pp.Wd2_hi, pp.Wd2_lo, 256, 32, idx); return; }
        idx -= T2;
        if (idx < T3) { tsp_one(pp.Wf1, pp.Wf1_hi, pp.Wf1_lo, 64, 256, idx); return; }
        idx -= T3;
        if (idx < T4) { tsp_one(pp.Wf2, pp.Wf2_hi, pp.Wf2_lo, 256, 2048, idx); return; }
        idx -= T4;
        tsp_one(pp.Wf3, pp.Wf3_hi, pp.Wf3_lo, 2048, 320, idx);
        return;
    }
    b -= TSP_BLK;
    int idx = b * 256 + threadIdx.x;          // < 1,600,000 (NN*HH/4)
    f32x4 v = *(const f32x4*)&pp.x[(long long)idx * 4];
    short4v o;
    #pragma unroll
    for (int c = 0; c < 4; c++) o[c] = f2bf(v[c]);
    *(short4v*)&pp.xb[(long long)idx * 4] = o;
}

// ---------------- CSR build ----------------
__global__ void count_kernel(const int* __restrict__ edges, int* __restrict__ counts) {
    int idx = blockIdx.x * 256 + threadIdx.x;
    if (idx >= RR * EE) return;
    int r = idx / EE;
    int dst = edges[2 * idx + 1];
    atomicAdd(&counts[dst * RR + r], 1);
}

__global__ void scan1(const int* __restrict__ counts, int* __restrict__ excl,
                      int* __restrict__ bsums, int n) {
    __shared__ int tmp[256];
    int tid = threadIdx.x;
    int gid = blockIdx.x * 256 + tid;
    int v = (gid < n) ? counts[gid] : 0;
    tmp[tid] = v;
    __syncthreads();
    #pragma unroll
    for (int off = 1; off < 256; off <<= 1) {
        int y = (tid >= off) ? tmp[tid - off] : 0;
        __syncthreads();
        tmp[tid] += y;
        __syncthreads();
    }
    if (gid < n) excl[gid] = tmp[tid] - v;
    if (tid == 255) bsums[blockIdx.x] = tmp[255];
}

__global__ void scan2(int* __restrict__ bsums, int nb) {
    __shared__ int tmp[256];
    __shared__ int carry;
    int tid = threadIdx.x;
    if (tid == 0) carry = 0;
    __syncthreads();
    for (int base = 0; base < nb; base += 256) {
        int i = base + tid;
        int v = (i < nb) ? bsums[i] : 0;
        tmp[tid] = v;
        __syncthreads();
        #pragma unroll
        for (int off = 1; off < 256; off <<= 1) {
            int y = (tid >= off) ? tmp[tid - off] : 0;
            __syncthreads();
            tmp[tid] += y;
            __syncthreads();
        }
        if (i < nb) bsums[i] = tmp[tid] - v + carry;
        __syncthreads();
        if (tid == 0) carry += tmp[255];
        __syncthreads();
    }
}

__global__ void scan3(const int* __restrict__ excl, const int* __restrict__ bsums,
                      int* __restrict__ row_ptr, int* __restrict__ cursor, int n, int total) {
    int gid = blockIdx.x * 256 + threadIdx.x;
    if (gid < n) {
        int v = excl[gid] + bsums[gid >> 8];
        row_ptr[gid] = v;
        cursor[gid] = v;
    }
    if (gid == 0) row_ptr[n] = total;
}

// fill: dst-partitioned so csr_src stores are localized (fixes writeback amplification)
__global__ void fill_csr(const int* __restrict__ edges, int* __restrict__ cursor,
                         int* __restrict__ csr_src) {
    int part = blockIdx.x & (FPART - 1);
    int idx = (blockIdx.x >> 3) * 256 + threadIdx.x;
    if (idx >= RR * EE) return;
    int dst = edges[2 * idx + 1];
    int lo = part * PWIDTH;
    if (dst < lo || dst >= lo + PWIDTH) return;
    int r = idx / EE;
    int src = edges[2 * idx];
    int pos = atomicAdd(&cursor[dst * RR + r], 1);
    csr_src[pos] = src;
}

// ---------------- gather aggregation ----------------
// One segment per 16-lane QUARTER-WAVE; lane covers 4 channels via one 8B load.
// 4-wide batched independent loads for MLP. 4 segments per wave.
__global__ __launch_bounds__(256) void gather_agg(const int* __restrict__ row_ptr,
                                                  const int* __restrict__ csr_src,
                                                  const short* __restrict__ feat,
                                                  short* __restrict__ agg) {
    long long tg = (long long)blockIdx.x * 256 + threadIdx.x;
    long long seg = tg >> 4;
    int cl = threadIdx.x & 15;           // channels 4cl .. 4cl+3
    if (seg >= (long long)NSEG) return;
    int beg = row_ptr[seg];
    int end = row_ptr[seg + 1];
    float s0 = 0.f, s1 = 0.f, s2 = 0.f, s3 = 0.f;
    int i = beg;
    for (; i + 4 <= end; i += 4) {
        int a = csr_src[i];
        int b = csr_src[i + 1];
        int c = csr_src[i + 2];
        int d = csr_src[i + 3];
        u32x2 va = *(const u32x2*)&feat[a * HH + cl * 4];
        u32x2 vb = *(const u32x2*)&feat[b * HH + cl * 4];
        u32x2 vc = *(const u32x2*)&feat[c * HH + cl * 4];
        u32x2 vd = *(const u32x2*)&feat[d * HH + cl * 4];
        s0 += (bflo(va.x) + bflo(vb.x)) + (bflo(vc.x) + bflo(vd.x));
        s1 += (bfhi(va.x) + bfhi(vb.x)) + (bfhi(vc.x) + bfhi(vd.x));
        s2 += (bflo(va.y) + bflo(vb.y)) + (bflo(vc.y) + bflo(vd.y));
        s3 += (bfhi(va.y) + bfhi(vb.y)) + (bfhi(vc.y) + bfhi(vd.y));
    }
    int rem = end - i;
    if (rem > 0) {
        int a = csr_src[i];
        int b = csr_src[rem > 1 ? i + 1 : i];
        int c = csr_src[rem > 2 ? i + 2 : i];
        u32x2 va = *(const u32x2*)&feat[a * HH + cl * 4];
        u32x2 vb = *(const u32x2*)&feat[b * HH + cl * 4];
        u32x2 vc = *(const u32x2*)&feat[c * HH + cl * 4];
        s0 += bflo(va.x); s1 += bfhi(va.x); s2 += bflo(va.y); s3 += bfhi(va.y);
        if (rem > 1) { s0 += bflo(vb.x); s1 += bfhi(vb.x); s2 += bflo(vb.y); s3 += bfhi(vb.y); }
        if (rem > 2) { s0 += bflo(vc.x); s1 += bfhi(vc.x); s2 += bflo(vc.y); s3 += bfhi(vc.y); }
    }
    int d = end - beg;
    float inv = 1.0f / (float)(d > 1 ? d : 1);
    u32x2 outp;
    outp.x = pack2(s0 * inv, s1 * inv);
    outp.y = pack2(s2 * inv, s3 * inv);
    *(u32x2*)&agg[seg * HH + cl * 4] = outp;
}

// split-K reduction + bias + tanh for f3
__global__ void reduce_tanh(const float* __restrict__ part, const float* __restrict__ bf3,
                            float* __restrict__ out) {
    int idx = blockIdx.x * 256 + threadIdx.x;
    if (idx >= PP * SS * 320) return;
    int p = idx / (SS * 320);
    int rem = idx - p * (SS * 320);
    int n = rem % 320;
    float s = bf3[p * 320 + n];
    #pragma unroll
    for (int ks = 0; ks < 4; ks++)
        s += part[((long long)(p * 4 + ks)) * SS * 320 + rem];
    out[idx] = tanhf(s);
}

// ================= MFMA GEMM, A = bf16 single plane (2 MFMAs), optional split-K =========
template <int ACT, bool OUTBF, int KSPLIT>
__global__ __launch_bounds__(256) void mfma_gemm_bfA(
    const short* __restrict__ A, int lda, long long sA,
    const short* __restrict__ Bhi, const short* __restrict__ Blo, long long sB,
    const float* __restrict__ bias, long long sBias,
    void* __restrict__ Cc, int ldc, long long sC,
    int M, int Nn, int K)
{
    __shared__ short As[128 * 32];
    __shared__ short Bs_hi[64 * 32];
    __shared__ short Bs_lo[64 * 32];

    int z = blockIdx.z;
    int p = z / KSPLIT, ks = z % KSPLIT;
    A += (long long)p * sA;
    Bhi += (long long)p * sB;
    Blo += (long long)p * sB;
    const float* bz = bias ? bias + (long long)p * sBias : nullptr;
    long long cbase = (long long)((KSPLIT > 1) ? z : p) * sC;

    int Kc = K / KSPLIT;
    int kbeg = ks * Kc;

    int m0 = blockIdx.y * 128;
    int n0 = blockIdx.x * 64;
    int tid = threadIdx.x;
    int lane = tid & 63;
    int w = tid >> 6;
    int wm = w >> 1, wn = w & 1;
    int mrow = lane & 15;
    int quad = lane >> 4;

    f32x4 acc[4][2];
    #pragma unroll
    for (int s = 0; s < 4; s++)
        #pragma unroll
        for (int t = 0; t < 2; t++)
            acc[s][t] = (f32x4){0.f, 0.f, 0.f, 0.f};

    for (int k0 = kbeg; k0 < kbeg + Kc; k0 += 32) {
        #pragma unroll
        for (int i = 0; i < 2; i++) {
            int f = tid + i * 256;
            int m = f >> 2, q = f & 3;
            int gm = m0 + m;
            short8 av = (short8)0;
            if (gm < M) av = *(const short8*)&A[(long long)gm * lda + k0 + q * 8];
            *(short8*)&As[m * 32 + q * 8] = av;
        }
        {
            int n = tid >> 2, q = tid & 3;
            int gn = n0 + n;
            short8 bh = (short8)0, bl = (short8)0;
            if (gn < Nn) {
                long long boff = (long long)gn * K + k0 + q * 8;
                bh = *(const short8*)&Bhi[boff];
                bl = *(const short8*)&Blo[boff];
            }
            *(short8*)&Bs_hi[n * 32 + q * 8] = bh;
            *(short8*)&Bs_lo[n * 32 + q * 8] = bl;
        }
        __syncthreads();

        short8 ah[4], bh[2], bl[2];
        #pragma unroll
        for (int s = 0; s < 4; s++)
            ah[s] = *(const short8*)&As[(wm * 64 + s * 16 + mrow) * 32 + quad * 8];
        #pragma unroll
        for (int t = 0; t < 2; t++) {
            int soff = (wn * 32 + t * 16 + mrow) * 32 + quad * 8;
            bh[t] = *(const short8*)&Bs_hi[soff];
            bl[t] = *(const short8*)&Bs_lo[soff];
        }
        #pragma unroll
        for (int s = 0; s < 4; s++)
            #pragma unroll
            for (int t = 0; t < 2; t++) {
                acc[s][t] = __builtin_amdgcn_mfma_f32_16x16x32_bf16(ah[s], bh[t], acc[s][t], 0, 0, 0);
                acc[s][t] = __builtin_amdgcn_mfma_f32_16x16x32_bf16(ah[s], bl[t], acc[s][t], 0, 0, 0);
            }
        __syncthreads();
    }

    #pragma unroll
    for (int s = 0; s < 4; s++) {
        int gmBase = m0 + wm * 64 + s * 16 + quad * 4;
        #pragma unroll
        for (int t = 0; t < 2; t++) {
            int gn = n0 + wn * 32 + t * 16 + mrow;
            if (gn >= Nn) continue;
            float bb = bz ? bz[gn] : 0.f;
            #pragma unroll
            for (int r = 0; r < 4; r++) {
                int gm = gmBase + r;
                if (gm >= M) continue;
                float v = acc[s][t][r] + bb;
                if (ACT == 1) v = fmaxf(v, 0.f);
                else if (ACT == 2) v = (v > 0.f) ? v : 0.01f * v;
                long long co = cbase + (long long)gm * ldc + gn;
                if (OUTBF) ((short*)Cc)[co] = f2bf(v);
                else ((float*)Cc)[co] = v;
            }
        }
    }
}

// ======== fused combine2 + linear: h3 = leaky(relu(agg@Wr2) @ Wlin + blin) + noise ======
__global__ __launch_bounds__(256) void combine2_linear(
    const short* __restrict__ A,                                       // agg2 [NN][256]
    const short* __restrict__ Bhi, const short* __restrict__ Blo,      // Wr2t [64][256]
    const short* __restrict__ Lhi, const short* __restrict__ Llo,      // Wlint [64][64]
    const float* __restrict__ blin, const float* __restrict__ noise,
    float* __restrict__ h3)
{
    __shared__ short As[128 * 32];
    __shared__ short Bs_hi[64 * 32];
    __shared__ short Bs_lo[64 * 32];
    __shared__ short Ls_hi[64 * 64];
    __shared__ short Ls_lo[64 * 64];
    __shared__ short h2s[128 * 64];

    int tid = threadIdx.x;
    int lane = tid & 63;
    int w = tid >> 6;
    int wm = w >> 1, wn = w & 1;
    int mrow = lane & 15;
    int quad = lane >> 4;
    int m0 = blockIdx.x * 128;

    // stage Wlin (both planes) once
    {
        int base = tid * 16;
        *(short8*)&Ls_hi[base] = *(const short8*)&Lhi[base];
        *(short8*)&Ls_hi[base + 8] = *(const short8*)&Lhi[base + 8];
        *(short8*)&Ls_lo[base] = *(const short8*)&Llo[base];
        *(short8*)&Ls_lo[base + 8] = *(const short8*)&Llo[base + 8];
    }

    f32x4 acc[4][2];
    #pragma unroll
    for (int s = 0; s < 4; s++)
        #pragma unroll
        for (int t = 0; t < 2; t++)
            acc[s][t] = (f32x4){0.f, 0.f, 0.f, 0.f};

    for (int k0 = 0; k0 < 256; k0 += 32) {
        #pragma unroll
        for (int i = 0; i < 2; i++) {
            int f = tid + i * 256;
            int m = f >> 2, q = f & 3;
            int gm = m0 + m;
            short8 av = (short8)0;
            if (gm < NN) av = *(const short8*)&A[(long long)gm * 256 + k0 + q * 8];
            *(short8*)&As[m * 32 + q * 8] = av;
        }
        {
            int n = tid >> 2, q = tid & 3;
            long long boff = (long long)n * 256 + k0 + q * 8;
            *(short8*)&Bs_hi[n * 32 + q * 8] = *(const short8*)&Bhi[boff];
            *(short8*)&Bs_lo[n * 32 + q * 8] = *(const short8*)&Blo[boff];
        }
        __syncthreads();

        short8 ah[4], bh[2], bl[2];
        #pragma unroll
        for (int s = 0; s < 4; s++)
            ah[s] = *(const short8*)&As[(wm * 64 + s * 16 + mrow) * 32 + quad * 8];
        #pragma unroll
        for (int t = 0; t < 2; t++) {
            int soff = (wn * 32 + t * 16 + mrow) * 32 + quad * 8;
            bh[t] = *(const short8*)&Bs_hi[soff];
            bl[t] = *(const short8*)&Bs_lo[soff];
        }
        #pragma unroll
        for (int s = 0; s < 4; s++)
            #pragma unroll
            for (int t = 0; t < 2; t++) {
                acc[s][t] = __builtin_amdgcn_mfma_f32_16x16x32_bf16(ah[s], bh[t], acc[s][t], 0, 0, 0);
                acc[s][t] = __builtin_amdgcn_mfma_f32_16x16x32_bf16(ah[s], bl[t], acc[s][t], 0, 0, 0);
            }
        __syncthreads();
    }

    // h2 = relu(acc) -> LDS bf16 [row][col]
    #pragma unroll
    for (int s = 0; s < 4; s++) {
        int rowB = wm * 64 + s * 16 + quad * 4;
        #pragma unroll
        for (int t = 0; t < 2; t++) {
            int col = wn * 32 + t * 16 + mrow;
            #pragma unroll
            for (int r = 0; r < 4; r++)
                h2s[(rowB + r) * 64 + col] = f2bf(fmaxf(acc[s][t][r], 0.f));
        }
    }
    __syncthreads();

    // phase 2: h3 = leaky(h2 @ Wlin + blin) + noise
    f32x4 acc2[4][2];
    #pragma unroll
    for (int s = 0; s < 4; s++)
        #pragma unroll
        for (int t = 0; t < 2; t++)
            acc2[s][t] = (f32x4){0.f, 0.f, 0.f, 0.f};

    #pragma unroll
    for (int k0 = 0; k0 < 64; k0 += 32) {
        short8 ah[4], bh[2], bl[2];
        #pragma unroll
        for (int s = 0; s < 4; s++)
            ah[s] = *(const short8*)&h2s[(wm * 64 + s * 16 + mrow) * 64 + k0 + quad * 8];
        #pragma unroll
        for (int t = 0; t < 2; t++) {
            int soff = (wn * 32 + t * 16 + mrow) * 64 + k0 + quad * 8;
            bh[t] = *(const short8*)&Ls_hi[soff];
            bl[t] = *(const short8*)&Ls_lo[soff];
        }
        #pragma unroll
        for (int s = 0; s < 4; s++)
            #pragma unroll
            for (int t = 0; t < 2; t++) {
                acc2[s][t] = __builtin_amdgcn_mfma_f32_16x16x32_bf16(ah[s], bh[t], acc2[s][t], 0, 0, 0);
                acc2[s][t] = __builtin_amdgcn_mfma_f32_16x16x32_bf16(ah[s], bl[t], acc2[s][t], 0, 0, 0);
            }
    }

    #pragma unroll
    for (int s = 0; s < 4; s++) {
        int gmBase = m0 + wm * 64 + s * 16 + quad * 4;
        #pragma unroll
        for (int t = 0; t < 2; t++) {
            int gn = wn * 32 + t * 16 + mrow;
            float bb = blin[gn];
            #pragma unroll
            for (int r = 0; r < 4; r++) {
                int gm = gmBase + r;
                if (gm >= NN) continue;
                float v = acc2[s][t][r] + bb;
                v = (v > 0.f) ? v : 0.01f * v;
                v += noise[(long long)gm * 64 + gn];
                h3[(long long)gm * 64 + gn] = v;
            }
        }
    }
}

// ======== head layer-1 GEMM with integrated seed gather (d1 leaky + f1 relu) ====
__global__ __launch_bounds__(256) void head1_gemm(
    const float* __restrict__ h3, const int* __restrict__ seeds,
    const short* __restrict__ Bd_hi, const short* __restrict__ Bd_lo, const float* __restrict__ bd,
    const short* __restrict__ Bf_hi, const short* __restrict__ Bf_lo, const float* __restrict__ bfb,
    short* __restrict__ outd, short* __restrict__ outf)
{
    __shared__ short As_hi[128 * 32];
    __shared__ short As_lo[128 * 32];
    __shared__ short Bs_hi[64 * 32];
    __shared__ short Bs_lo[64 * 32];

    int z = blockIdx.z;
    int head = z >> 1, p = z & 1;
    const short* Bhi = (head ? Bf_hi : Bd_hi) + (long long)p * 256 * 64;
    const short* Blo = (head ? Bf_lo : Bd_lo) + (long long)p * 256 * 64;
    const float* bz = (head ? bfb : bd) + p * 256;
    short* Cc = (head ? outf : outd) + (long long)p * SS * 256;

    int m0 = blockIdx.y * 128;
    int n0 = blockIdx.x * 64;
    int tid = threadIdx.x;
    int lane = tid & 63;
    int w = tid >> 6;
    int wm = w >> 1, wn = w & 1;
    int mrow = lane & 15;
    int quad = lane >> 4;

    f32x4 acc[4][2];
    #pragma unroll
    for (int s = 0; s < 4; s++)
        #pragma unroll
        for (int t = 0; t < 2; t++)
            acc[s][t] = (f32x4){0.f, 0.f, 0.f, 0.f};

    #pragma unroll
    for (int k0 = 0; k0 < 64; k0 += 32) {
        #pragma unroll
        for (int i = 0; i < 4; i++) {
            int f = tid + i * 256;
            int m = f >> 3, k4 = f & 7;
            int node = seeds[m0 + m];
            f32x4 v = *(const f32x4*)&h3[(long long)node * 64 + k0 + k4 * 4];
            short4v hv, lv;
            #pragma unroll
            for (int c = 0; c < 4; c++) {
                short hh = f2bf(v[c]);
                hv[c] = hh;
                lv[c] = f2bf(v[c] - bf2f(hh));
            }
            *(short4v*)&As_hi[m * 32 + k4 * 4] = hv;
            *(short4v*)&As_lo[m * 32 + k4 * 4] = lv;
        }
        {
            int n = tid >> 2, q = tid & 3;
            long long boff = (long long)(n0 + n) * 64 + k0 + q * 8;
            *(short8*)&Bs_hi[n * 32 + q * 8] = *(const short8*)&Bhi[boff];
            *(short8*)&Bs_lo[n * 32 + q * 8] = *(const short8*)&Blo[boff];
        }
        __syncthreads();

        short8 ah[4], al[4], bh[2], bl[2];
        #pragma unroll
        for (int s = 0; s < 4; s++) {
            int soff = (wm * 64 + s * 16 + mrow) * 32 + quad * 8;
            ah[s] = *(const short8*)&As_hi[soff];
            al[s] = *(const short8*)&As_lo[soff];
        }
        #pragma unroll
        for (int t = 0; t < 2; t++) {
            int soff = (wn * 32 + t * 16 + mrow) * 32 + quad * 8;
            bh[t] = *(const short8*)&Bs_hi[soff];
            bl[t] = *(const short8*)&Bs_lo[soff];
        }
        #pragma unroll
        for (int s = 0; s < 4; s++)
            #pragma unroll
            for (int t = 0; t < 2; t++) {
                acc[s][t] = __builtin_amdgcn_mfma_f32_16x16x32_bf16(ah[s], bh[t], acc[s][t], 0, 0, 0);
                acc[s][t] = __builtin_amdgcn_mfma_f32_16x16x32_bf16(ah[s], bl[t], acc[s][t], 0, 0, 0);
                acc[s][t] = __builtin_amdgcn_mfma_f32_16x16x32_bf16(al[s], bh[t], acc[s][t], 0, 0, 0);
            }
        __syncthreads();
    }

    #pragma unroll
    for (int s = 0; s < 4; s++) {
        int gmBase = m0 + wm * 64 + s * 16 + quad * 4;
        #pragma unroll
        for (int t = 0; t < 2; t++) {
            int gn = n0 + wn * 32 + t * 16 + mrow;
            float bb = bz[gn];
            #pragma unroll
            for (int r = 0; r < 4; r++) {
                int gm = gmBase + r;
                float v = acc[s][t][r] + bb;
                v = (head == 1) ? fmaxf(v, 0.f) : ((v > 0.f) ? v : 0.01f * v);
                Cc[(long long)gm * 256 + gn] = f2bf(v);
            }
        }
    }
}

// ======== fused d-head: pred_missing = relu(leaky(d1@Wd2+bd2) @ Wd3 + bd3) ========
__global__ __launch_bounds__(256) void dhead_gemm(
    const short* __restrict__ d1b,                                  // [P][4096][256]
    const short* __restrict__ Bhi, const short* __restrict__ Blo,   // Wd2t [P][32][256]
    const float* __restrict__ bd2, const float* __restrict__ Wd3,
    const float* __restrict__ bd3, float* __restrict__ out)
{
    __shared__ short As[128 * 32];
    __shared__ short Bs_hi[64 * 32];
    __shared__ short Bs_lo[64 * 32];
    __shared__ float d2s[128][33];

    int p = blockIdx.z;
    const short* A = d1b + (long long)p * SS * 256;
    const short* Bh = Bhi + (long long)p * 32 * 256;
    const short* Bl = Blo + (long long)p * 32 * 256;

    int m0 = blockIdx.y * 128;
    int tid = threadIdx.x;
    int lane = tid & 63;
    int w = tid >> 6;
    int wm = w >> 1, wn = w & 1;
    int mrow = lane & 15;
    int quad = lane >> 4;

    f32x4 acc[4][2];
    #pragma unroll
    for (int s = 0; s < 4; s++)
        #pragma unroll
        for (int t = 0; t < 2; t++)
            acc[s][t] = (f32x4){0.f, 0.f, 0.f, 0.f};

    for (int k0 = 0; k0 < 256; k0 += 32) {
        #pragma unroll
        for (int i = 0; i < 2; i++) {
            int f = tid + i * 256;
            int m = f >> 2, q = f & 3;
            *(short8*)&As[m * 32 + q * 8] = *(const short8*)&A[(long long)(m0 + m) * 256 + k0 + q * 8];
        }
        {
            int n = tid >> 2, q = tid & 3;
            short8 bh = (short8)0, bl = (short8)0;
            if (n < 32) {
                long long boff = (long long)n * 256 + k0 + q * 8;
                bh = *(const short8*)&Bh[boff];
                bl = *(const short8*)&Bl[boff];
            }
            *(short8*)&Bs_hi[n * 32 + q * 8] = bh;
            *(short8*)&Bs_lo[n * 32 + q * 8] = bl;
        }
        __syncthreads();

        short8 ah[4], bh[2], bl[2];
        #pragma unroll
        for (int s = 0; s < 4; s++)
            ah[s] = *(const short8*)&As[(wm * 64 + s * 16 + mrow) * 32 + quad * 8];
        #pragma unroll
        for (int t = 0; t < 2; t++) {
            int soff = (wn * 32 + t * 16 + mrow) * 32 + quad * 8;
            bh[t] = *(const short8*)&Bs_hi[soff];
            bl[t] = *(const short8*)&Bs_lo[soff];
        }
        #pragma unroll
        for (int s = 0; s < 4; s++)
            #pragma unroll
            for (int t = 0; t < 2; t++) {
                acc[s][t] = __builtin_amdgcn_mfma_f32_16x16x32_bf16(ah[s], bh[t], acc[s][t], 0, 0, 0);
                acc[s][t] = __builtin_amdgcn_mfma_f32_16x16x32_bf16(ah[s], bl[t], acc[s][t], 0, 0, 0);
            }
        __syncthreads();
    }

    // leaky(d2) -> LDS (only wn==0 waves hold cols 0..31)
    if (wn == 0) {
        #pragma unroll
        for (int s = 0; s < 4; s++) {
            int rowB = wm * 64 + s * 16 + quad * 4;
            #pragma unroll
            for (int t = 0; t < 2; t++) {
                int col = t * 16 + mrow;
                #pragma unroll
                for (int r = 0; r < 4; r++) {
                    float v = acc[s][t][r] + bd2[p * 32 + col];
                    d2s[rowB + r][col] = (v > 0.f) ? v : 0.01f * v;
                }
            }
        }
    }
    __syncthreads();

    if (tid < 128) {
        float sacc = bd3[p];
        #pragma unroll
        for (int k = 0; k < 32; k++) sacc += d2s[tid][k] * Wd3[p * 32 + k];
        out[p * SS + m0 + tid] = fmaxf(sacc, 0.f);
    }
}

extern "C" void kernel_launch(void* const* d_in, const int* in_sizes, int n_in,
                              void* d_out, int out_size, void* d_ws, size_t ws_size,
                              hipStream_t stream) {
    const float* x    = (const float*)d_in[0];
    const int* edges  = (const int*)d_in[1];
    const int* seeds  = (const int*)d_in[2];
    const float* noise= (const float*)d_in[3];
    const float* V1   = (const float*)d_in[4];
    const float* C1   = (const float*)d_in[5];
    const float* V2   = (const float*)d_in[6];
    const float* C2   = (const float*)d_in[7];
    const float* Wlin = (const float*)d_in[8];
    const float* blin = (const float*)d_in[9];
    const float* Wd1 = (const float*)d_in[10]; const float* bd1 = (const float*)d_in[11];
    const float* Wd2 = (const float*)d_in[12]; const float* bd2 = (const float*)d_in[13];
    const float* Wd3 = (const float*)d_in[14]; const float* bd3 = (const float*)d_in[15];
    const float* Wf1 = (const float*)d_in[16]; const float* bf1 = (const float*)d_in[17];
    const float* Wf2 = (const float*)d_in[18]; const float* bf2 = (const float*)d_in[19];
    const float* Wf3 = (const float*)d_in[20]; const float* bf3 = (const float*)d_in[21];

    float* out = (float*)d_out;

    char* ws = (char*)d_ws;
    size_t off = 0;
    auto allocf = [&](size_t nf) {
        float* p = (float*)(ws + off);
        off += ((nf * 4 + 255) / 256) * 256;
        return p;
    };
    auto allocs = [&](size_t ns) {
        short* p = (short*)(ws + off);
        off += ((ns * 2 + 255) / 256) * 256;
        return p;
    };
    auto alloci = [&](size_t ni) {
        int* p = (int*)(ws + off);
        off += ((ni * 4 + 255) / 256) * 256;
        return p;
    };

    short* Wrt1_hi = allocs(16384);          short* Wrt1_lo = allocs(16384);
    short* Wrt2_hi = allocs(16384);          short* Wrt2_lo = allocs(16384);
    short* Wlint_hi = allocs(4096);          short* Wlint_lo = allocs(4096);
    short* Wd1t_hi = allocs(2 * 64 * 256);   short* Wd1t_lo = allocs(2 * 64 * 256);
    short* Wd2t_hi = allocs(2 * 256 * 32);   short* Wd2t_lo = allocs(2 * 256 * 32);
    short* Wf1t_hi = allocs(2 * 64 * 256);   short* Wf1t_lo = allocs(2 * 64 * 256);
    short* Wf2t_hi = allocs((size_t)2 * 256 * 2048);  short* Wf2t_lo = allocs((size_t)2 * 256 * 2048);
    short* Wf3t_hi = allocs((size_t)2 * 2048 * 320);  short* Wf3t_lo = allocs((size_t)2 * 2048 * 320);

    // CSR
    int* counts  = alloci(NSEG);
    int* excl    = alloci(NSEG);
    int* bsums   = alloci(2048);
    int* row_ptr = alloci(NSEG + 1);
    int* cursor  = alloci(NSEG);
    int* csr_src = alloci((size_t)RR * EE);

    short* xb  = allocs((size_t)NN * HH);        // bf16 copy of x
    short* agg = allocs((size_t)NSEG * HH);      // 51.2 MB; reused as fpart later
    short* h1  = allocs((size_t)NN * HH);        // bf16
    float* h3  = allocf((size_t)NN * HH);        // fp32 (noise precision)
    short* d1b = allocs((size_t)PP * SS * 256);  // bf16
    short* f1  = allocs((size_t)PP * SS * 256);  // bf16
    short* f2b = allocs((size_t)PP * SS * 2048); // bf16

    float* fpart = (float*)agg;                  // 4*2*4096*320*4 = 41.9 MB <= 51.2 MB

    // ---- prep (1 launch): Wr1/Wr2 + all dense weights + x->bf16
    PrepPtrs pp;
    pp.Wlin = Wlin; pp.Wd1 = Wd1; pp.Wd2 = Wd2; pp.Wf1 = Wf1; pp.Wf2 = Wf2; pp.Wf3 = Wf3;
    pp.Wlin_hi = Wlint_hi; pp.Wlin_lo = Wlint_lo;
    pp.Wd1_hi = Wd1t_hi;   pp.Wd1_lo = Wd1t_lo;
    pp.Wd2_hi = Wd2t_hi;   pp.Wd2_lo = Wd2t_lo;
    pp.Wf1_hi = Wf1t_hi;   pp.Wf1_lo = Wf1t_lo;
    pp.Wf2_hi = Wf2t_hi;   pp.Wf2_lo = Wf2t_lo;
    pp.Wf3_hi = Wf3t_hi;   pp.Wf3_lo = Wf3t_lo;
    pp.C1 = C1; pp.V1 = V1; pp.C2 = C2; pp.V2 = V2;
    pp.wr1_hi = Wrt1_hi; pp.wr1_lo = Wrt1_lo; pp.wr2_hi = Wrt2_hi; pp.wr2_lo = Wrt2_lo;
    pp.x = x; pp.xb = xb;
    prep_all<<<WR_BLK + TSP_BLK + XB_BLK, 256, 0, stream>>>(pp);

    // ---- CSR build
    hipMemsetAsync(counts, 0, (size_t)NSEG * 4, stream);
    int eb0 = (RR * EE + 255) / 256;                      // 4688
    count_kernel<<<eb0, 256, 0, stream>>>(edges, counts);
    int nb = (NSEG + 255) / 256;                          // 1563
    scan1<<<nb, 256, 0, stream>>>(counts, excl, bsums, NSEG);
    scan2<<<1, 256, 0, stream>>>(bsums, nb);
    scan3<<<nb, 256, 0, stream>>>(excl, bsums, row_ptr, cursor, NSEG, RR * EE);
    fill_csr<<<eb0 * FPART, 256, 0, stream>>>(edges, cursor, csr_src);

    int gb = (int)(((long long)NSEG * 16 + 255) / 256);   // 25000 blocks
    int MY = (NN + 127) / 128;                            // 782

    // ---- layer 1
    gather_agg<<<gb, 256, 0, stream>>>(row_ptr, csr_src, xb, agg);
    mfma_gemm_bfA<1, true, 1><<<dim3(1, MY, 1), 256, 0, stream>>>(
        agg, 256, 0, Wrt1_hi, Wrt1_lo, 0, nullptr, 0,
        h1, 64, 0, NN, 64, 256);

    // ---- layer 2 + linear (fused)
    gather_agg<<<gb, 256, 0, stream>>>(row_ptr, csr_src, h1, agg);
    combine2_linear<<<MY, 256, 0, stream>>>(
        agg, Wrt2_hi, Wrt2_lo, Wlint_hi, Wlint_lo, blin, noise, h3);

    // head layer 1: d1 (leaky) + f1 (relu), seeds gathered in-kernel
    head1_gemm<<<dim3(4, 32, 4), 256, 0, stream>>>(
        h3, seeds, Wd1t_hi, Wd1t_lo, bd1, Wf1t_hi, Wf1t_lo, bf1, d1b, f1);

    // d-head fused: d2+d3 -> out[0 : P*S]
    dhead_gemm<<<dim3(1, 32, PP), 256, 0, stream>>>(
        d1b, Wd2t_hi, Wd2t_lo, bd2, Wd3, bd3, out);

    // f2 = relu(f1 @ Wf2 + bf2) -> bf16
    mfma_gemm_bfA<1, true, 1><<<dim3(32, 32, PP), 256, 0, stream>>>(
        f1, 256, (long long)SS * 256, Wf2t_hi, Wf2t_lo, (long long)2048 * 256, bf2, 2048,
        f2b, 2048, (long long)SS * 2048, SS, 2048, 256);
    // f3 partials: split-K=4
    mfma_gemm_bfA<0, false, 4><<<dim3(5, 32, PP * 4), 256, 0, stream>>>(
        f2b, 2048, (long long)SS * 2048, Wf3t_hi, Wf3t_lo, (long long)320 * 2048, nullptr, 0,
        fpart, 320, (long long)SS * 320, SS, 320, 2048);
    reduce_tanh<<<(PP * SS * 320 + 255) / 256, 256, 0, stream>>>(fpart, bf3, out + (size_t)PP * SS);
}

// Round 9
// 481.604 us; speedup vs baseline: 3.1718x; 1.0986x over previous
//
#include <hip/hip_runtime.h>
#include <math.h>

#define NN 100000
#define RR 4
#define EE 300000
#define PP 2
#define HH 64
#define SS 4096
#define NSEG (NN * RR)          // 400000 segments
#define FPART 8
#define PWIDTH ((NN + FPART - 1) / FPART)   // 12500

typedef __attribute__((ext_vector_type(8))) short short8;
typedef __attribute__((ext_vector_type(4))) short short4v;
typedef __attribute__((ext_vector_type(4))) float f32x4;

__device__ __forceinline__ short f2bf(float v) {
    unsigned u = __float_as_uint(v);
    unsigned r = (u + 0x7FFFu + ((u >> 16) & 1u)) >> 16;
    return (short)r;
}
__device__ __forceinline__ float bf2f(short s) {
    return __uint_as_float(((unsigned)(unsigned short)s) << 16);
}

// ---- consolidated prep: Wr both layers + dense weight transp/split + x->bf16 ----
struct PrepPtrs {
    const float *Wlin, *Wd1, *Wd2, *Wf1, *Wf2, *Wf3;
    short *Wlin_hi, *Wlin_lo, *Wd1_hi, *Wd1_lo, *Wd2_hi, *Wd2_lo,
          *Wf1_hi, *Wf1_lo, *Wf2_hi, *Wf2_lo, *Wf3_hi, *Wf3_lo;
    const float *C1, *V1, *C2, *V2;
    short *wr1_hi, *wr1_lo, *wr2_hi, *wr2_lo;
    const float *x;
    short *xb;
};

__device__ __forceinline__ void tsp_one(const float* __restrict__ W, short* __restrict__ hi,
                                        short* __restrict__ lo, int K, int N, int idx) {
    int total = K * N;
    int z = idx / total;
    int rem = idx - z * total;
    int n = rem / K;
    int k = rem - n * K;
    float v = W[(long long)z * total + (long long)k * N + n];
    short h = f2bf(v);
    hi[idx] = h;
    lo[idx] = f2bf(v - bf2f(h));
}

#define T0 4096
#define T1 32768
#define T2 16384
#define T3 32768
#define T4 1048576
#define T5 1310720
#define TSP_TOTAL (T0 + T1 + T2 + T3 + T4 + T5)   // 2445312 = 9552*256
#define WR_BLK 128
#define TSP_BLK 9552
#define XB_BLK 6250

__global__ void prep_all(PrepPtrs pp) {
    int b = blockIdx.x;
    if (b < WR_BLK) {
        const float* C = (b < 64) ? pp.C1 : pp.C2;
        const float* V = (b < 64) ? pp.V1 : pp.V2;
        short* hi = (b < 64) ? pp.wr1_hi : pp.wr2_hi;
        short* lo = (b < 64) ? pp.wr1_lo : pp.wr2_lo;
        int idx = (b & 63) * 256 + threadIdx.x;
        int o = idx >> 8;
        int ri = idx & 255;
        int r = ri >> 6;
        int i = ri & 63;
        float v = C[r * 2] * V[i * 64 + o] + C[r * 2 + 1] * V[4096 + i * 64 + o];
        short h = f2bf(v);
        hi[idx] = h;
        lo[idx] = f2bf(v - bf2f(h));
        return;
    }
    b -= WR_BLK;
    if (b < TSP_BLK) {
        int idx = b * 256 + threadIdx.x;
        if (idx < T0) { tsp_one(pp.Wlin, pp.Wlin_hi, pp.Wlin_lo, 64, 64, idx); return; }
        idx -= T0;
        if (idx < T1) { tsp_one(pp.Wd1, pp.Wd1_hi, pp.Wd1_lo, 64, 256, idx); return; }
        idx -= T1;
        if (idx < T2) { tsp_one(pp.Wd2, pp.Wd2_hi, pp.Wd2_lo, 256, 32, idx); return; }
        idx -= T2;
        if (idx < T3) { tsp_one(pp.Wf1, pp.Wf1_hi, pp.Wf1_lo, 64, 256, idx); return; }
        idx -= T3;
        if (idx < T4) { tsp_one(pp.Wf2, pp.Wf2_hi, pp.Wf2_lo, 256, 2048, idx); return; }
        idx -= T4;
        tsp_one(pp.Wf3, pp.Wf3_hi, pp.Wf3_lo, 2048, 320, idx);
        return;
    }
    b -= TSP_BLK;
    int idx = b * 256 + threadIdx.x;          // < 1,600,000 (NN*HH/4)
    f32x4 v = *(const f32x4*)&pp.x[(long long)idx * 4];
    short4v o;
    #pragma unroll
    for (int c = 0; c < 4; c++) o[c] = f2bf(v[c]);
    *(short4v*)&pp.xb[(long long)idx * 4] = o;
}

// ---------------- CSR build ----------------
__global__ void count_kernel(const int* __restrict__ edges, int* __restrict__ counts) {
    int idx = blockIdx.x * 256 + threadIdx.x;
    if (idx >= RR * EE) return;
    int r = idx / EE;
    int dst = edges[2 * idx + 1];
    atomicAdd(&counts[dst * RR + r], 1);
}

__global__ void scan1(const int* __restrict__ counts, int* __restrict__ excl,
                      int* __restrict__ bsums, int n) {
    __shared__ int tmp[256];
    int tid = threadIdx.x;
    int gid = blockIdx.x * 256 + tid;
    int v = (gid < n) ? counts[gid] : 0;
    tmp[tid] = v;
    __syncthreads();
    #pragma unroll
    for (int off = 1; off < 256; off <<= 1) {
        int y = (tid >= off) ? tmp[tid - off] : 0;
        __syncthreads();
        tmp[tid] += y;
        __syncthreads();
    }
    if (gid < n) excl[gid] = tmp[tid] - v;
    if (tid == 255) bsums[blockIdx.x] = tmp[255];
}

__global__ void scan2(int* __restrict__ bsums, int nb) {
    __shared__ int tmp[256];
    __shared__ int carry;
    int tid = threadIdx.x;
    if (tid == 0) carry = 0;
    __syncthreads();
    for (int base = 0; base < nb; base += 256) {
        int i = base + tid;
        int v = (i < nb) ? bsums[i] : 0;
        tmp[tid] = v;
        __syncthreads();
        #pragma unroll
        for (int off = 1; off < 256; off <<= 1) {
            int y = (tid >= off) ? tmp[tid - off] : 0;
            __syncthreads();
            tmp[tid] += y;
            __syncthreads();
        }
        if (i < nb) bsums[i] = tmp[tid] - v + carry;
        __syncthreads();
        if (tid == 0) carry += tmp[255];
        __syncthreads();
    }
}

__global__ void scan3(const int* __restrict__ excl, const int* __restrict__ bsums,
                      int* __restrict__ row_ptr, int* __restrict__ cursor, int n, int total) {
    int gid = blockIdx.x * 256 + threadIdx.x;
    if (gid < n) {
        int v = excl[gid] + bsums[gid >> 8];
        row_ptr[gid] = v;
        cursor[gid] = v;
    }
    if (gid == 0) row_ptr[n] = total;
}

__global__ void fill_csr(const int* __restrict__ edges, int* __restrict__ cursor,
                         int* __restrict__ csr_src) {
    int part = blockIdx.x & (FPART - 1);
    int idx = (blockIdx.x >> 3) * 256 + threadIdx.x;
    if (idx >= RR * EE) return;
    int dst = edges[2 * idx + 1];
    int lo = part * PWIDTH;
    if (dst < lo || dst >= lo + PWIDTH) return;
    int r = idx / EE;
    int src = edges[2 * idx];
    int pos = atomicAdd(&cursor[dst * RR + r], 1);
    csr_src[pos] = src;
}

// ---------------- gather aggregation ----------------
// One segment per 8-lane group; lane covers 8 channels via one 16B load.
// 4-wide batched independent loads; 8 segments per wave.
__global__ __launch_bounds__(256) void gather_agg(const int* __restrict__ row_ptr,
                                                  const int* __restrict__ csr_src,
                                                  const short* __restrict__ feat,
                                                  short* __restrict__ agg) {
    long long tg = (long long)blockIdx.x * 256 + threadIdx.x;
    long long seg = tg >> 3;
    int cl = threadIdx.x & 7;           // channels 8cl .. 8cl+7
    if (seg >= (long long)NSEG) return;
    int beg = row_ptr[seg];
    int end = row_ptr[seg + 1];
    float s[8] = {0.f, 0.f, 0.f, 0.f, 0.f, 0.f, 0.f, 0.f};
    int i = beg;
    for (; i + 4 <= end; i += 4) {
        int a = csr_src[i];
        int b = csr_src[i + 1];
        int c = csr_src[i + 2];
        int d = csr_src[i + 3];
        short8 va = *(const short8*)&feat[a * HH + cl * 8];
        short8 vb = *(const short8*)&feat[b * HH + cl * 8];
        short8 vc = *(const short8*)&feat[c * HH + cl * 8];
        short8 vd = *(const short8*)&feat[d * HH + cl * 8];
        #pragma unroll
        for (int j = 0; j < 8; j++)
            s[j] += (bf2f(va[j]) + bf2f(vb[j])) + (bf2f(vc[j]) + bf2f(vd[j]));
    }
    int rem = end - i;
    if (rem > 0) {
        int a = csr_src[i];
        int b = csr_src[rem > 1 ? i + 1 : i];
        int c = csr_src[rem > 2 ? i + 2 : i];
        short8 va = *(const short8*)&feat[a * HH + cl * 8];
        short8 vb = *(const short8*)&feat[b * HH + cl * 8];
        short8 vc = *(const short8*)&feat[c * HH + cl * 8];
        #pragma unroll
        for (int j = 0; j < 8; j++) {
            s[j] += bf2f(va[j]);
            s[j] += (rem > 1) ? bf2f(vb[j]) : 0.f;
            s[j] += (rem > 2) ? bf2f(vc[j]) : 0.f;
        }
    }
    int d = end - beg;
    float inv = 1.0f / (float)(d > 1 ? d : 1);
    short8 o;
    #pragma unroll
    for (int j = 0; j < 8; j++) o[j] = f2bf(s[j] * inv);
    *(short8*)&agg[seg * HH + cl * 8] = o;
}

// split-K reduction + bias + tanh for f3
__global__ void reduce_tanh(const float* __restrict__ part, const float* __restrict__ bf3,
                            float* __restrict__ out) {
    int idx = blockIdx.x * 256 + threadIdx.x;
    if (idx >= PP * SS * 320) return;
    int p = idx / (SS * 320);
    int rem = idx - p * (SS * 320);
    int n = rem % 320;
    float s = bf3[p * 320 + n];
    #pragma unroll
    for (int ks = 0; ks < 4; ks++)
        s += part[((long long)(p * 4 + ks)) * SS * 320 + rem];
    out[idx] = tanhf(s);
}

// ======== combine1: h1 = relu(agg @ Wr1), 64-row tile, grid 1563 ========
__global__ __launch_bounds__(256) void combine1_kernel(
    const short* __restrict__ A,                                   // [NN][256]
    const short* __restrict__ Bhi, const short* __restrict__ Blo,  // [64][256]
    short* __restrict__ h1)
{
    __shared__ short As[64 * 32];
    __shared__ short Bs_hi[64 * 32];
    __shared__ short Bs_lo[64 * 32];

    int tid = threadIdx.x;
    int lane = tid & 63;
    int w = tid >> 6, wm = w >> 1, wn = w & 1;
    int mrow = lane & 15, quad = lane >> 4;
    int m0 = blockIdx.x * 64;

    f32x4 acc[2][2];
    #pragma unroll
    for (int s = 0; s < 2; s++)
        #pragma unroll
        for (int t = 0; t < 2; t++)
            acc[s][t] = (f32x4){0.f, 0.f, 0.f, 0.f};

    for (int k0 = 0; k0 < 256; k0 += 32) {
        {
            int m = tid >> 2, q = tid & 3;
            int gm = m0 + m;
            short8 av = (short8)0;
            if (gm < NN) av = *(const short8*)&A[(long long)gm * 256 + k0 + q * 8];
            *(short8*)&As[m * 32 + q * 8] = av;
            long long boff = (long long)m * 256 + k0 + q * 8;   // m doubles as n
            *(short8*)&Bs_hi[m * 32 + q * 8] = *(const short8*)&Bhi[boff];
            *(short8*)&Bs_lo[m * 32 + q * 8] = *(const short8*)&Blo[boff];
        }
        __syncthreads();

        short8 ah[2], bh[2], bl[2];
        #pragma unroll
        for (int s = 0; s < 2; s++)
            ah[s] = *(const short8*)&As[(wm * 32 + s * 16 + mrow) * 32 + quad * 8];
        #pragma unroll
        for (int t = 0; t < 2; t++) {
            int soff = (wn * 32 + t * 16 + mrow) * 32 + quad * 8;
            bh[t] = *(const short8*)&Bs_hi[soff];
            bl[t] = *(const short8*)&Bs_lo[soff];
        }
        #pragma unroll
        for (int s = 0; s < 2; s++)
            #pragma unroll
            for (int t = 0; t < 2; t++) {
                acc[s][t] = __builtin_amdgcn_mfma_f32_16x16x32_bf16(ah[s], bh[t], acc[s][t], 0, 0, 0);
                acc[s][t] = __builtin_amdgcn_mfma_f32_16x16x32_bf16(ah[s], bl[t], acc[s][t], 0, 0, 0);
            }
        __syncthreads();
    }

    #pragma unroll
    for (int s = 0; s < 2; s++) {
        int gmBase = m0 + wm * 32 + s * 16 + quad * 4;
        #pragma unroll
        for (int t = 0; t < 2; t++) {
            int gn = wn * 32 + t * 16 + mrow;
            #pragma unroll
            for (int r = 0; r < 4; r++) {
                int gm = gmBase + r;
                if (gm >= NN) continue;
                h1[(long long)gm * 64 + gn] = f2bf(fmaxf(acc[s][t][r], 0.f));
            }
        }
    }
}

// ======== combine2+linear fused: h3b = bf16(leaky(relu(agg@Wr2) @ Wlin + blin) + noise) =
// 64-row tile (grid 1563); Wlin fragments in registers; h2 round-trips through aliased LDS.
__global__ __launch_bounds__(256) void combine2_linear(
    const short* __restrict__ A,                                       // agg2 [NN][256]
    const short* __restrict__ Bhi, const short* __restrict__ Blo,      // Wr2t [64][256]
    const short* __restrict__ Lhi, const short* __restrict__ Llo,      // Wlint [64][64]
    const float* __restrict__ blin, const float* __restrict__ noise,
    short* __restrict__ h3b)
{
    __shared__ short smem[6144];       // As | Bs_hi | Bs_lo ; h2s (64x72) aliases all
    short* As = smem;
    short* Bs_hi = smem + 2048;
    short* Bs_lo = smem + 4096;
    short* h2s = smem;

    int tid = threadIdx.x;
    int lane = tid & 63;
    int w = tid >> 6, wm = w >> 1, wn = w & 1;
    int mrow = lane & 15, quad = lane >> 4;
    int m0 = blockIdx.x * 64;

    // Wlin fragments in registers (this wave's cols, both k-halves, hi+lo)
    short8 lhi[2][2], llo[2][2];
    #pragma unroll
    for (int t = 0; t < 2; t++)
        #pragma unroll
        for (int kk = 0; kk < 2; kk++) {
            int loff = (wn * 32 + t * 16 + mrow) * 64 + kk * 32 + quad * 8;
            lhi[t][kk] = *(const short8*)&Lhi[loff];
            llo[t][kk] = *(const short8*)&Llo[loff];
        }

    f32x4 acc[2][2];
    #pragma unroll
    for (int s = 0; s < 2; s++)
        #pragma unroll
        for (int t = 0; t < 2; t++)
            acc[s][t] = (f32x4){0.f, 0.f, 0.f, 0.f};

    for (int k0 = 0; k0 < 256; k0 += 32) {
        {
            int m = tid >> 2, q = tid & 3;
            int gm = m0 + m;
            short8 av = (short8)0;
            if (gm < NN) av = *(const short8*)&A[(long long)gm * 256 + k0 + q * 8];
            *(short8*)&As[m * 32 + q * 8] = av;
            long long boff = (long long)m * 256 + k0 + q * 8;
            *(short8*)&Bs_hi[m * 32 + q * 8] = *(const short8*)&Bhi[boff];
            *(short8*)&Bs_lo[m * 32 + q * 8] = *(const short8*)&Blo[boff];
        }
        __syncthreads();

        short8 ah[2], bh[2], bl[2];
        #pragma unroll
        for (int s = 0; s < 2; s++)
            ah[s] = *(const short8*)&As[(wm * 32 + s * 16 + mrow) * 32 + quad * 8];
        #pragma unroll
        for (int t = 0; t < 2; t++) {
            int soff = (wn * 32 + t * 16 + mrow) * 32 + quad * 8;
            bh[t] = *(const short8*)&Bs_hi[soff];
            bl[t] = *(const short8*)&Bs_lo[soff];
        }
        #pragma unroll
        for (int s = 0; s < 2; s++)
            #pragma unroll
            for (int t = 0; t < 2; t++) {
                acc[s][t] = __builtin_amdgcn_mfma_f32_16x16x32_bf16(ah[s], bh[t], acc[s][t], 0, 0, 0);
                acc[s][t] = __builtin_amdgcn_mfma_f32_16x16x32_bf16(ah[s], bl[t], acc[s][t], 0, 0, 0);
            }
        __syncthreads();
    }

    // h2 = relu(acc) -> aliased LDS (stride 72 to break bank conflicts)
    #pragma unroll
    for (int s = 0; s < 2; s++) {
        int rowB = wm * 32 + s * 16 + quad * 4;
        #pragma unroll
        for (int t = 0; t < 2; t++) {
            int col = wn * 32 + t * 16 + mrow;
            #pragma unroll
            for (int r = 0; r < 4; r++)
                h2s[(rowB + r) * 72 + col] = f2bf(fmaxf(acc[s][t][r], 0.f));
        }
    }
    __syncthreads();

    // phase 2: h3 = leaky(h2 @ Wlin + blin) + noise
    f32x4 acc2[2][2];
    #pragma unroll
    for (int s = 0; s < 2; s++)
        #pragma unroll
        for (int t = 0; t < 2; t++)
            acc2[s][t] = (f32x4){0.f, 0.f, 0.f, 0.f};

    #pragma unroll
    for (int kk = 0; kk < 2; kk++) {
        short8 ah[2];
        #pragma unroll
        for (int s = 0; s < 2; s++)
            ah[s] = *(const short8*)&h2s[(wm * 32 + s * 16 + mrow) * 72 + kk * 32 + quad * 8];
        #pragma unroll
        for (int s = 0; s < 2; s++)
            #pragma unroll
            for (int t = 0; t < 2; t++) {
                acc2[s][t] = __builtin_amdgcn_mfma_f32_16x16x32_bf16(ah[s], lhi[t][kk], acc2[s][t], 0, 0, 0);
                acc2[s][t] = __builtin_amdgcn_mfma_f32_16x16x32_bf16(ah[s], llo[t][kk], acc2[s][t], 0, 0, 0);
            }
    }

    #pragma unroll
    for (int s = 0; s < 2; s++) {
        int gmBase = m0 + wm * 32 + s * 16 + quad * 4;
        #pragma unroll
        for (int t = 0; t < 2; t++) {
            int gn = wn * 32 + t * 16 + mrow;
            float bb = blin[gn];
            #pragma unroll
            for (int r = 0; r < 4; r++) {
                int gm = gmBase + r;
                if (gm >= NN) continue;
                float v = acc2[s][t][r] + bb;
                v = (v > 0.f) ? v : 0.01f * v;
                v += noise[(long long)gm * 64 + gn];
                h3b[(long long)gm * 64 + gn] = f2bf(v);
            }
        }
    }
}

// ======== head layer-1 GEMM with integrated seed gather (bf16 h3, 2 MFMAs) ====
__global__ __launch_bounds__(256) void head1_gemm(
    const short* __restrict__ h3b, const int* __restrict__ seeds,
    const short* __restrict__ Bd_hi, const short* __restrict__ Bd_lo, const float* __restrict__ bd,
    const short* __restrict__ Bf_hi, const short* __restrict__ Bf_lo, const float* __restrict__ bfb,
    short* __restrict__ outd, short* __restrict__ outf)
{
    __shared__ short As[128 * 32];
    __shared__ short Bs_hi[64 * 32];
    __shared__ short Bs_lo[64 * 32];

    int z = blockIdx.z;
    int head = z >> 1, p = z & 1;
    const short* Bhi = (head ? Bf_hi : Bd_hi) + (long long)p * 256 * 64;
    const short* Blo = (head ? Bf_lo : Bd_lo) + (long long)p * 256 * 64;
    const float* bz = (head ? bfb : bd) + p * 256;
    short* Cc = (head ? outf : outd) + (long long)p * SS * 256;

    int m0 = blockIdx.y * 128;
    int n0 = blockIdx.x * 64;
    int tid = threadIdx.x;
    int lane = tid & 63;
    int w = tid >> 6;
    int wm = w >> 1, wn = w & 1;
    int mrow = lane & 15;
    int quad = lane >> 4;

    f32x4 acc[4][2];
    #pragma unroll
    for (int s = 0; s < 4; s++)
        #pragma unroll
        for (int t = 0; t < 2; t++)
            acc[s][t] = (f32x4){0.f, 0.f, 0.f, 0.f};

    #pragma unroll
    for (int k0 = 0; k0 < 64; k0 += 32) {
        #pragma unroll
        for (int i = 0; i < 2; i++) {
            int f = tid + i * 256;
            int m = f >> 2, q = f & 3;
            int node = seeds[m0 + m];
            *(short8*)&As[m * 32 + q * 8] = *(const short8*)&h3b[(long long)node * 64 + k0 + q * 8];
        }
        {
            int n = tid >> 2, q = tid & 3;
            long long boff = (long long)(n0 + n) * 64 + k0 + q * 8;
            *(short8*)&Bs_hi[n * 32 + q * 8] = *(const short8*)&Bhi[boff];
            *(short8*)&Bs_lo[n * 32 + q * 8] = *(const short8*)&Blo[boff];
        }
        __syncthreads();

        short8 ah[4], bh[2], bl[2];
        #pragma unroll
        for (int s = 0; s < 4; s++)
            ah[s] = *(const short8*)&As[(wm * 64 + s * 16 + mrow) * 32 + quad * 8];
        #pragma unroll
        for (int t = 0; t < 2; t++) {
            int soff = (wn * 32 + t * 16 + mrow) * 32 + quad * 8;
            bh[t] = *(const short8*)&Bs_hi[soff];
            bl[t] = *(const short8*)&Bs_lo[soff];
        }
        #pragma unroll
        for (int s = 0; s < 4; s++)
            #pragma unroll
            for (int t = 0; t < 2; t++) {
                acc[s][t] = __builtin_amdgcn_mfma_f32_16x16x32_bf16(ah[s], bh[t], acc[s][t], 0, 0, 0);
                acc[s][t] = __builtin_amdgcn_mfma_f32_16x16x32_bf16(ah[s], bl[t], acc[s][t], 0, 0, 0);
            }
        __syncthreads();
    }

    #pragma unroll
    for (int s = 0; s < 4; s++) {
        int gmBase = m0 + wm * 64 + s * 16 + quad * 4;
        #pragma unroll
        for (int t = 0; t < 2; t++) {
            int gn = n0 + wn * 32 + t * 16 + mrow;
            float bb = bz[gn];
            #pragma unroll
            for (int r = 0; r < 4; r++) {
                int gm = gmBase + r;
                float v = acc[s][t][r] + bb;
                v = (head == 1) ? fmaxf(v, 0.f) : ((v > 0.f) ? v : 0.01f * v);
                Cc[(long long)gm * 256 + gn] = f2bf(v);
            }
        }
    }
}

// ======== fused d-head: pred_missing = relu(leaky(d1@Wd2+bd2) @ Wd3 + bd3) ========
__global__ __launch_bounds__(256) void dhead_gemm(
    const short* __restrict__ d1b,                                  // [P][4096][256]
    const short* __restrict__ Bhi, const short* __restrict__ Blo,   // Wd2t [P][32][256]
    const float* __restrict__ bd2, const float* __restrict__ Wd3,
    const float* __restrict__ bd3, float* __restrict__ out)
{
    __shared__ short As[128 * 32];
    __shared__ short Bs_hi[64 * 32];
    __shared__ short Bs_lo[64 * 32];
    __shared__ float d2s[128][33];

    int p = blockIdx.z;
    const short* A = d1b + (long long)p * SS * 256;
    const short* Bh = Bhi + (long long)p * 32 * 256;
    const short* Bl = Blo + (long long)p * 32 * 256;

    int m0 = blockIdx.y * 128;
    int tid = threadIdx.x;
    int lane = tid & 63;
    int w = tid >> 6;
    int wm = w >> 1, wn = w & 1;
    int mrow = lane & 15;
    int quad = lane >> 4;

    f32x4 acc[4][2];
    #pragma unroll
    for (int s = 0; s < 4; s++)
        #pragma unroll
        for (int t = 0; t < 2; t++)
            acc[s][t] = (f32x4){0.f, 0.f, 0.f, 0.f};

    for (int k0 = 0; k0 < 256; k0 += 32) {
        #pragma unroll
        for (int i = 0; i < 2; i++) {
            int f = tid + i * 256;
            int m = f >> 2, q = f & 3;
            *(short8*)&As[m * 32 + q * 8] = *(const short8*)&A[(long long)(m0 + m) * 256 + k0 + q * 8];
        }
        {
            int n = tid >> 2, q = tid & 3;
            short8 bh = (short8)0, bl = (short8)0;
            if (n < 32) {
                long long boff = (long long)n * 256 + k0 + q * 8;
                bh = *(const short8*)&Bh[boff];
                bl = *(const short8*)&Bl[boff];
            }
            *(short8*)&Bs_hi[n * 32 + q * 8] = bh;
            *(short8*)&Bs_lo[n * 32 + q * 8] = bl;
        }
        __syncthreads();

        short8 ah[4], bh[2], bl[2];
        #pragma unroll
        for (int s = 0; s < 4; s++)
            ah[s] = *(const short8*)&As[(wm * 64 + s * 16 + mrow) * 32 + quad * 8];
        #pragma unroll
        for (int t = 0; t < 2; t++) {
            int soff = (wn * 32 + t * 16 + mrow) * 32 + quad * 8;
            bh[t] = *(const short8*)&Bs_hi[soff];
            bl[t] = *(const short8*)&Bs_lo[soff];
        }
        #pragma unroll
        for (int s = 0; s < 4; s++)
            #pragma unroll
            for (int t = 0; t < 2; t++) {
                acc[s][t] = __builtin_amdgcn_mfma_f32_16x16x32_bf16(ah[s], bh[t], acc[s][t], 0, 0, 0);
                acc[s][t] = __builtin_amdgcn_mfma_f32_16x16x32_bf16(ah[s], bl[t], acc[s][t], 0, 0, 0);
            }
        __syncthreads();
    }

    if (wn == 0) {
        #pragma unroll
        for (int s = 0; s < 4; s++) {
            int rowB = wm * 64 + s * 16 + quad * 4;
            #pragma unroll
            for (int t = 0; t < 2; t++) {
                int col = t * 16 + mrow;
                #pragma unroll
                for (int r = 0; r < 4; r++) {
                    float v = acc[s][t][r] + bd2[p * 32 + col];
                    d2s[rowB + r][col] = (v > 0.f) ? v : 0.01f * v;
                }
            }
        }
    }
    __syncthreads();

    if (tid < 128) {
        float sacc = bd3[p];
        #pragma unroll
        for (int k = 0; k < 32; k++) sacc += d2s[tid][k] * Wd3[p * 32 + k];
        out[p * SS + m0 + tid] = fmaxf(sacc, 0.f);
    }
}

// ================= MFMA GEMM, A = bf16 single plane (2 MFMAs), optional split-K =========
template <int ACT, bool OUTBF, int KSPLIT>
__global__ __launch_bounds__(256) void mfma_gemm_bfA(
    const short* __restrict__ A, int lda, long long sA,
    const short* __restrict__ Bhi, const short* __restrict__ Blo, long long sB,
    const float* __restrict__ bias, long long sBias,
    void* __restrict__ Cc, int ldc, long long sC,
    int M, int Nn, int K)
{
    __shared__ short As[128 * 32];
    __shared__ short Bs_hi[64 * 32];
    __shared__ short Bs_lo[64 * 32];

    int z = blockIdx.z;
    int p = z / KSPLIT, ks = z % KSPLIT;
    A += (long long)p * sA;
    Bhi += (long long)p * sB;
    Blo += (long long)p * sB;
    const float* bz = bias ? bias + (long long)p * sBias : nullptr;
    long long cbase = (long long)((KSPLIT > 1) ? z : p) * sC;

    int Kc = K / KSPLIT;
    int kbeg = ks * Kc;

    int m0 = blockIdx.y * 128;
    int n0 = blockIdx.x * 64;
    int tid = threadIdx.x;
    int lane = tid & 63;
    int w = tid >> 6;
    int wm = w >> 1, wn = w & 1;
    int mrow = lane & 15;
    int quad = lane >> 4;

    f32x4 acc[4][2];
    #pragma unroll
    for (int s = 0; s < 4; s++)
        #pragma unroll
        for (int t = 0; t < 2; t++)
            acc[s][t] = (f32x4){0.f, 0.f, 0.f, 0.f};

    for (int k0 = kbeg; k0 < kbeg + Kc; k0 += 32) {
        #pragma unroll
        for (int i = 0; i < 2; i++) {
            int f = tid + i * 256;
            int m = f >> 2, q = f & 3;
            int gm = m0 + m;
            short8 av = (short8)0;
            if (gm < M) av = *(const short8*)&A[(long long)gm * lda + k0 + q * 8];
            *(short8*)&As[m * 32 + q * 8] = av;
        }
        {
            int n = tid >> 2, q = tid & 3;
            int gn = n0 + n;
            short8 bh = (short8)0, bl = (short8)0;
            if (gn < Nn) {
                long long boff = (long long)gn * K + k0 + q * 8;
                bh = *(const short8*)&Bhi[boff];
                bl = *(const short8*)&Blo[boff];
            }
            *(short8*)&Bs_hi[n * 32 + q * 8] = bh;
            *(short8*)&Bs_lo[n * 32 + q * 8] = bl;
        }
        __syncthreads();

        short8 ah[4], bh[2], bl[2];
        #pragma unroll
        for (int s = 0; s < 4; s++)
            ah[s] = *(const short8*)&As[(wm * 64 + s * 16 + mrow) * 32 + quad * 8];
        #pragma unroll
        for (int t = 0; t < 2; t++) {
            int soff = (wn * 32 + t * 16 + mrow) * 32 + quad * 8;
            bh[t] = *(const short8*)&Bs_hi[soff];
            bl[t] = *(const short8*)&Bs_lo[soff];
        }
        #pragma unroll
        for (int s = 0; s < 4; s++)
            #pragma unroll
            for (int t = 0; t < 2; t++) {
                acc[s][t] = __builtin_amdgcn_mfma_f32_16x16x32_bf16(ah[s], bh[t], acc[s][t], 0, 0, 0);
                acc[s][t] = __builtin_amdgcn_mfma_f32_16x16x32_bf16(ah[s], bl[t], acc[s][t], 0, 0, 0);
            }
        __syncthreads();
    }

    #pragma unroll
    for (int s = 0; s < 4; s++) {
        int gmBase = m0 + wm * 64 + s * 16 + quad * 4;
        #pragma unroll
        for (int t = 0; t < 2; t++) {
            int gn = n0 + wn * 32 + t * 16 + mrow;
            if (gn >= Nn) continue;
            float bb = bz ? bz[gn] : 0.f;
            #pragma unroll
            for (int r = 0; r < 4; r++) {
                int gm = gmBase + r;
                if (gm >= M) continue;
                float v = acc[s][t][r] + bb;
                if (ACT == 1) v = fmaxf(v, 0.f);
                long long co = cbase + (long long)gm * ldc + gn;
                if (OUTBF) ((short*)Cc)[co] = f2bf(v);
                else ((float*)Cc)[co] = v;
            }
        }
    }
}

extern "C" void kernel_launch(void* const* d_in, const int* in_sizes, int n_in,
                              void* d_out, int out_size, void* d_ws, size_t ws_size,
                              hipStream_t stream) {
    const float* x    = (const float*)d_in[0];
    const int* edges  = (const int*)d_in[1];
    const int* seeds  = (const int*)d_in[2];
    const float* noise= (const float*)d_in[3];
    const float* V1   = (const float*)d_in[4];
    const float* C1   = (const float*)d_in[5];
    const float* V2   = (const float*)d_in[6];
    const float* C2   = (const float*)d_in[7];
    const float* Wlin = (const float*)d_in[8];
    const float* blin = (const float*)d_in[9];
    const float* Wd1 = (const float*)d_in[10]; const float* bd1 = (const float*)d_in[11];
    const float* Wd2 = (const float*)d_in[12]; const float* bd2 = (const float*)d_in[13];
    const float* Wd3 = (const float*)d_in[14]; const float* bd3 = (const float*)d_in[15];
    const float* Wf1 = (const float*)d_in[16]; const float* bf1 = (const float*)d_in[17];
    const float* Wf2 = (const float*)d_in[18]; const float* bf2 = (const float*)d_in[19];
    const float* Wf3 = (const float*)d_in[20]; const float* bf3 = (const float*)d_in[21];

    float* out = (float*)d_out;

    char* ws = (char*)d_ws;
    size_t off = 0;
    auto allocs = [&](size_t ns) {
        short* p = (short*)(ws + off);
        off += ((ns * 2 + 255) / 256) * 256;
        return p;
    };
    auto alloci = [&](size_t ni) {
        int* p = (int*)(ws + off);
        off += ((ni * 4 + 255) / 256) * 256;
        return p;
    };

    short* Wrt1_hi = allocs(16384);          short* Wrt1_lo = allocs(16384);
    short* Wrt2_hi = allocs(16384);          short* Wrt2_lo = allocs(16384);
    short* Wlint_hi = allocs(4096);          short* Wlint_lo = allocs(4096);
    short* Wd1t_hi = allocs(2 * 64 * 256);   short* Wd1t_lo = allocs(2 * 64 * 256);
    short* Wd2t_hi = allocs(2 * 256 * 32);   short* Wd2t_lo = allocs(2 * 256 * 32);
    short* Wf1t_hi = allocs(2 * 64 * 256);   short* Wf1t_lo = allocs(2 * 64 * 256);
    short* Wf2t_hi = allocs((size_t)2 * 256 * 2048);  short* Wf2t_lo = allocs((size_t)2 * 256 * 2048);
    short* Wf3t_hi = allocs((size_t)2 * 2048 * 320);  short* Wf3t_lo = allocs((size_t)2 * 2048 * 320);

    // CSR
    int* counts  = alloci(NSEG);
    int* excl    = alloci(NSEG);
    int* bsums   = alloci(2048);
    int* row_ptr = alloci(NSEG + 1);
    int* cursor  = alloci(NSEG);
    int* csr_src = alloci((size_t)RR * EE);

    short* xb  = allocs((size_t)NN * HH);        // bf16 copy of x
    short* agg = allocs((size_t)NSEG * HH);      // 51.2 MB; reused as fpart later
    short* h1  = allocs((size_t)NN * HH);        // bf16
    short* h3b = allocs((size_t)NN * HH);        // bf16 (post-noise)
    short* d1b = allocs((size_t)PP * SS * 256);  // bf16
    short* f1  = allocs((size_t)PP * SS * 256);  // bf16
    short* f2b = allocs((size_t)PP * SS * 2048); // bf16

    float* fpart = (float*)agg;                  // 4*2*4096*320*4 = 41.9 MB <= 51.2 MB

    // ---- prep (1 launch)
    PrepPtrs pp;
    pp.Wlin = Wlin; pp.Wd1 = Wd1; pp.Wd2 = Wd2; pp.Wf1 = Wf1; pp.Wf2 = Wf2; pp.Wf3 = Wf3;
    pp.Wlin_hi = Wlint_hi; pp.Wlin_lo = Wlint_lo;
    pp.Wd1_hi = Wd1t_hi;   pp.Wd1_lo = Wd1t_lo;
    pp.Wd2_hi = Wd2t_hi;   pp.Wd2_lo = Wd2t_lo;
    pp.Wf1_hi = Wf1t_hi;   pp.Wf1_lo = Wf1t_lo;
    pp.Wf2_hi = Wf2t_hi;   pp.Wf2_lo = Wf2t_lo;
    pp.Wf3_hi = Wf3t_hi;   pp.Wf3_lo = Wf3t_lo;
    pp.C1 = C1; pp.V1 = V1; pp.C2 = C2; pp.V2 = V2;
    pp.wr1_hi = Wrt1_hi; pp.wr1_lo = Wrt1_lo; pp.wr2_hi = Wrt2_hi; pp.wr2_lo = Wrt2_lo;
    pp.x = x; pp.xb = xb;
    prep_all<<<WR_BLK + TSP_BLK + XB_BLK, 256, 0, stream>>>(pp);

    // ---- CSR build
    hipMemsetAsync(counts, 0, (size_t)NSEG * 4, stream);
    int eb0 = (RR * EE + 255) / 256;                      // 4688
    count_kernel<<<eb0, 256, 0, stream>>>(edges, counts);
    int nb = (NSEG + 255) / 256;                          // 1563
    scan1<<<nb, 256, 0, stream>>>(counts, excl, bsums, NSEG);
    scan2<<<1, 256, 0, stream>>>(bsums, nb);
    scan3<<<nb, 256, 0, stream>>>(excl, bsums, row_ptr, cursor, NSEG, RR * EE);
    fill_csr<<<eb0 * FPART, 256, 0, stream>>>(edges, cursor, csr_src);

    int gb = (int)(((long long)NSEG * 8 + 255) / 256);    // 12500 blocks
    int MB64 = (NN + 63) / 64;                            // 1563

    // ---- layer 1
    gather_agg<<<gb, 256, 0, stream>>>(row_ptr, csr_src, xb, agg);
    combine1_kernel<<<MB64, 256, 0, stream>>>(agg, Wrt1_hi, Wrt1_lo, h1);

    // ---- layer 2 + linear (fused)
    gather_agg<<<gb, 256, 0, stream>>>(row_ptr, csr_src, h1, agg);
    combine2_linear<<<MB64, 256, 0, stream>>>(
        agg, Wrt2_hi, Wrt2_lo, Wlint_hi, Wlint_lo, blin, noise, h3b);

    // head layer 1: d1 (leaky) + f1 (relu), seeds gathered in-kernel
    head1_gemm<<<dim3(4, 32, 4), 256, 0, stream>>>(
        h3b, seeds, Wd1t_hi, Wd1t_lo, bd1, Wf1t_hi, Wf1t_lo, bf1, d1b, f1);

    // d-head fused: d2+d3 -> out[0 : P*S]
    dhead_gemm<<<dim3(1, 32, PP), 256, 0, stream>>>(
        d1b, Wd2t_hi, Wd2t_lo, bd2, Wd3, bd3, out);

    // f2 = relu(f1 @ Wf2 + bf2) -> bf16
    mfma_gemm_bfA<1, true, 1><<<dim3(32, 32, PP), 256, 0, stream>>>(
        f1, 256, (long long)SS * 256, Wf2t_hi, Wf2t_lo, (long long)2048 * 256, bf2, 2048,
        f2b, 2048, (long long)SS * 2048, SS, 2048, 256);
    // f3 partials: split-K=4
    mfma_gemm_bfA<0, false, 4><<<dim3(5, 32, PP * 4), 256, 0, stream>>>(
        f2b, 2048, (long long)SS * 2048, Wf3t_hi, Wf3t_lo, (long long)320 * 2048, nullptr, 0,
        fpart, 320, (long long)SS * 320, SS, 320, 2048);
    reduce_tanh<<<(PP * SS * 320 + 255) / 256, 256, 0, stream>>>(fpart, bf3, out + (size_t)PP * SS);
}